// Round 1
// 1902.224 us; speedup vs baseline: 4.3562x; 4.3562x over previous
//
#include <hip/hip_runtime.h>
#include <hip/hip_bf16.h>

#define L_SEQ 4096
#define HDIM 2048
#define NPROJA 8256      // packed q(2048) k(2048) v(4096) ba(64)
#define WLD 12352        // row stride of in_proj_w
#define EPS_ 1e-6f

using bf16 = __hip_bfloat16;
typedef __attribute__((ext_vector_type(8))) short short8;
typedef __attribute__((ext_vector_type(4))) float f32x4;

__device__ __forceinline__ float b2f(bf16 x) { return __bfloat162float(x); }
__device__ __forceinline__ bf16 f2b(float x) { return __float2bfloat16(x); }
__device__ __forceinline__ unsigned short b2u(bf16 x) {
  union { bf16 b; unsigned short u; } c; c.b = x; return c.u;
}
// XOR-swizzled LDS addressing (16B-slot swizzle keyed on row&7) for MFMA frags
__device__ __forceinline__ void* swz(void* base, int row, int rowbytes, int colbyte) {
  return (void*)((char*)base + row * rowbytes + (colbyte ^ ((row & 7) << 4)));
}
__device__ __forceinline__ const void* swzc(const void* base, int row, int rowbytes, int colbyte) {
  return (const void*)((const char*)base + row * rowbytes + (colbyte ^ ((row & 7) << 4)));
}

__device__ __forceinline__ void async_copy16(const void* g, void* l) {
  __builtin_amdgcn_global_load_lds(
      (const __attribute__((address_space(1))) void*)g,
      (__attribute__((address_space(3))) void*)l, 16, 0, 0);
}

// ---------------- fp32 -> bf16 convert (linear) ---------------------------
__global__ __launch_bounds__(256) void cvt_bf16(const float* __restrict__ in,
                                                bf16* __restrict__ outp) {
  int i = (blockIdx.x * 256 + threadIdx.x) * 4;
  float4 v = *(const float4*)&in[i];
  bf16 o4[4] = {f2b(v.x), f2b(v.y), f2b(v.z), f2b(v.w)};
  *(ushort4*)&outp[i] = *(ushort4*)o4;
}

// ---------------- MFMA bf16 GEMM with B-column remap ----------------------
// MODE 0: identity. MODE 1: qkvz+ba interleaved -> packed qkv|ba cols.
// MODE 2: z columns only.
template <int MODE>
__device__ __forceinline__ int colmap(int n) {
  if constexpr (MODE == 1) {
    if (n < 2048) return (n >> 7) * 768 + (n & 127);
    else if (n < 4096) { int m = n - 2048; return (m >> 7) * 768 + 128 + (m & 127); }
    else if (n < 8192) { int m = n - 4096; return (m >> 8) * 768 + 256 + (m & 255); }
    else return 12288 + (n - 8192);
  } else if constexpr (MODE == 2) {
    return (n >> 8) * 768 + 512 + (n & 255);
  } else {
    return n;
  }
}

template <bool CBF16, int MODE>
__global__ __launch_bounds__(256) void gemm_mfma(
    const bf16* __restrict__ A, const float* __restrict__ B, void* __restrict__ Cv,
    int M, int N, int Kd, int ldb) {
  __shared__ bf16 As[128 * 32];
  __shared__ bf16 Bs[4 * 128 * 8];
  const int tid = threadIdx.x;
  const int wave = tid >> 6, lane = tid & 63;
  const int l15 = lane & 15, quad = lane >> 4;
  const int m0 = blockIdx.y * 128, n0 = blockIdx.x * 128;
  const int mw = (wave >> 1) * 64, nw = (wave & 1) * 64;

  f32x4 acc[4][4];
#pragma unroll
  for (int i = 0; i < 4; i++)
#pragma unroll
    for (int j = 0; j < 4; j++) acc[i][j] = {0.f, 0.f, 0.f, 0.f};

  const bf16* a_src0 = A + (size_t)(m0 + (tid >> 2)) * Kd + (tid & 3) * 8;
  const bf16* a_src1 = A + (size_t)(m0 + 64 + (tid >> 2)) * Kd + (tid & 3) * 8;
  bf16* a_dst0 = &As[tid * 8];
  bf16* a_dst1 = &As[(tid + 256) * 8];
  int bc0 = n0 + lane, bc1 = n0 + 64 + lane;
  bc0 = bc0 < N ? bc0 : N - 1;
  bc1 = bc1 < N ? bc1 : N - 1;
  const int bm0 = colmap<MODE>(bc0);
  const int bm1 = colmap<MODE>(bc1);

  for (int k0 = 0; k0 < Kd; k0 += 32) {
    float bv0[8], bv1[8];
#pragma unroll
    for (int j = 0; j < 8; j++) {
      const float* brow = B + (size_t)(k0 + wave * 8 + j) * ldb;
      bv0[j] = brow[bm0];
      bv1[j] = brow[bm1];
    }
    __syncthreads();
    async_copy16(a_src0 + k0, a_dst0);
    async_copy16(a_src1 + k0, a_dst1);
    bf16 bb0[8], bb1[8];
#pragma unroll
    for (int j = 0; j < 8; j++) { bb0[j] = f2b(bv0[j]); bb1[j] = f2b(bv1[j]); }
    *(float4*)&Bs[(wave * 128 + lane) * 8] = *(float4*)bb0;
    *(float4*)&Bs[(wave * 128 + 64 + lane) * 8] = *(float4*)bb1;
    __syncthreads();

    short8 af[4], bfr[4];
#pragma unroll
    for (int i = 0; i < 4; i++)
      af[i] = *(const short8*)&As[(mw + i * 16 + l15) * 32 + quad * 8];
#pragma unroll
    for (int j = 0; j < 4; j++)
      bfr[j] = *(const short8*)&Bs[(quad * 128 + nw + j * 16 + l15) * 8];
#pragma unroll
    for (int i = 0; i < 4; i++)
#pragma unroll
      for (int j = 0; j < 4; j++)
        acc[i][j] = __builtin_amdgcn_mfma_f32_16x16x32_bf16(af[i], bfr[j],
                                                            acc[i][j], 0, 0, 0);
  }

#pragma unroll
  for (int i = 0; i < 4; i++) {
#pragma unroll
    for (int j = 0; j < 4; j++) {
      int col = n0 + nw + j * 16 + l15;
      if (col < N) {
#pragma unroll
        for (int r = 0; r < 4; r++) {
          int row = m0 + mw + i * 16 + quad * 4 + r;
          if (CBF16)
            ((bf16*)Cv)[(size_t)row * N + col] = f2b(acc[i][j][r]);
          else
            ((float*)Cv)[(size_t)row * N + col] = acc[i][j][r];
        }
      }
    }
  }
}

// ------- fused conv(K=4 causal) + SiLU + l2norm for q and k ---------------
__global__ __launch_bounds__(128) void conv_norm_qk(
    const bf16* __restrict__ proj, const float* __restrict__ conv_w,
    bf16* __restrict__ qn, bf16* __restrict__ kn) {
  const int t = blockIdx.x >> 4, hk = blockIdx.x & 15;
  const int d = threadIdx.x;
  const int cq = hk * 128 + d;          // conv channel == packed col
  const int ck = 2048 + hk * 128 + d;
  float sq = 0.f, sk = 0.f;
#pragma unroll
  for (int j = 0; j < 4; j++) {
    int ts = t + j - 3;
    if (ts >= 0) {
      sq += conv_w[cq * 4 + j] * b2f(proj[(size_t)ts * NPROJA + cq]);
      sk += conv_w[ck * 4 + j] * b2f(proj[(size_t)ts * NPROJA + ck]);
    }
  }
  float qv = sq / (1.f + expf(-sq));
  float kv = sk / (1.f + expf(-sk));
  float ssq = qv * qv, ssk = kv * kv;
#pragma unroll
  for (int off = 32; off > 0; off >>= 1) {
    ssq += __shfl_down(ssq, off, 64);
    ssk += __shfl_down(ssk, off, 64);
  }
  __shared__ float red[4];
  if ((d & 63) == 0) {
    red[(d >> 6) * 2] = ssq;
    red[(d >> 6) * 2 + 1] = ssk;
  }
  __syncthreads();
  float sumq = red[0] + red[2];
  float sumk = red[1] + red[3];
  size_t o = (size_t)(t * 16 + hk) * 128 + d;
  qn[o] = f2b(qv * rsqrtf(sumq + EPS_) * 0.08838834764831845f);
  kn[o] = f2b(kv * rsqrtf(sumk + EPS_));
}

// ------- conv + SiLU for v channels ---------------------------------------
__global__ __launch_bounds__(256) void conv_silu_v(
    const bf16* __restrict__ proj, const float* __restrict__ conv_w,
    bf16* __restrict__ vbuf) {
  int idx = blockIdx.x * 256 + threadIdx.x;
  int t = idx >> 12, c = idx & 4095;
  int chan = 4096 + c;                  // conv channel == packed col
  float s = 0.f;
#pragma unroll
  for (int j = 0; j < 4; j++) {
    int ts = t + j - 3;
    if (ts >= 0) s += conv_w[chan * 4 + j] * b2f(proj[(size_t)ts * NPROJA + chan]);
  }
  vbuf[idx] = f2b(s / (1.f + expf(-s)));
}

// ---------------- beta / g ------------------------------------------------
__global__ __launch_bounds__(256) void compute_bg(
    const bf16* __restrict__ proj, const float* __restrict__ A_log,
    const float* __restrict__ dt_bias, float* __restrict__ beta_arr,
    float* __restrict__ g_arr) {
  int idx = blockIdx.x * 256 + threadIdx.x;
  int t = idx >> 5, hv = idx & 31;
  size_t base = (size_t)t * NPROJA + 8192 + (hv >> 1) * 4 + (hv & 1);
  float b = b2f(proj[base]);
  float a = b2f(proj[base + 2]);
  beta_arr[idx] = 1.f / (1.f + expf(-b));
  float x = a + dt_bias[hv];
  float sp = (x > 20.f) ? x : log1pf(expf(x));
  g_arr[idx] = -expf(A_log[hv]) * sp;
}

// ---------------- chunked WY precompute: TV = T@V, TK = T@Ktilde ----------
// one block per (chunk c, head h). T = (I + diag(beta) A)^-1 diag(beta),
// A[i][j] = exp(cg_i - cg_j) k_i.k_j (strictly lower).
__global__ __launch_bounds__(256) void precompute_chunk(
    const bf16* __restrict__ kn, const bf16* __restrict__ vbuf,
    const float* __restrict__ g_arr, const float* __restrict__ beta_arr,
    bf16* __restrict__ TV, bf16* __restrict__ TK) {
  const int c = blockIdx.x >> 5, h = blockIdx.x & 31, hk = h >> 1;
  const int t0 = c * 64, tid = threadIdx.x;
  __shared__ float Kf[64][129];
  __shared__ float X[64][256];
  __shared__ float BA[64][64];
  __shared__ float cgs[64], bet[64], eKs[64];

  for (int e = tid; e < 1024; e += 256) {
    int row = e >> 4, s = e & 15;
    short8 v = *(const short8*)(kn + ((size_t)(t0 + row) * 16 + hk) * 128 + s * 8);
    bf16 tmp[8];
    *(short8*)tmp = v;
#pragma unroll
    for (int k = 0; k < 8; ++k) Kf[row][s * 8 + k] = b2f(tmp[k]);
  }
  if (tid < 64) bet[tid] = beta_arr[(size_t)(t0 + tid) * 32 + h];
  if (tid < 64) {
    float x = g_arr[(size_t)(t0 + tid) * 32 + h];
#pragma unroll
    for (int off = 1; off < 64; off <<= 1) {
      float o = __shfl_up(x, off, 64);
      if (tid >= off) x += o;
    }
    cgs[tid] = x;
    eKs[tid] = bet[tid] * expf(x);   // beta_i * Lambda_i
  }
  __syncthreads();
  // X init = diag(beta) [V | Ktilde]
  for (int e = tid; e < 8192; e += 256) {
    int i = e >> 7, d = e & 127;
    X[i][d] = bet[i] * b2f(vbuf[(size_t)(t0 + i) * 4096 + h * 128 + d]);
    X[i][128 + d] = eKs[i] * Kf[i][d];
  }
  // BA[i][j] = beta_i * exp(cg_i - cg_j) * (k_i . k_j), strictly lower
  {
    const int ti = tid >> 4, tj = tid & 15;
    float acc[4][4];
#pragma unroll
    for (int r = 0; r < 4; ++r)
#pragma unroll
      for (int s = 0; s < 4; ++s) acc[r][s] = 0.f;
    for (int dk = 0; dk < 128; ++dk) {
      float a0 = Kf[ti * 4 + 0][dk], a1 = Kf[ti * 4 + 1][dk];
      float a2 = Kf[ti * 4 + 2][dk], a3 = Kf[ti * 4 + 3][dk];
      float c0 = Kf[tj * 4 + 0][dk], c1 = Kf[tj * 4 + 1][dk];
      float c2 = Kf[tj * 4 + 2][dk], c3 = Kf[tj * 4 + 3][dk];
      acc[0][0] += a0 * c0; acc[0][1] += a0 * c1; acc[0][2] += a0 * c2; acc[0][3] += a0 * c3;
      acc[1][0] += a1 * c0; acc[1][1] += a1 * c1; acc[1][2] += a1 * c2; acc[1][3] += a1 * c3;
      acc[2][0] += a2 * c0; acc[2][1] += a2 * c1; acc[2][2] += a2 * c2; acc[2][3] += a2 * c3;
      acc[3][0] += a3 * c0; acc[3][1] += a3 * c1; acc[3][2] += a3 * c2; acc[3][3] += a3 * c3;
    }
#pragma unroll
    for (int r = 0; r < 4; ++r)
#pragma unroll
      for (int s = 0; s < 4; ++s) {
        int i = ti * 4 + r, j = tj * 4 + s;
        BA[i][j] = (j < i) ? bet[i] * expf(cgs[i] - cgs[j]) * acc[r][s] : 0.f;
      }
  }
  __syncthreads();
  // forward substitution: thread owns column tid -> no barriers needed
  {
    const int d = tid;
    for (int i = 1; i < 64; ++i) {
      float s = 0.f;
      const float* bar = BA[i];
      for (int j = 0; j < i; ++j) s += bar[j] * X[j][d];
      X[i][d] -= s;
    }
  }
  __syncthreads();
  for (int e = tid; e < 8192; e += 256) {
    int i = e >> 7, d = e & 127;
    size_t o = ((size_t)(t0 + i) * 32 + h) * 128 + d;
    TV[o] = f2b(X[i][d]);
    TK[o] = f2b(X[i][128 + d]);
  }
}

// ---------------- sequential inter-chunk recurrence (MFMA, hi/lo S) -------
// per head: for each chunk c:
//   x = TK_c @ S                   (GEMM1, hi+lo on S)
//   Oinner_c = Qtilde_c @ S        (GEMM3, hi only)
//   U_c = TV_c - x                 (write bf16 global, hi/lo to LDS)
//   S = lam*S + Khat'^T @ U_c      (GEMM2, hi+lo on U; S in f32 regs)
__global__ __launch_bounds__(512) void seq_kernel(
    bf16* TVU,                       // [4096][32][128]: TV in, U out (in-place)
    const bf16* __restrict__ TKg, const bf16* __restrict__ qn,
    const bf16* __restrict__ kn, const float* __restrict__ g_arr,
    bf16* __restrict__ Oin) {        // vbuf reused: Oinner out
  const int h = blockIdx.x, hk = h >> 1;
  const int tid = threadIdx.x;
  const int wave = tid >> 6, lane = tid & 63, l15 = lane & 15, quad = lane >> 4;
  const int mi = wave >> 1, half = wave & 1;

  __shared__ bf16 STh[128 * 128], STl[128 * 128];  // S^T [n][dk] hi/lo
  __shared__ bf16 UTh[128 * 64], UTl[128 * 64];    // U^T [n][i]  hi/lo
  __shared__ bf16 TKs[64 * 128];                   // TK [i][dk]
  __shared__ bf16 Qts[64 * 128];                   // Qtilde [i][dk]
  __shared__ bf16 KhT[128 * 64];                   // Khat'^T [dk][i]
  __shared__ float cgs[64], fQs[64], fKs[64];
  __shared__ float lam_s;

  for (int e = tid; e < 8192; e += 512) {
    ((unsigned int*)STh)[e] = 0u;
    ((unsigned int*)STl)[e] = 0u;
  }
  f32x4 Sf[8];
#pragma unroll
  for (int i = 0; i < 8; i++) Sf[i] = {0.f, 0.f, 0.f, 0.f};

  for (int c = 0; c < 64; ++c) {
    const int t0 = c << 6;
    __syncthreads();  // (1) prev ST writes visible; staging buffers free

    // TV prefetch into registers (consumed at U-phase)
    bf16 tvp[4][4];
#pragma unroll
    for (int nj = 0; nj < 4; nj++) {
      const int nrow = half * 64 + nj * 16 + l15;
#pragma unroll
      for (int r = 0; r < 4; r++) {
        const int i = mi * 16 + quad * 4 + r;
        tvp[nj][r] = TVU[((size_t)(t0 + i) * 32 + h) * 128 + nrow];
      }
    }
    // stage TK tile
#pragma unroll
    for (int it = 0; it < 2; ++it) {
      int e = tid + it * 512;
      int row = e >> 4, s = e & 15;
      short8 v = *(const short8*)(TKg + ((size_t)(t0 + row) * 32 + h) * 128 + s * 8);
      *(short8*)swz(TKs, row, 256, s * 16) = v;
    }
    // chunk-local cumulative g and decay factors (wave 0)
    if (tid < 64) {
      float x = g_arr[(size_t)(t0 + tid) * 32 + h];
#pragma unroll
      for (int off = 1; off < 64; off <<= 1) {
        float o = __shfl_up(x, off, 64);
        if (tid >= off) x += o;
      }
      cgs[tid] = x;
      float cg63 = __shfl(x, 63, 64);
      fQs[tid] = expf(x);
      fKs[tid] = expf(cg63 - x);
      if (tid == 0) lam_s = expf(cg63);
    }
    __syncthreads();  // (2) factors visible
    // stage Qtilde and Khat'^T
#pragma unroll
    for (int it = 0; it < 2; ++it) {
      int e = tid + it * 512;
      int row = e >> 4, s = e & 15;
      short8 v = *(const short8*)(qn + ((size_t)(t0 + row) * 16 + hk) * 128 + s * 8);
      bf16 tmp[8];
      *(short8*)tmp = v;
      float fq = fQs[row];
#pragma unroll
      for (int k = 0; k < 8; k++) tmp[k] = f2b(b2f(tmp[k]) * fq);
      *(short8*)swz(Qts, row, 256, s * 16) = *(short8*)tmp;
    }
#pragma unroll
    for (int it = 0; it < 2; ++it) {
      int e = tid + it * 512;
      int row = e >> 4, s = e & 15;
      short8 v = *(const short8*)(kn + ((size_t)(t0 + row) * 16 + hk) * 128 + s * 8);
      bf16 tmp[8];
      *(short8*)tmp = v;
      float fk = fKs[row];
#pragma unroll
      for (int k = 0; k < 8; k++) {
        int dk = s * 8 + k;
        *(bf16*)swz(KhT, dk, 128, row * 2) = f2b(b2f(tmp[k]) * fk);
      }
    }
    __syncthreads();  // (3) operands staged

    // GEMM3 (Oinner) + GEMM1 (x) fused over shared B reads
    f32x4 oacc[4], xacc[4];
#pragma unroll
    for (int nj = 0; nj < 4; nj++) { oacc[nj] = {0.f,0.f,0.f,0.f}; xacc[nj] = {0.f,0.f,0.f,0.f}; }
    const int arow = mi * 16 + l15;
#pragma unroll
    for (int ks = 0; ks < 4; ++ks) {
      const int cb = ks * 64 + quad * 16;
      short8 aq = *(const short8*)swzc(Qts, arow, 256, cb);
      short8 at = *(const short8*)swzc(TKs, arow, 256, cb);
#pragma unroll
      for (int nj = 0; nj < 4; nj++) {
        const int nrow = half * 64 + nj * 16 + l15;
        short8 bh = *(const short8*)swzc(STh, nrow, 256, cb);
        short8 bl = *(const short8*)swzc(STl, nrow, 256, cb);
        oacc[nj] = __builtin_amdgcn_mfma_f32_16x16x32_bf16(aq, bh, oacc[nj], 0, 0, 0);
        xacc[nj] = __builtin_amdgcn_mfma_f32_16x16x32_bf16(at, bh, xacc[nj], 0, 0, 0);
        xacc[nj] = __builtin_amdgcn_mfma_f32_16x16x32_bf16(at, bl, xacc[nj], 0, 0, 0);
      }
    }
    // U phase: U = TV - x; write Oinner + U(global) + U^T hi/lo (LDS)
#pragma unroll
    for (int nj = 0; nj < 4; nj++) {
      const int nrow = half * 64 + nj * 16 + l15;
      unsigned short ph[4], pl[4];
#pragma unroll
      for (int r = 0; r < 4; ++r) {
        const int i = mi * 16 + quad * 4 + r;
        const size_t go = ((size_t)(t0 + i) * 32 + h) * 128 + nrow;
        Oin[go] = f2b(oacc[nj][r]);
        float uv = b2f(tvp[nj][r]) - xacc[nj][r];
        bf16 hb = f2b(uv);
        TVU[go] = hb;
        float hif = b2f(hb);
        ph[r] = b2u(hb);
        pl[r] = b2u(f2b(uv - hif));
      }
      const int cb = (mi * 16 + quad * 4) * 2;
      ushort4 vh; vh.x = ph[0]; vh.y = ph[1]; vh.z = ph[2]; vh.w = ph[3];
      ushort4 vl; vl.x = pl[0]; vl.y = pl[1]; vl.z = pl[2]; vl.w = pl[3];
      *(ushort4*)swz(UTh, nrow, 128, cb) = vh;
      *(ushort4*)swz(UTl, nrow, 128, cb) = vl;
    }
    __syncthreads();  // (4) UT visible

    // GEMM2: S = lam*S + Khat'^T @ U  (S master in f32 accumulators)
    const float lam = lam_s;
#pragma unroll
    for (int nj = 0; nj < 8; nj++) {
      Sf[nj][0] *= lam; Sf[nj][1] *= lam; Sf[nj][2] *= lam; Sf[nj][3] *= lam;
    }
    const int krow = wave * 16 + l15;
#pragma unroll
    for (int ks = 0; ks < 2; ++ks) {
      const int cb = ks * 64 + quad * 16;
      short8 ak = *(const short8*)swzc(KhT, krow, 128, cb);
#pragma unroll
      for (int nj = 0; nj < 8; nj++) {
        const int nrow = nj * 16 + l15;
        short8 bh = *(const short8*)swzc(UTh, nrow, 128, cb);
        short8 bl = *(const short8*)swzc(UTl, nrow, 128, cb);
        Sf[nj] = __builtin_amdgcn_mfma_f32_16x16x32_bf16(ak, bh, Sf[nj], 0, 0, 0);
        Sf[nj] = __builtin_amdgcn_mfma_f32_16x16x32_bf16(ak, bl, Sf[nj], 0, 0, 0);
      }
    }
    // write S^T hi/lo for next chunk
#pragma unroll
    for (int nj = 0; nj < 8; nj++) {
      const int nrow = nj * 16 + l15;
      unsigned short ph[4], pl[4];
#pragma unroll
      for (int r = 0; r < 4; ++r) {
        float s = Sf[nj][r];
        bf16 hb = f2b(s);
        float hif = b2f(hb);
        ph[r] = b2u(hb);
        pl[r] = b2u(f2b(s - hif));
      }
      const int cb = (wave * 16 + quad * 4) * 2;
      ushort4 vh; vh.x = ph[0]; vh.y = ph[1]; vh.z = ph[2]; vh.w = ph[3];
      ushort4 vl; vl.x = pl[0]; vl.y = pl[1]; vl.z = pl[2]; vl.w = pl[3];
      *(ushort4*)swz(STh, nrow, 256, cb) = vh;
      *(ushort4*)swz(STl, nrow, 256, cb) = vl;
    }
  }
}

// ---------------- pass2: O = Oinner + Attn@U, fused gated RMSNorm ---------
__global__ __launch_bounds__(256) void pass2_kernel(
    bf16* UC,                        // U in, normed core out (in-place)
    const bf16* __restrict__ Oin, const bf16* __restrict__ qn,
    const bf16* __restrict__ kn, const float* __restrict__ g_arr,
    const bf16* __restrict__ zbuf, const float* __restrict__ norm_w) {
  const int c = blockIdx.x >> 5, h = blockIdx.x & 31, hk = h >> 1;
  const int t0 = c * 64, tid = threadIdx.x;
  __shared__ float Qf[64][129], Kf[64][129];
  __shared__ float Uf[64][128];
  __shared__ float Of[64][129];
  __shared__ float At[64][65];
  __shared__ float cgs[64], nw[128];

  for (int e = tid; e < 1024; e += 256) {
    int row = e >> 4, s = e & 15;
    size_t qko = ((size_t)(t0 + row) * 16 + hk) * 128 + s * 8;
    size_t uo = ((size_t)(t0 + row) * 32 + h) * 128 + s * 8;
    short8 vq = *(const short8*)(qn + qko);
    short8 vk = *(const short8*)(kn + qko);
    short8 vu = *(const short8*)(UC + uo);
    short8 vo = *(const short8*)(Oin + uo);
    bf16 tq[8], tk[8], tu[8], to[8];
    *(short8*)tq = vq; *(short8*)tk = vk; *(short8*)tu = vu; *(short8*)to = vo;
#pragma unroll
    for (int k = 0; k < 8; ++k) {
      Qf[row][s * 8 + k] = b2f(tq[k]);
      Kf[row][s * 8 + k] = b2f(tk[k]);
      Uf[row][s * 8 + k] = b2f(tu[k]);
      Of[row][s * 8 + k] = b2f(to[k]);
    }
  }
  if (tid < 64) {
    float x = g_arr[(size_t)(t0 + tid) * 32 + h];
#pragma unroll
    for (int off = 1; off < 64; off <<= 1) {
      float o = __shfl_up(x, off, 64);
      if (tid >= off) x += o;
    }
    cgs[tid] = x;
  }
  if (tid < 128) nw[tid] = norm_w[tid];
  __syncthreads();
  // Attn build (includes diagonal)
  {
    const int ti = tid >> 4, tj = tid & 15;
    float acc[4][4];
#pragma unroll
    for (int r = 0; r < 4; ++r)
#pragma unroll
      for (int s = 0; s < 4; ++s) acc[r][s] = 0.f;
    for (int dk = 0; dk < 128; ++dk) {
      float a0 = Qf[ti * 4 + 0][dk], a1 = Qf[ti * 4 + 1][dk];
      float a2 = Qf[ti * 4 + 2][dk], a3 = Qf[ti * 4 + 3][dk];
      float c0 = Kf[tj * 4 + 0][dk], c1 = Kf[tj * 4 + 1][dk];
      float c2 = Kf[tj * 4 + 2][dk], c3 = Kf[tj * 4 + 3][dk];
      acc[0][0] += a0 * c0; acc[0][1] += a0 * c1; acc[0][2] += a0 * c2; acc[0][3] += a0 * c3;
      acc[1][0] += a1 * c0; acc[1][1] += a1 * c1; acc[1][2] += a1 * c2; acc[1][3] += a1 * c3;
      acc[2][0] += a2 * c0; acc[2][1] += a2 * c1; acc[2][2] += a2 * c2; acc[2][3] += a2 * c3;
      acc[3][0] += a3 * c0; acc[3][1] += a3 * c1; acc[3][2] += a3 * c2; acc[3][3] += a3 * c3;
    }
#pragma unroll
    for (int r = 0; r < 4; ++r)
#pragma unroll
      for (int s = 0; s < 4; ++s) {
        int i = ti * 4 + r, j = tj * 4 + s;
        At[i][j] = (j <= i) ? expf(cgs[i] - cgs[j]) * acc[r][s] : 0.f;
      }
  }
  __syncthreads();
  // O += Attn @ U
  {
    const int ti2 = tid >> 4, tn = tid & 15;
    float acc[4][8];
#pragma unroll
    for (int r = 0; r < 4; ++r)
#pragma unroll
      for (int k = 0; k < 8; ++k) acc[r][k] = 0.f;
    for (int j = 0; j < 64; ++j) {
      float a0 = At[ti2 * 4 + 0][j], a1 = At[ti2 * 4 + 1][j];
      float a2 = At[ti2 * 4 + 2][j], a3 = At[ti2 * 4 + 3][j];
#pragma unroll
      for (int k = 0; k < 8; ++k) {
        float u = Uf[j][tn + 16 * k];
        acc[0][k] += a0 * u; acc[1][k] += a1 * u;
        acc[2][k] += a2 * u; acc[3][k] += a3 * u;
      }
    }
#pragma unroll
    for (int r = 0; r < 4; ++r)
#pragma unroll
      for (int k = 0; k < 8; ++k)
        Of[ti2 * 4 + r][tn + 16 * k] += acc[r][k];
  }
  __syncthreads();
  // gated RMSNorm + store
  {
    const int r = tid >> 2, q4 = tid & 3;
    float ss = 0.f;
#pragma unroll
    for (int k = 0; k < 32; ++k) {
      float v = Of[r][q4 + 4 * k];
      ss += v * v;
    }
    ss += __shfl_xor(ss, 1, 64);
    ss += __shfl_xor(ss, 2, 64);
    float scale = rsqrtf(ss * (1.f / 128.f) + EPS_);
#pragma unroll
    for (int k = 0; k < 32; ++k) {
      int n = q4 + 4 * k;
      float val = Of[r][n] * scale * nw[n];
      float zz = b2f(zbuf[(size_t)(t0 + r) * 4096 + h * 128 + n]);
      val *= zz / (1.f + expf(-zz));
      UC[((size_t)(t0 + r) * 32 + h) * 128 + n] = f2b(val);
    }
  }
}

extern "C" void kernel_launch(void* const* d_in, const int* in_sizes, int n_in,
                              void* d_out, int out_size, void* d_ws,
                              size_t ws_size, hipStream_t stream) {
  const float* hidden = (const float*)d_in[0];
  const float* in_w = (const float*)d_in[1];
  const float* conv_w = (const float*)d_in[2];
  const float* A_log = (const float*)d_in[3];
  const float* dt_bias = (const float*)d_in[4];
  const float* norm_w = (const float*)d_in[5];
  const float* out_w = (const float*)d_in[6];
  float* out = (float*)d_out;

  // workspace layout: total 169,345,024 B (proven size)
  char* p = (char*)d_ws;
  bf16* projA = (bf16*)p;                         // 67,633,152 [4096][8256]
  bf16* TV = (bf16*)p;                            // alias: TV -> U -> core
  bf16* TK = (bf16*)(p + 33554432ULL);            // alias upper half of projA
  p += 67633152ULL;
  bf16* zbuf = (bf16*)p; p += 33554432ULL;        // [4096][32][128]
  bf16* vbuf = (bf16*)p; p += 33554432ULL;        // V, then Oinner
  float* beta = (float*)p; p += 524288ULL;
  float* g = (float*)p; p += 524288ULL;
  bf16* qn = (bf16*)p; p += 16777216ULL;
  bf16* kn = (bf16*)p;                            // 16,777,216
  bf16* hb16 = qn;  // aliases qn region; dead before conv_norm_qk writes qn

  // 0. hidden fp32 -> bf16
  cvt_bf16<<<(L_SEQ * HDIM) / 1024, 256, 0, stream>>>(hidden, hb16);
  // 1a. in_proj GEMM, packed q|k|v|ba columns
  gemm_mfma<true, 1><<<dim3(65, 32), 256, 0, stream>>>(hb16, in_w, projA, L_SEQ,
                                                       NPROJA, HDIM, WLD);
  // 1b. in_proj GEMM, z columns -> zbuf
  gemm_mfma<true, 2><<<dim3(32, 32), 256, 0, stream>>>(hb16, in_w, zbuf, L_SEQ,
                                                       4096, HDIM, WLD);
  // 2. fused conv + silu + l2norm for q,k
  conv_norm_qk<<<L_SEQ * 16, 128, 0, stream>>>(projA, conv_w, qn, kn);
  // 3. conv + silu for v
  conv_silu_v<<<(L_SEQ * 4096) / 256, 256, 0, stream>>>(projA, conv_w, vbuf);
  // 4. beta / g
  compute_bg<<<(L_SEQ * 32) / 256, 256, 0, stream>>>(projA, A_log, dt_bias,
                                                     beta, g);
  // 5. chunked WY precompute (projA dead -> TV/TK overwrite it)
  precompute_chunk<<<2048, 256, 0, stream>>>(kn, vbuf, g, beta, TV, TK);
  // 6. sequential inter-chunk recurrence (TV->U in place, Oinner->vbuf)
  seq_kernel<<<32, 512, 0, stream>>>(TV, TK, qn, kn, g, vbuf);
  // 7. intra-chunk attention + gated RMSNorm (U->core in place)
  pass2_kernel<<<2048, 256, 0, stream>>>(TV, vbuf, qn, kn, g, zbuf, norm_w);
  // 8. out_proj GEMM
  gemm_mfma<false, 0><<<dim3(16, 32), 256, 0, stream>>>(TV, out_w, out, L_SEQ,
                                                        2048, 4096, 2048);
}

// Round 3
// 1643.771 us; speedup vs baseline: 5.0411x; 1.1572x over previous
//
#include <hip/hip_runtime.h>
#include <hip/hip_bf16.h>

#define L_SEQ 4096
#define HDIM 2048
#define NPROJA 8256      // packed q(2048) k(2048) v(4096) ba(64)
#define WLD 12352        // row stride of in_proj_w
#define EPS_ 1e-6f

using bf16 = __hip_bfloat16;
typedef __attribute__((ext_vector_type(8))) short short8;
typedef __attribute__((ext_vector_type(4))) float f32x4;

__device__ __forceinline__ float b2f(bf16 x) { return __bfloat162float(x); }
__device__ __forceinline__ bf16 f2b(float x) { return __float2bfloat16(x); }
__device__ __forceinline__ unsigned short b2u(bf16 x) {
  union { bf16 b; unsigned short u; } c; c.b = x; return c.u;
}
// XOR-swizzled LDS addressing keyed on row&7 (for 256B/128B-row MFMA tiles)
__device__ __forceinline__ void* swz(void* base, int row, int rowbytes, int colbyte) {
  return (void*)((char*)base + row * rowbytes + (colbyte ^ ((row & 7) << 4)));
}
__device__ __forceinline__ const void* swzc(const void* base, int row, int rowbytes, int colbyte) {
  return (const void*)((const char*)base + row * rowbytes + (colbyte ^ ((row & 7) << 4)));
}
// KhT swizzle: key on (row>>3)&7 so the scalar transpose WRITES (lane-varying
// scol = dk>>3) spread across banks instead of 32-way colliding on dk&7=const.
__device__ __forceinline__ void* swzk(void* base, int row, int colbyte) {
  return (void*)((char*)base + row * 128 + (colbyte ^ (((row >> 3) & 7) << 4)));
}
__device__ __forceinline__ const void* swzkc(const void* base, int row, int colbyte) {
  return (const void*)((const char*)base + row * 128 + (colbyte ^ (((row >> 3) & 7) << 4)));
}

__device__ __forceinline__ void async_copy16(const void* g, void* l) {
  __builtin_amdgcn_global_load_lds(
      (const __attribute__((address_space(1))) void*)g,
      (__attribute__((address_space(3))) void*)l, 16, 0, 0);
}

// ---------------- fp32 -> bf16 convert (linear) ---------------------------
__global__ __launch_bounds__(256) void cvt_bf16(const float* __restrict__ in,
                                                bf16* __restrict__ outp) {
  int i = (blockIdx.x * 256 + threadIdx.x) * 4;
  float4 v = *(const float4*)&in[i];
  bf16 o4[4] = {f2b(v.x), f2b(v.y), f2b(v.z), f2b(v.w)};
  *(ushort4*)&outp[i] = *(ushort4*)o4;
}

// ---------------- MFMA bf16 GEMM with B-column remap ----------------------
template <int MODE>
__device__ __forceinline__ int colmap(int n) {
  if constexpr (MODE == 1) {
    if (n < 2048) return (n >> 7) * 768 + (n & 127);
    else if (n < 4096) { int m = n - 2048; return (m >> 7) * 768 + 128 + (m & 127); }
    else if (n < 8192) { int m = n - 4096; return (m >> 8) * 768 + 256 + (m & 255); }
    else return 12288 + (n - 8192);
  } else if constexpr (MODE == 2) {
    return (n >> 8) * 768 + 512 + (n & 255);
  } else {
    return n;
  }
}

template <bool CBF16, int MODE>
__global__ __launch_bounds__(256) void gemm_mfma(
    const bf16* __restrict__ A, const float* __restrict__ B, void* __restrict__ Cv,
    int M, int N, int Kd, int ldb) {
  __shared__ bf16 As[128 * 32];
  __shared__ bf16 Bs[4 * 128 * 8];
  const int tid = threadIdx.x;
  const int wave = tid >> 6, lane = tid & 63;
  const int l15 = lane & 15, quad = lane >> 4;
  const int m0 = blockIdx.y * 128, n0 = blockIdx.x * 128;
  const int mw = (wave >> 1) * 64, nw = (wave & 1) * 64;

  f32x4 acc[4][4];
#pragma unroll
  for (int i = 0; i < 4; i++)
#pragma unroll
    for (int j = 0; j < 4; j++) acc[i][j] = {0.f, 0.f, 0.f, 0.f};

  const bf16* a_src0 = A + (size_t)(m0 + (tid >> 2)) * Kd + (tid & 3) * 8;
  const bf16* a_src1 = A + (size_t)(m0 + 64 + (tid >> 2)) * Kd + (tid & 3) * 8;
  bf16* a_dst0 = &As[tid * 8];
  bf16* a_dst1 = &As[(tid + 256) * 8];
  int bc0 = n0 + lane, bc1 = n0 + 64 + lane;
  bc0 = bc0 < N ? bc0 : N - 1;
  bc1 = bc1 < N ? bc1 : N - 1;
  const int bm0 = colmap<MODE>(bc0);
  const int bm1 = colmap<MODE>(bc1);

  for (int k0 = 0; k0 < Kd; k0 += 32) {
    float bv0[8], bv1[8];
#pragma unroll
    for (int j = 0; j < 8; j++) {
      const float* brow = B + (size_t)(k0 + wave * 8 + j) * ldb;
      bv0[j] = brow[bm0];
      bv1[j] = brow[bm1];
    }
    __syncthreads();
    async_copy16(a_src0 + k0, a_dst0);
    async_copy16(a_src1 + k0, a_dst1);
    bf16 bb0[8], bb1[8];
#pragma unroll
    for (int j = 0; j < 8; j++) { bb0[j] = f2b(bv0[j]); bb1[j] = f2b(bv1[j]); }
    *(float4*)&Bs[(wave * 128 + lane) * 8] = *(float4*)bb0;
    *(float4*)&Bs[(wave * 128 + 64 + lane) * 8] = *(float4*)bb1;
    __syncthreads();

    short8 af[4], bfr[4];
#pragma unroll
    for (int i = 0; i < 4; i++)
      af[i] = *(const short8*)&As[(mw + i * 16 + l15) * 32 + quad * 8];
#pragma unroll
    for (int j = 0; j < 4; j++)
      bfr[j] = *(const short8*)&Bs[(quad * 128 + nw + j * 16 + l15) * 8];
#pragma unroll
    for (int i = 0; i < 4; i++)
#pragma unroll
      for (int j = 0; j < 4; j++)
        acc[i][j] = __builtin_amdgcn_mfma_f32_16x16x32_bf16(af[i], bfr[j],
                                                            acc[i][j], 0, 0, 0);
  }

#pragma unroll
  for (int i = 0; i < 4; i++) {
#pragma unroll
    for (int j = 0; j < 4; j++) {
      int col = n0 + nw + j * 16 + l15;
      if (col < N) {
#pragma unroll
        for (int r = 0; r < 4; r++) {
          int row = m0 + mw + i * 16 + quad * 4 + r;
          if (CBF16)
            ((bf16*)Cv)[(size_t)row * N + col] = f2b(acc[i][j][r]);
          else
            ((float*)Cv)[(size_t)row * N + col] = acc[i][j][r];
        }
      }
    }
  }
}

// ------- fused conv(K=4 causal) + SiLU + l2norm for q and k ---------------
__global__ __launch_bounds__(128) void conv_norm_qk(
    const bf16* __restrict__ proj, const float* __restrict__ conv_w,
    bf16* __restrict__ qn, bf16* __restrict__ kn) {
  const int t = blockIdx.x >> 4, hk = blockIdx.x & 15;
  const int d = threadIdx.x;
  const int cq = hk * 128 + d;
  const int ck = 2048 + hk * 128 + d;
  float sq = 0.f, sk = 0.f;
#pragma unroll
  for (int j = 0; j < 4; j++) {
    int ts = t + j - 3;
    if (ts >= 0) {
      sq += conv_w[cq * 4 + j] * b2f(proj[(size_t)ts * NPROJA + cq]);
      sk += conv_w[ck * 4 + j] * b2f(proj[(size_t)ts * NPROJA + ck]);
    }
  }
  float qv = sq / (1.f + expf(-sq));
  float kv = sk / (1.f + expf(-sk));
  float ssq = qv * qv, ssk = kv * kv;
#pragma unroll
  for (int off = 32; off > 0; off >>= 1) {
    ssq += __shfl_down(ssq, off, 64);
    ssk += __shfl_down(ssk, off, 64);
  }
  __shared__ float red[4];
  if ((d & 63) == 0) {
    red[(d >> 6) * 2] = ssq;
    red[(d >> 6) * 2 + 1] = ssk;
  }
  __syncthreads();
  float sumq = red[0] + red[2];
  float sumk = red[1] + red[3];
  size_t o = (size_t)(t * 16 + hk) * 128 + d;
  qn[o] = f2b(qv * rsqrtf(sumq + EPS_) * 0.08838834764831845f);
  kn[o] = f2b(kv * rsqrtf(sumk + EPS_));
}

// ------- conv + SiLU for v channels ---------------------------------------
__global__ __launch_bounds__(256) void conv_silu_v(
    const bf16* __restrict__ proj, const float* __restrict__ conv_w,
    bf16* __restrict__ vbuf) {
  int idx = blockIdx.x * 256 + threadIdx.x;
  int t = idx >> 12, c = idx & 4095;
  int chan = 4096 + c;
  float s = 0.f;
#pragma unroll
  for (int j = 0; j < 4; j++) {
    int ts = t + j - 3;
    if (ts >= 0) s += conv_w[chan * 4 + j] * b2f(proj[(size_t)ts * NPROJA + chan]);
  }
  vbuf[idx] = f2b(s / (1.f + expf(-s)));
}

// ---------------- beta / g ------------------------------------------------
__global__ __launch_bounds__(256) void compute_bg(
    const bf16* __restrict__ proj, const float* __restrict__ A_log,
    const float* __restrict__ dt_bias, float* __restrict__ beta_arr,
    float* __restrict__ g_arr) {
  int idx = blockIdx.x * 256 + threadIdx.x;
  int t = idx >> 5, hv = idx & 31;
  size_t base = (size_t)t * NPROJA + 8192 + (hv >> 1) * 4 + (hv & 1);
  float b = b2f(proj[base]);
  float a = b2f(proj[base + 2]);
  beta_arr[idx] = 1.f / (1.f + expf(-b));
  float x = a + dt_bias[hv];
  float sp = (x > 20.f) ? x : log1pf(expf(x));
  g_arr[idx] = -expf(A_log[hv]) * sp;
}

// ---------------- chunked WY precompute (512 threads: 8 waves/CU) ---------
__global__ __launch_bounds__(512) void precompute_chunk(
    const bf16* __restrict__ kn, const bf16* __restrict__ vbuf,
    const float* __restrict__ g_arr, const float* __restrict__ beta_arr,
    bf16* __restrict__ TV, bf16* __restrict__ TK) {
  const int c = blockIdx.x >> 5, h = blockIdx.x & 31, hk = h >> 1;
  const int t0 = c * 64, tid = threadIdx.x;
  __shared__ float Kf[64][129];
  __shared__ float X[64][256];
  __shared__ float BA[64][64];
  __shared__ float cgs[64], bet[64], eKs[64];

  for (int e = tid; e < 1024; e += 512) {
    int row = e >> 4, s = e & 15;
    short8 v = *(const short8*)(kn + ((size_t)(t0 + row) * 16 + hk) * 128 + s * 8);
    bf16 tmp[8];
    *(short8*)tmp = v;
#pragma unroll
    for (int k = 0; k < 8; ++k) Kf[row][s * 8 + k] = b2f(tmp[k]);
  }
  if (tid < 64) {
    float bb = beta_arr[(size_t)(t0 + tid) * 32 + h];
    bet[tid] = bb;
    float x = g_arr[(size_t)(t0 + tid) * 32 + h];
#pragma unroll
    for (int off = 1; off < 64; off <<= 1) {
      float o = __shfl_up(x, off, 64);
      if (tid >= off) x += o;
    }
    cgs[tid] = x;
    eKs[tid] = bb * expf(x);
  }
  __syncthreads();
  // X init = diag(beta) [V | Ktilde]
  for (int e = tid; e < 8192; e += 512) {
    int i = e >> 7, d = e & 127;
    X[i][d] = bet[i] * b2f(vbuf[(size_t)(t0 + i) * 4096 + h * 128 + d]);
    X[i][128 + d] = eKs[i] * Kf[i][d];
  }
  // BA[i][j] = beta_i * exp(cg_i - cg_j) * (k_i . k_j), strictly lower
  {
    const int ti = tid >> 4, tj = tid & 15;   // ti: 2 rows, tj: 4 cols
    float acc[2][4];
#pragma unroll
    for (int r = 0; r < 2; ++r)
#pragma unroll
      for (int s = 0; s < 4; ++s) acc[r][s] = 0.f;
    for (int dk = 0; dk < 128; ++dk) {
      float a0 = Kf[ti * 2 + 0][dk], a1 = Kf[ti * 2 + 1][dk];
      float c0 = Kf[tj * 4 + 0][dk], c1 = Kf[tj * 4 + 1][dk];
      float c2 = Kf[tj * 4 + 2][dk], c3 = Kf[tj * 4 + 3][dk];
      acc[0][0] += a0 * c0; acc[0][1] += a0 * c1; acc[0][2] += a0 * c2; acc[0][3] += a0 * c3;
      acc[1][0] += a1 * c0; acc[1][1] += a1 * c1; acc[1][2] += a1 * c2; acc[1][3] += a1 * c3;
    }
#pragma unroll
    for (int r = 0; r < 2; ++r)
#pragma unroll
      for (int s = 0; s < 4; ++s) {
        int i = ti * 2 + r, j = tj * 4 + s;
        BA[i][j] = (j < i) ? bet[i] * expf(cgs[i] - cgs[j]) * acc[r][s] : 0.f;
      }
  }
  __syncthreads();
  // forward substitution: thread owns column (256 cols; waves 4-7 idle here)
  if (tid < 256) {
    const int d = tid;
    for (int i = 1; i < 64; ++i) {
      const float* bar = BA[i];
      float s0 = 0.f, s1 = 0.f;
      int j = 0;
      for (; j + 1 < i; j += 2) {
        s0 += bar[j] * X[j][d];
        s1 += bar[j + 1] * X[j + 1][d];
      }
      if (j < i) s0 += bar[j] * X[j][d];
      X[i][d] -= s0 + s1;
    }
  }
  __syncthreads();
  for (int e = tid; e < 8192; e += 512) {
    int i = e >> 7, d = e & 127;
    size_t o = ((size_t)(t0 + i) * 32 + h) * 128 + d;
    TV[o] = f2b(X[i][d]);
    TK[o] = f2b(X[i][128 + d]);
  }
}

// ---------------- sequential inter-chunk recurrence (MFMA, hi/lo S) -------
// dv-split x2: 64 blocks (h, dv-half). 3 barriers/chunk, reg-prefetched
// operands (T14), all-wave factor scan, swzk'd KhT transpose staging.
__global__ __launch_bounds__(512) void seq_kernel(
    bf16* TVU,                       // [4096][32][128]: TV in, U out (in-place)
    const bf16* __restrict__ TKg, const bf16* __restrict__ qn,
    const bf16* __restrict__ kn, const float* __restrict__ g_arr,
    bf16* __restrict__ Oin) {        // vbuf reused: Oinner out
  const int h = blockIdx.x >> 1, dvh = blockIdx.x & 1, hk = h >> 1;
  const int dv0 = dvh * 64;
  const int tid = threadIdx.x;
  const int wave = tid >> 6, lane = tid & 63, l15 = lane & 15, quad = lane >> 4;
  const int mi = wave >> 1, half = wave & 1;
  const int srow = tid >> 4, scol = tid & 15;

  __shared__ bf16 STh[64 * 128], STl[64 * 128];  // S^T [dv][dk] hi/lo, 16KB ea
  __shared__ bf16 UTh[64 * 64], UTl[64 * 64];    // U^T [dv][i]  hi/lo, 8KB ea
  __shared__ bf16 TKs[64 * 128];                 // TK [i][dk]
  __shared__ bf16 Qts[64 * 128];                 // Qtilde [i][dk]
  __shared__ bf16 KhT[128 * 64];                 // Khat'^T [dk][i] (swzk)

  for (int e = tid; e < 4096; e += 512) {
    ((unsigned int*)STh)[e] = 0u;
    ((unsigned int*)STl)[e] = 0u;
  }
  f32x4 Sf[4];
#pragma unroll
  for (int i = 0; i < 4; i++) Sf[i] = {0.f, 0.f, 0.f, 0.f};

  short8 tkr0, tkr1, qr0, qr1, kr0, kr1;
  float gv;
  auto issue_loads = [&](int c) {
    const size_t t0 = (size_t)c << 6;
    tkr0 = *(const short8*)(TKg + ((t0 + srow) * 32 + h) * 128 + scol * 8);
    tkr1 = *(const short8*)(TKg + ((t0 + 32 + srow) * 32 + h) * 128 + scol * 8);
    qr0 = *(const short8*)(qn + ((t0 + srow) * 16 + hk) * 128 + scol * 8);
    qr1 = *(const short8*)(qn + ((t0 + 32 + srow) * 16 + hk) * 128 + scol * 8);
    kr0 = *(const short8*)(kn + ((t0 + srow) * 16 + hk) * 128 + scol * 8);
    kr1 = *(const short8*)(kn + ((t0 + 32 + srow) * 16 + hk) * 128 + scol * 8);
    gv = g_arr[(t0 + lane) * 32 + h];
  };
  issue_loads(0);

  for (int c = 0; c < 64; ++c) {
    const int t0 = c << 6;
    __syncthreads();  // (A) prev-chunk GEMM reads done; staging buffers free

    // TV prefetch (consumed in U-phase)
    bf16 tvp[2][4];
#pragma unroll
    for (int nj = 0; nj < 2; nj++) {
      const int nrow = half * 32 + nj * 16 + l15;
#pragma unroll
      for (int r = 0; r < 4; r++) {
        const int i = mi * 16 + quad * 4 + r;
        tvp[nj][r] = TVU[((size_t)(t0 + i) * 32 + h) * 128 + dv0 + nrow];
      }
    }
    // all-wave chunk-local cumulative-g scan (lane = chunk row)
    float cg = gv;
#pragma unroll
    for (int off = 1; off < 64; off <<= 1) {
      float o = __shfl_up(cg, off, 64);
      if (lane >= off) cg += o;
    }
    const float cg63 = __shfl(cg, 63, 64);
    const float lam = expf(cg63);
    const float fq = expf(cg);          // this lane's row decay
    const float fk = expf(cg63 - cg);
    // stage TK (vectorized)
    *(short8*)swz(TKs, srow, 256, scol * 16) = tkr0;
    *(short8*)swz(TKs, srow + 32, 256, scol * 16) = tkr1;
    // stage Qtilde = q * fq[row]
    {
      const float f0 = __shfl(fq, srow, 64);
      const float f1 = __shfl(fq, srow + 32, 64);
      bf16 ta[8], tb[8];
      *(short8*)ta = qr0;
      *(short8*)tb = qr1;
#pragma unroll
      for (int k = 0; k < 8; k++) {
        ta[k] = f2b(b2f(ta[k]) * f0);
        tb[k] = f2b(b2f(tb[k]) * f1);
      }
      *(short8*)swz(Qts, srow, 256, scol * 16) = *(short8*)ta;
      *(short8*)swz(Qts, srow + 32, 256, scol * 16) = *(short8*)tb;
    }
    // stage Khat'^T = (k * fk[row])^T, scalar writes spread via swzk
    {
      const float f0 = __shfl(fk, srow, 64);
      const float f1 = __shfl(fk, srow + 32, 64);
      bf16 ka[8], kb[8];
      *(short8*)ka = kr0;
      *(short8*)kb = kr1;
#pragma unroll
      for (int k = 0; k < 8; k++) {
        const int dk = scol * 8 + k;
        *(bf16*)swzk(KhT, dk, srow * 2) = f2b(b2f(ka[k]) * f0);
        *(bf16*)swzk(KhT, dk, (srow + 32) * 2) = f2b(b2f(kb[k]) * f1);
      }
    }
    // T14: issue next-chunk global loads now (fly during GEMM phases)
    issue_loads(c + 1 < 64 ? c + 1 : 63);
    __syncthreads();  // (B) operands staged

    // GEMM3 (Oinner = Qtilde@S) + GEMM1 (x = TK@S) fused over shared B reads
    f32x4 oacc[2], xacc[2];
#pragma unroll
    for (int nj = 0; nj < 2; nj++) { oacc[nj] = {0.f,0.f,0.f,0.f}; xacc[nj] = {0.f,0.f,0.f,0.f}; }
    const int arow = mi * 16 + l15;
#pragma unroll
    for (int ks = 0; ks < 4; ++ks) {
      const int cb = ks * 64 + quad * 16;
      short8 aq = *(const short8*)swzc(Qts, arow, 256, cb);
      short8 at = *(const short8*)swzc(TKs, arow, 256, cb);
#pragma unroll
      for (int nj = 0; nj < 2; nj++) {
        const int nrow = half * 32 + nj * 16 + l15;
        short8 bh = *(const short8*)swzc(STh, nrow, 256, cb);
        short8 bl = *(const short8*)swzc(STl, nrow, 256, cb);
        oacc[nj] = __builtin_amdgcn_mfma_f32_16x16x32_bf16(aq, bh, oacc[nj], 0, 0, 0);
        xacc[nj] = __builtin_amdgcn_mfma_f32_16x16x32_bf16(at, bh, xacc[nj], 0, 0, 0);
        xacc[nj] = __builtin_amdgcn_mfma_f32_16x16x32_bf16(at, bl, xacc[nj], 0, 0, 0);
      }
    }
    // hoist KhT A-fragments into regs (frees KhT before next staging w/o a 4th barrier)
    const int krow = wave * 16 + l15;
    short8 ak0 = *(const short8*)swzkc(KhT, krow, 0 * 64 + quad * 16);
    short8 ak1 = *(const short8*)swzkc(KhT, krow, 1 * 64 + quad * 16);

    // U phase: U = TV - x; write Oinner + U(global) + U^T hi/lo (LDS)
#pragma unroll
    for (int nj = 0; nj < 2; nj++) {
      const int nrow = half * 32 + nj * 16 + l15;
      unsigned short ph[4], pl[4];
#pragma unroll
      for (int r = 0; r < 4; ++r) {
        const int i = mi * 16 + quad * 4 + r;
        const size_t go = ((size_t)(t0 + i) * 32 + h) * 128 + dv0 + nrow;
        Oin[go] = f2b(oacc[nj][r]);
        float uv = b2f(tvp[nj][r]) - xacc[nj][r];
        bf16 hb = f2b(uv);
        TVU[go] = hb;
        ph[r] = b2u(hb);
        pl[r] = b2u(f2b(uv - b2f(hb)));
      }
      const int cb = (mi * 16 + quad * 4) * 2;
      ushort4 vh; vh.x = ph[0]; vh.y = ph[1]; vh.z = ph[2]; vh.w = ph[3];
      ushort4 vl; vl.x = pl[0]; vl.y = pl[1]; vl.z = pl[2]; vl.w = pl[3];
      *(ushort4*)swz(UTh, nrow, 128, cb) = vh;
      *(ushort4*)swz(UTl, nrow, 128, cb) = vl;
    }
    __syncthreads();  // (C) UT visible

    // GEMM2: S = lam*S + Khat'^T @ U  (S master in f32 accumulators)
#pragma unroll
    for (int nj = 0; nj < 4; nj++) {
      Sf[nj][0] *= lam; Sf[nj][1] *= lam; Sf[nj][2] *= lam; Sf[nj][3] *= lam;
    }
#pragma unroll
    for (int ks = 0; ks < 2; ++ks) {
      const short8 ak = ks ? ak1 : ak0;
      const int cb = ks * 64 + quad * 16;
#pragma unroll
      for (int nj = 0; nj < 4; nj++) {
        const int nrow = nj * 16 + l15;
        short8 bh = *(const short8*)swzc(UTh, nrow, 128, cb);
        short8 bl = *(const short8*)swzc(UTl, nrow, 128, cb);
        Sf[nj] = __builtin_amdgcn_mfma_f32_16x16x32_bf16(ak, bh, Sf[nj], 0, 0, 0);
        Sf[nj] = __builtin_amdgcn_mfma_f32_16x16x32_bf16(ak, bl, Sf[nj], 0, 0, 0);
      }
    }
    // write S^T hi/lo for next chunk
#pragma unroll
    for (int nj = 0; nj < 4; nj++) {
      const int nrow = nj * 16 + l15;
      unsigned short ph[4], pl[4];
#pragma unroll
      for (int r = 0; r < 4; ++r) {
        float s = Sf[nj][r];
        bf16 hb = f2b(s);
        ph[r] = b2u(hb);
        pl[r] = b2u(f2b(s - b2f(hb)));
      }
      const int cb = (wave * 16 + quad * 4) * 2;
      ushort4 vh; vh.x = ph[0]; vh.y = ph[1]; vh.z = ph[2]; vh.w = ph[3];
      ushort4 vl; vl.x = pl[0]; vl.y = pl[1]; vl.z = pl[2]; vl.w = pl[3];
      *(ushort4*)swz(STh, nrow, 256, cb) = vh;
      *(ushort4*)swz(STl, nrow, 256, cb) = vl;
    }
  }
}

// ---------------- pass2: O = Oinner + Attn@U, fused gated RMSNorm ---------
// 512 threads (8 waves/CU) for latency hiding; same math as 256-thread ver.
__global__ __launch_bounds__(512) void pass2_kernel(
    bf16* UC,                        // U in, normed core out (in-place)
    const bf16* __restrict__ Oin, const bf16* __restrict__ qn,
    const bf16* __restrict__ kn, const float* __restrict__ g_arr,
    const bf16* __restrict__ zbuf, const float* __restrict__ norm_w) {
  const int c = blockIdx.x >> 5, h = blockIdx.x & 31, hk = h >> 1;
  const int t0 = c * 64, tid = threadIdx.x;
  __shared__ float Qf[64][129], Kf[64][129];
  __shared__ float Uf[64][128];
  __shared__ float Of[64][129];
  __shared__ float At[64][65];
  __shared__ float cgs[64], nw[128];

  for (int e = tid; e < 1024; e += 512) {
    int row = e >> 4, s = e & 15;
    size_t qko = ((size_t)(t0 + row) * 16 + hk) * 128 + s * 8;
    size_t uo = ((size_t)(t0 + row) * 32 + h) * 128 + s * 8;
    short8 vq = *(const short8*)(qn + qko);
    short8 vk = *(const short8*)(kn + qko);
    short8 vu = *(const short8*)(UC + uo);
    short8 vo = *(const short8*)(Oin + uo);
    bf16 tq[8], tk[8], tu[8], to[8];
    *(short8*)tq = vq; *(short8*)tk = vk; *(short8*)tu = vu; *(short8*)to = vo;
#pragma unroll
    for (int k = 0; k < 8; ++k) {
      Qf[row][s * 8 + k] = b2f(tq[k]);
      Kf[row][s * 8 + k] = b2f(tk[k]);
      Uf[row][s * 8 + k] = b2f(tu[k]);
      Of[row][s * 8 + k] = b2f(to[k]);
    }
  }
  if (tid < 64) {
    float x = g_arr[(size_t)(t0 + tid) * 32 + h];
#pragma unroll
    for (int off = 1; off < 64; off <<= 1) {
      float o = __shfl_up(x, off, 64);
      if (tid >= off) x += o;
    }
    cgs[tid] = x;
  }
  if (tid < 128) nw[tid] = norm_w[tid];
  __syncthreads();
  // Attn build (includes diagonal): 2 rows x 4 cols per thread
  {
    const int ti = tid >> 4, tj = tid & 15;
    float acc[2][4];
#pragma unroll
    for (int r = 0; r < 2; ++r)
#pragma unroll
      for (int s = 0; s < 4; ++s) acc[r][s] = 0.f;
    for (int dk = 0; dk < 128; ++dk) {
      float a0 = Qf[ti * 2 + 0][dk], a1 = Qf[ti * 2 + 1][dk];
      float c0 = Kf[tj * 4 + 0][dk], c1 = Kf[tj * 4 + 1][dk];
      float c2 = Kf[tj * 4 + 2][dk], c3 = Kf[tj * 4 + 3][dk];
      acc[0][0] += a0 * c0; acc[0][1] += a0 * c1; acc[0][2] += a0 * c2; acc[0][3] += a0 * c3;
      acc[1][0] += a1 * c0; acc[1][1] += a1 * c1; acc[1][2] += a1 * c2; acc[1][3] += a1 * c3;
    }
#pragma unroll
    for (int r = 0; r < 2; ++r)
#pragma unroll
      for (int s = 0; s < 4; ++s) {
        int i = ti * 2 + r, j = tj * 4 + s;
        At[i][j] = (j <= i) ? expf(cgs[i] - cgs[j]) * acc[r][s] : 0.f;
      }
  }
  __syncthreads();
  // O += Attn @ U: 2 rows x 8 cols per thread
  {
    const int ri = tid >> 4, tn = tid & 15;
    float acc[2][8];
#pragma unroll
    for (int r = 0; r < 2; ++r)
#pragma unroll
      for (int k = 0; k < 8; ++k) acc[r][k] = 0.f;
    for (int j = 0; j < 64; ++j) {
      float a0 = At[ri * 2 + 0][j], a1 = At[ri * 2 + 1][j];
#pragma unroll
      for (int k = 0; k < 8; ++k) {
        float u = Uf[j][tn + 16 * k];
        acc[0][k] += a0 * u;
        acc[1][k] += a1 * u;
      }
    }
#pragma unroll
    for (int r = 0; r < 2; ++r)
#pragma unroll
      for (int k = 0; k < 8; ++k)
        Of[ri * 2 + r][tn + 16 * k] += acc[r][k];
  }
  __syncthreads();
  // gated RMSNorm + store: 8 lanes per row
  {
    const int r = tid >> 3, q8 = tid & 7;
    float ss = 0.f;
#pragma unroll
    for (int k = 0; k < 16; ++k) {
      float v = Of[r][q8 + 8 * k];
      ss += v * v;
    }
    ss += __shfl_xor(ss, 1, 64);
    ss += __shfl_xor(ss, 2, 64);
    ss += __shfl_xor(ss, 4, 64);
    float scale = rsqrtf(ss * (1.f / 128.f) + EPS_);
#pragma unroll
    for (int k = 0; k < 16; ++k) {
      int n = q8 + 8 * k;
      float val = Of[r][n] * scale * nw[n];
      float zz = b2f(zbuf[(size_t)(t0 + r) * 4096 + h * 128 + n]);
      val *= zz / (1.f + expf(-zz));
      UC[((size_t)(t0 + r) * 32 + h) * 128 + n] = f2b(val);
    }
  }
}

extern "C" void kernel_launch(void* const* d_in, const int* in_sizes, int n_in,
                              void* d_out, int out_size, void* d_ws,
                              size_t ws_size, hipStream_t stream) {
  const float* hidden = (const float*)d_in[0];
  const float* in_w = (const float*)d_in[1];
  const float* conv_w = (const float*)d_in[2];
  const float* A_log = (const float*)d_in[3];
  const float* dt_bias = (const float*)d_in[4];
  const float* norm_w = (const float*)d_in[5];
  const float* out_w = (const float*)d_in[6];
  float* out = (float*)d_out;

  // workspace layout: total 169,345,024 B (proven size)
  char* p = (char*)d_ws;
  bf16* projA = (bf16*)p;                         // 67,633,152 [4096][8256]
  bf16* TV = (bf16*)p;                            // alias: TV -> U -> core
  bf16* TK = (bf16*)(p + 33554432ULL);            // alias upper half of projA
  p += 67633152ULL;
  bf16* zbuf = (bf16*)p; p += 33554432ULL;        // [4096][32][128]
  bf16* vbuf = (bf16*)p; p += 33554432ULL;        // V, then Oinner
  float* beta = (float*)p; p += 524288ULL;
  float* g = (float*)p; p += 524288ULL;
  bf16* qn = (bf16*)p; p += 16777216ULL;
  bf16* kn = (bf16*)p;                            // 16,777,216
  bf16* hb16 = qn;  // aliases qn region; dead before conv_norm_qk writes qn

  // 0. hidden fp32 -> bf16
  cvt_bf16<<<(L_SEQ * HDIM) / 1024, 256, 0, stream>>>(hidden, hb16);
  // 1a. in_proj GEMM, packed q|k|v|ba columns
  gemm_mfma<true, 1><<<dim3(65, 32), 256, 0, stream>>>(hb16, in_w, projA, L_SEQ,
                                                       NPROJA, HDIM, WLD);
  // 1b. in_proj GEMM, z columns -> zbuf
  gemm_mfma<true, 2><<<dim3(32, 32), 256, 0, stream>>>(hb16, in_w, zbuf, L_SEQ,
                                                       4096, HDIM, WLD);
  // 2. fused conv + silu + l2norm for q,k
  conv_norm_qk<<<L_SEQ * 16, 128, 0, stream>>>(projA, conv_w, qn, kn);
  // 3. conv + silu for v
  conv_silu_v<<<(L_SEQ * 4096) / 256, 256, 0, stream>>>(projA, conv_w, vbuf);
  // 4. beta / g
  compute_bg<<<(L_SEQ * 32) / 256, 256, 0, stream>>>(projA, A_log, dt_bias,
                                                     beta, g);
  // 5. chunked WY precompute (projA dead -> TV/TK overwrite it)
  precompute_chunk<<<2048, 512, 0, stream>>>(kn, vbuf, g, beta, TV, TK);
  // 6. sequential inter-chunk recurrence (TV->U in place, Oinner->vbuf)
  seq_kernel<<<64, 512, 0, stream>>>(TV, TK, qn, kn, g, vbuf);
  // 7. intra-chunk attention + gated RMSNorm (U->core in place)
  pass2_kernel<<<2048, 512, 0, stream>>>(TV, vbuf, qn, kn, g, zbuf, norm_w);
  // 8. out_proj GEMM
  gemm_mfma<false, 0><<<dim3(16, 32), 256, 0, stream>>>(TV, out_w, out, L_SEQ,
                                                        2048, 4096, 2048);
}

// Round 4
// 1455.970 us; speedup vs baseline: 5.6913x; 1.1290x over previous
//
#include <hip/hip_runtime.h>
#include <hip/hip_bf16.h>

#define L_SEQ 4096
#define HDIM 2048
#define NPROJA 8256      // packed q(2048) k(2048) v(4096) ba(64)
#define NPACK 12352      // packed incl z: q|k|v|ba|z
#define WLD 12352        // row stride of in_proj_w
#define EPS_ 1e-6f

using bf16 = __hip_bfloat16;
typedef __attribute__((ext_vector_type(8))) short short8;
typedef __attribute__((ext_vector_type(4))) float f32x4;

__device__ __forceinline__ float b2f(bf16 x) { return __bfloat162float(x); }
__device__ __forceinline__ bf16 f2b(float x) { return __float2bfloat16(x); }
__device__ __forceinline__ unsigned short b2u(bf16 x) {
  union { bf16 b; unsigned short u; } c; c.b = x; return c.u;
}
// XOR-swizzled LDS addressing keyed on row&7 (for 256B/128B-row MFMA tiles)
__device__ __forceinline__ void* swz(void* base, int row, int rowbytes, int colbyte) {
  return (void*)((char*)base + row * rowbytes + (colbyte ^ ((row & 7) << 4)));
}
__device__ __forceinline__ const void* swzc(const void* base, int row, int rowbytes, int colbyte) {
  return (const void*)((const char*)base + row * rowbytes + (colbyte ^ ((row & 7) << 4)));
}
// KhT swizzle: key on (row>>3)&7 (lane-varying) to spread transpose writes
__device__ __forceinline__ void* swzk(void* base, int row, int colbyte) {
  return (void*)((char*)base + row * 128 + (colbyte ^ (((row >> 3) & 7) << 4)));
}
__device__ __forceinline__ const void* swzkc(const void* base, int row, int colbyte) {
  return (const void*)((const char*)base + row * 128 + (colbyte ^ (((row >> 3) & 7) << 4)));
}

__device__ __forceinline__ void async_copy16(const void* g, void* l) {
  __builtin_amdgcn_global_load_lds(
      (const __attribute__((address_space(1))) void*)g,
      (__attribute__((address_space(3))) void*)l, 16, 0, 0);
}

// ---------------- fp32 -> bf16 convert (linear) ---------------------------
__global__ __launch_bounds__(256) void cvt_bf16(const float* __restrict__ in,
                                                bf16* __restrict__ outp) {
  int i = (blockIdx.x * 256 + threadIdx.x) * 4;
  float4 v = *(const float4*)&in[i];
  bf16 o4[4] = {f2b(v.x), f2b(v.y), f2b(v.z), f2b(v.w)};
  *(ushort4*)&outp[i] = *(ushort4*)o4;
}

// -------- packed-column map: n(packed) -> source col of in_proj_w ---------
// pieces (q:128-blocks, k:128-blocks, v:256-blocks, ba:64, z:256-blocks) are
// all >=64 wide and 64-aligned, so any 64-aligned tile is source-contiguous.
template <int MODE>
__device__ __forceinline__ int pmap(int n) {
  if constexpr (MODE == 3) {
    if (n < 2048) return (n >> 7) * 768 + (n & 127);
    else if (n < 4096) { int m = n - 2048; return (m >> 7) * 768 + 128 + (m & 127); }
    else if (n < 8192) { int m = n - 4096; return (m >> 8) * 768 + 256 + (m & 255); }
    else if (n < 8256) return 12288 + (n - 8192);
    else { int m = n - 8256; return (m >> 8) * 768 + 512 + (m & 255); }
  } else {
    return n;
  }
}

// -------- weight transpose+convert: Bt[n][k] = bf16(W[k][pmap(n)]) --------
// 64x64 tiles via LDS; read coalesced along source cols, write along k.
template <int MODE>
__global__ __launch_bounds__(256) void transpose_w(
    const float* __restrict__ W, bf16* __restrict__ Bt, int ldw, int Kd) {
  __shared__ float T[64][65];
  const int nb = blockIdx.x * 64, kb = blockIdx.y * 64;
  const int tid = threadIdx.x;
  const int c = tid & 63, gq = tid >> 6;
  const int sbase = pmap<MODE>(nb);
#pragma unroll
  for (int i = 0; i < 16; ++i) {
    int r = gq * 16 + i;
    T[c][r] = W[(size_t)(kb + r) * ldw + sbase + c];
  }
  __syncthreads();
#pragma unroll
  for (int i = 0; i < 16; ++i) {
    int n = gq * 16 + i;
    Bt[(size_t)(nb + n) * Kd + kb + c] = f2b(T[n][c]);
  }
}

// ---------------- MFMA bf16 GEMM, both operands K-major (m97-style) -------
// A[M][Kd], Bt[N][Kd] (= B^T), both staged via global_load_lds width-16.
// ROUTE 0: C fp32 [M][N]. ROUTE 1: split bf16 projA(8256) / zbuf(4096).
template <int ROUTE>
__global__ __launch_bounds__(256) void gemm_bt(
    const bf16* __restrict__ A, const bf16* __restrict__ Bt,
    void* __restrict__ Cp, bf16* __restrict__ Cz, int N, int Kd) {
  __shared__ bf16 As[128 * 32];
  __shared__ bf16 Bs[128 * 32];
  const int tid = threadIdx.x;
  const int wave = tid >> 6, lane = tid & 63;
  const int l15 = lane & 15, quad = lane >> 4;
  const int m0 = blockIdx.y * 128, n0 = blockIdx.x * 128;
  const int mw = (wave >> 1) * 64, nw = (wave & 1) * 64;

  f32x4 acc[4][4];
#pragma unroll
  for (int i = 0; i < 4; i++)
#pragma unroll
    for (int j = 0; j < 4; j++) acc[i][j] = {0.f, 0.f, 0.f, 0.f};

  // staging: chunk = tid (+256); row = chunk>>2, k8 = chunk&3 (16B each)
  const bf16* a_src0 = A + (size_t)(m0 + (tid >> 2)) * Kd + (tid & 3) * 8;
  const bf16* a_src1 = a_src0 + (size_t)64 * Kd;
  const bf16* b_src0 = Bt + (size_t)(n0 + (tid >> 2)) * Kd + (tid & 3) * 8;
  const bf16* b_src1 = b_src0 + (size_t)64 * Kd;
  bf16* a_dst0 = &As[tid * 8];
  bf16* a_dst1 = &As[(tid + 256) * 8];
  bf16* b_dst0 = &Bs[tid * 8];
  bf16* b_dst1 = &Bs[(tid + 256) * 8];

  for (int k0 = 0; k0 < Kd; k0 += 32) {
    __syncthreads();  // previous iteration's frag reads done
    async_copy16(a_src0 + k0, a_dst0);
    async_copy16(a_src1 + k0, a_dst1);
    async_copy16(b_src0 + k0, b_dst0);
    async_copy16(b_src1 + k0, b_dst1);
    __syncthreads();  // staged data visible (compiler drains vmcnt)

    short8 af[4], bfr[4];
#pragma unroll
    for (int i = 0; i < 4; i++)
      af[i] = *(const short8*)&As[(mw + i * 16 + l15) * 32 + quad * 8];
#pragma unroll
    for (int j = 0; j < 4; j++)
      bfr[j] = *(const short8*)&Bs[(nw + j * 16 + l15) * 32 + quad * 8];
#pragma unroll
    for (int i = 0; i < 4; i++)
#pragma unroll
      for (int j = 0; j < 4; j++)
        acc[i][j] = __builtin_amdgcn_mfma_f32_16x16x32_bf16(af[i], bfr[j],
                                                            acc[i][j], 0, 0, 0);
  }

#pragma unroll
  for (int i = 0; i < 4; i++) {
#pragma unroll
    for (int j = 0; j < 4; j++) {
      int col = n0 + nw + j * 16 + l15;
      if (col < N) {
#pragma unroll
        for (int r = 0; r < 4; r++) {
          int row = m0 + mw + i * 16 + quad * 4 + r;
          if (ROUTE == 0) {
            ((float*)Cp)[(size_t)row * N + col] = acc[i][j][r];
          } else {
            if (col < NPROJA)
              ((bf16*)Cp)[(size_t)row * NPROJA + col] = f2b(acc[i][j][r]);
            else
              Cz[(size_t)row * 4096 + (col - NPROJA)] = f2b(acc[i][j][r]);
          }
        }
      }
    }
  }
}

// ------- fused conv(K=4 causal) + SiLU + l2norm for q and k ---------------
__global__ __launch_bounds__(128) void conv_norm_qk(
    const bf16* __restrict__ proj, const float* __restrict__ conv_w,
    bf16* __restrict__ qn, bf16* __restrict__ kn) {
  const int t = blockIdx.x >> 4, hk = blockIdx.x & 15;
  const int d = threadIdx.x;
  const int cq = hk * 128 + d;
  const int ck = 2048 + hk * 128 + d;
  float sq = 0.f, sk = 0.f;
#pragma unroll
  for (int j = 0; j < 4; j++) {
    int ts = t + j - 3;
    if (ts >= 0) {
      sq += conv_w[cq * 4 + j] * b2f(proj[(size_t)ts * NPROJA + cq]);
      sk += conv_w[ck * 4 + j] * b2f(proj[(size_t)ts * NPROJA + ck]);
    }
  }
  float qv = sq / (1.f + expf(-sq));
  float kv = sk / (1.f + expf(-sk));
  float ssq = qv * qv, ssk = kv * kv;
#pragma unroll
  for (int off = 32; off > 0; off >>= 1) {
    ssq += __shfl_down(ssq, off, 64);
    ssk += __shfl_down(ssk, off, 64);
  }
  __shared__ float red[4];
  if ((d & 63) == 0) {
    red[(d >> 6) * 2] = ssq;
    red[(d >> 6) * 2 + 1] = ssk;
  }
  __syncthreads();
  float sumq = red[0] + red[2];
  float sumk = red[1] + red[3];
  size_t o = (size_t)(t * 16 + hk) * 128 + d;
  qn[o] = f2b(qv * rsqrtf(sumq + EPS_) * 0.08838834764831845f);
  kn[o] = f2b(kv * rsqrtf(sumk + EPS_));
}

// ------- conv + SiLU for v channels ---------------------------------------
__global__ __launch_bounds__(256) void conv_silu_v(
    const bf16* __restrict__ proj, const float* __restrict__ conv_w,
    bf16* __restrict__ vbuf) {
  int idx = blockIdx.x * 256 + threadIdx.x;
  int t = idx >> 12, c = idx & 4095;
  int chan = 4096 + c;
  float s = 0.f;
#pragma unroll
  for (int j = 0; j < 4; j++) {
    int ts = t + j - 3;
    if (ts >= 0) s += conv_w[chan * 4 + j] * b2f(proj[(size_t)ts * NPROJA + chan]);
  }
  vbuf[idx] = f2b(s / (1.f + expf(-s)));
}

// ---------------- beta / g ------------------------------------------------
__global__ __launch_bounds__(256) void compute_bg(
    const bf16* __restrict__ proj, const float* __restrict__ A_log,
    const float* __restrict__ dt_bias, float* __restrict__ beta_arr,
    float* __restrict__ g_arr) {
  int idx = blockIdx.x * 256 + threadIdx.x;
  int t = idx >> 5, hv = idx & 31;
  size_t base = (size_t)t * NPROJA + 8192 + (hv >> 1) * 4 + (hv & 1);
  float b = b2f(proj[base]);
  float a = b2f(proj[base + 2]);
  beta_arr[idx] = 1.f / (1.f + expf(-b));
  float x = a + dt_bias[hv];
  float sp = (x > 20.f) ? x : log1pf(expf(x));
  g_arr[idx] = -expf(A_log[hv]) * sp;
}

// ---------------- chunked WY precompute (512 threads: 8 waves/CU) ---------
__global__ __launch_bounds__(512) void precompute_chunk(
    const bf16* __restrict__ kn, const bf16* __restrict__ vbuf,
    const float* __restrict__ g_arr, const float* __restrict__ beta_arr,
    bf16* __restrict__ TV, bf16* __restrict__ TK) {
  const int c = blockIdx.x >> 5, h = blockIdx.x & 31, hk = h >> 1;
  const int t0 = c * 64, tid = threadIdx.x;
  __shared__ float Kf[64][129];
  __shared__ float X[64][256];
  __shared__ float BA[64][64];
  __shared__ float cgs[64], bet[64], eKs[64];

  for (int e = tid; e < 1024; e += 512) {
    int row = e >> 4, s = e & 15;
    short8 v = *(const short8*)(kn + ((size_t)(t0 + row) * 16 + hk) * 128 + s * 8);
    bf16 tmp[8];
    *(short8*)tmp = v;
#pragma unroll
    for (int k = 0; k < 8; ++k) Kf[row][s * 8 + k] = b2f(tmp[k]);
  }
  if (tid < 64) {
    float bb = beta_arr[(size_t)(t0 + tid) * 32 + h];
    bet[tid] = bb;
    float x = g_arr[(size_t)(t0 + tid) * 32 + h];
#pragma unroll
    for (int off = 1; off < 64; off <<= 1) {
      float o = __shfl_up(x, off, 64);
      if (tid >= off) x += o;
    }
    cgs[tid] = x;
    eKs[tid] = bb * expf(x);
  }
  __syncthreads();
  // X init = diag(beta) [V | Ktilde]
  for (int e = tid; e < 8192; e += 512) {
    int i = e >> 7, d = e & 127;
    X[i][d] = bet[i] * b2f(vbuf[(size_t)(t0 + i) * 4096 + h * 128 + d]);
    X[i][128 + d] = eKs[i] * Kf[i][d];
  }
  // BA[i][j] = beta_i * exp(cg_i - cg_j) * (k_i . k_j), strictly lower
  {
    const int ti = tid >> 4, tj = tid & 15;
    float acc[2][4];
#pragma unroll
    for (int r = 0; r < 2; ++r)
#pragma unroll
      for (int s = 0; s < 4; ++s) acc[r][s] = 0.f;
    for (int dk = 0; dk < 128; ++dk) {
      float a0 = Kf[ti * 2 + 0][dk], a1 = Kf[ti * 2 + 1][dk];
      float c0 = Kf[tj * 4 + 0][dk], c1 = Kf[tj * 4 + 1][dk];
      float c2 = Kf[tj * 4 + 2][dk], c3 = Kf[tj * 4 + 3][dk];
      acc[0][0] += a0 * c0; acc[0][1] += a0 * c1; acc[0][2] += a0 * c2; acc[0][3] += a0 * c3;
      acc[1][0] += a1 * c0; acc[1][1] += a1 * c1; acc[1][2] += a1 * c2; acc[1][3] += a1 * c3;
    }
#pragma unroll
    for (int r = 0; r < 2; ++r)
#pragma unroll
      for (int s = 0; s < 4; ++s) {
        int i = ti * 2 + r, j = tj * 4 + s;
        BA[i][j] = (j < i) ? bet[i] * expf(cgs[i] - cgs[j]) * acc[r][s] : 0.f;
      }
  }
  __syncthreads();
  // forward substitution: thread owns column (256 cols; waves 4-7 idle here)
  if (tid < 256) {
    const int d = tid;
    for (int i = 1; i < 64; ++i) {
      const float* bar = BA[i];
      float s0 = 0.f, s1 = 0.f;
      int j = 0;
      for (; j + 1 < i; j += 2) {
        s0 += bar[j] * X[j][d];
        s1 += bar[j + 1] * X[j + 1][d];
      }
      if (j < i) s0 += bar[j] * X[j][d];
      X[i][d] -= s0 + s1;
    }
  }
  __syncthreads();
  for (int e = tid; e < 8192; e += 512) {
    int i = e >> 7, d = e & 127;
    size_t o = ((size_t)(t0 + i) * 32 + h) * 128 + d;
    TV[o] = f2b(X[i][d]);
    TK[o] = f2b(X[i][128 + d]);
  }
}

// ---------------- sequential inter-chunk recurrence (MFMA, hi/lo S) -------
__global__ __launch_bounds__(512) void seq_kernel(
    bf16* TVU,                       // [4096][32][128]: TV in, U out (in-place)
    const bf16* __restrict__ TKg, const bf16* __restrict__ qn,
    const bf16* __restrict__ kn, const float* __restrict__ g_arr,
    bf16* __restrict__ Oin) {        // vbuf reused: Oinner out
  const int h = blockIdx.x >> 1, dvh = blockIdx.x & 1, hk = h >> 1;
  const int dv0 = dvh * 64;
  const int tid = threadIdx.x;
  const int wave = tid >> 6, lane = tid & 63, l15 = lane & 15, quad = lane >> 4;
  const int mi = wave >> 1, half = wave & 1;
  const int srow = tid >> 4, scol = tid & 15;

  __shared__ bf16 STh[64 * 128], STl[64 * 128];  // S^T [dv][dk] hi/lo
  __shared__ bf16 UTh[64 * 64], UTl[64 * 64];    // U^T [dv][i]  hi/lo
  __shared__ bf16 TKs[64 * 128];                 // TK [i][dk]
  __shared__ bf16 Qts[64 * 128];                 // Qtilde [i][dk]
  __shared__ bf16 KhT[128 * 64];                 // Khat'^T [dk][i] (swzk)

  for (int e = tid; e < 4096; e += 512) {
    ((unsigned int*)STh)[e] = 0u;
    ((unsigned int*)STl)[e] = 0u;
  }
  f32x4 Sf[4];
#pragma unroll
  for (int i = 0; i < 4; i++) Sf[i] = {0.f, 0.f, 0.f, 0.f};

  short8 tkr0, tkr1, qr0, qr1, kr0, kr1;
  float gv;
  auto issue_loads = [&](int c) {
    const size_t t0 = (size_t)c << 6;
    tkr0 = *(const short8*)(TKg + ((t0 + srow) * 32 + h) * 128 + scol * 8);
    tkr1 = *(const short8*)(TKg + ((t0 + 32 + srow) * 32 + h) * 128 + scol * 8);
    qr0 = *(const short8*)(qn + ((t0 + srow) * 16 + hk) * 128 + scol * 8);
    qr1 = *(const short8*)(qn + ((t0 + 32 + srow) * 16 + hk) * 128 + scol * 8);
    kr0 = *(const short8*)(kn + ((t0 + srow) * 16 + hk) * 128 + scol * 8);
    kr1 = *(const short8*)(kn + ((t0 + 32 + srow) * 16 + hk) * 128 + scol * 8);
    gv = g_arr[(t0 + lane) * 32 + h];
  };
  issue_loads(0);

  for (int c = 0; c < 64; ++c) {
    const int t0 = c << 6;
    __syncthreads();  // (A) prev-chunk GEMM reads done; staging buffers free

    // TV prefetch (consumed in U-phase)
    bf16 tvp[2][4];
#pragma unroll
    for (int nj = 0; nj < 2; nj++) {
      const int nrow = half * 32 + nj * 16 + l15;
#pragma unroll
      for (int r = 0; r < 4; r++) {
        const int i = mi * 16 + quad * 4 + r;
        tvp[nj][r] = TVU[((size_t)(t0 + i) * 32 + h) * 128 + dv0 + nrow];
      }
    }
    // all-wave chunk-local cumulative-g scan (lane = chunk row)
    float cg = gv;
#pragma unroll
    for (int off = 1; off < 64; off <<= 1) {
      float o = __shfl_up(cg, off, 64);
      if (lane >= off) cg += o;
    }
    const float cg63 = __shfl(cg, 63, 64);
    const float lam = expf(cg63);
    const float fq = expf(cg);
    const float fk = expf(cg63 - cg);
    // stage TK (vectorized)
    *(short8*)swz(TKs, srow, 256, scol * 16) = tkr0;
    *(short8*)swz(TKs, srow + 32, 256, scol * 16) = tkr1;
    // stage Qtilde = q * fq[row]
    {
      const float f0 = __shfl(fq, srow, 64);
      const float f1 = __shfl(fq, srow + 32, 64);
      bf16 ta[8], tb[8];
      *(short8*)ta = qr0;
      *(short8*)tb = qr1;
#pragma unroll
      for (int k = 0; k < 8; k++) {
        ta[k] = f2b(b2f(ta[k]) * f0);
        tb[k] = f2b(b2f(tb[k]) * f1);
      }
      *(short8*)swz(Qts, srow, 256, scol * 16) = *(short8*)ta;
      *(short8*)swz(Qts, srow + 32, 256, scol * 16) = *(short8*)tb;
    }
    // stage Khat'^T = (k * fk[row])^T, scalar writes spread via swzk
    {
      const float f0 = __shfl(fk, srow, 64);
      const float f1 = __shfl(fk, srow + 32, 64);
      bf16 ka[8], kb[8];
      *(short8*)ka = kr0;
      *(short8*)kb = kr1;
#pragma unroll
      for (int k = 0; k < 8; k++) {
        const int dk = scol * 8 + k;
        *(bf16*)swzk(KhT, dk, srow * 2) = f2b(b2f(ka[k]) * f0);
        *(bf16*)swzk(KhT, dk, (srow + 32) * 2) = f2b(b2f(kb[k]) * f1);
      }
    }
    // T14: issue next-chunk global loads now (fly during GEMM phases)
    issue_loads(c + 1 < 64 ? c + 1 : 63);
    __syncthreads();  // (B) operands staged

    // GEMM3 (Oinner = Qtilde@S) + GEMM1 (x = TK@S) fused over shared B reads
    f32x4 oacc[2], xacc[2];
#pragma unroll
    for (int nj = 0; nj < 2; nj++) { oacc[nj] = {0.f,0.f,0.f,0.f}; xacc[nj] = {0.f,0.f,0.f,0.f}; }
    const int arow = mi * 16 + l15;
#pragma unroll
    for (int ks = 0; ks < 4; ++ks) {
      const int cb = ks * 64 + quad * 16;
      short8 aq = *(const short8*)swzc(Qts, arow, 256, cb);
      short8 at = *(const short8*)swzc(TKs, arow, 256, cb);
#pragma unroll
      for (int nj = 0; nj < 2; nj++) {
        const int nrow = half * 32 + nj * 16 + l15;
        short8 bh = *(const short8*)swzc(STh, nrow, 256, cb);
        short8 bl = *(const short8*)swzc(STl, nrow, 256, cb);
        oacc[nj] = __builtin_amdgcn_mfma_f32_16x16x32_bf16(aq, bh, oacc[nj], 0, 0, 0);
        xacc[nj] = __builtin_amdgcn_mfma_f32_16x16x32_bf16(at, bh, xacc[nj], 0, 0, 0);
        xacc[nj] = __builtin_amdgcn_mfma_f32_16x16x32_bf16(at, bl, xacc[nj], 0, 0, 0);
      }
    }
    // hoist KhT A-fragments into regs
    const int krow = wave * 16 + l15;
    short8 ak0 = *(const short8*)swzkc(KhT, krow, 0 * 64 + quad * 16);
    short8 ak1 = *(const short8*)swzkc(KhT, krow, 1 * 64 + quad * 16);

    // U phase: U = TV - x; write Oinner + U(global) + U^T hi/lo (LDS)
#pragma unroll
    for (int nj = 0; nj < 2; nj++) {
      const int nrow = half * 32 + nj * 16 + l15;
      unsigned short ph[4], pl[4];
#pragma unroll
      for (int r = 0; r < 4; ++r) {
        const int i = mi * 16 + quad * 4 + r;
        const size_t go = ((size_t)(t0 + i) * 32 + h) * 128 + dv0 + nrow;
        Oin[go] = f2b(oacc[nj][r]);
        float uv = b2f(tvp[nj][r]) - xacc[nj][r];
        bf16 hb = f2b(uv);
        TVU[go] = hb;
        ph[r] = b2u(hb);
        pl[r] = b2u(f2b(uv - b2f(hb)));
      }
      const int cb = (mi * 16 + quad * 4) * 2;
      ushort4 vh; vh.x = ph[0]; vh.y = ph[1]; vh.z = ph[2]; vh.w = ph[3];
      ushort4 vl; vl.x = pl[0]; vl.y = pl[1]; vl.z = pl[2]; vl.w = pl[3];
      *(ushort4*)swz(UTh, nrow, 128, cb) = vh;
      *(ushort4*)swz(UTl, nrow, 128, cb) = vl;
    }
    __syncthreads();  // (C) UT visible

    // GEMM2: S = lam*S + Khat'^T @ U  (S master in f32 accumulators)
#pragma unroll
    for (int nj = 0; nj < 4; nj++) {
      Sf[nj][0] *= lam; Sf[nj][1] *= lam; Sf[nj][2] *= lam; Sf[nj][3] *= lam;
    }
#pragma unroll
    for (int ks = 0; ks < 2; ++ks) {
      const short8 ak = ks ? ak1 : ak0;
      const int cb = ks * 64 + quad * 16;
#pragma unroll
      for (int nj = 0; nj < 4; nj++) {
        const int nrow = nj * 16 + l15;
        short8 bh = *(const short8*)swzc(UTh, nrow, 128, cb);
        short8 bl = *(const short8*)swzc(UTl, nrow, 128, cb);
        Sf[nj] = __builtin_amdgcn_mfma_f32_16x16x32_bf16(ak, bh, Sf[nj], 0, 0, 0);
        Sf[nj] = __builtin_amdgcn_mfma_f32_16x16x32_bf16(ak, bl, Sf[nj], 0, 0, 0);
      }
    }
    // write S^T hi/lo for next chunk
#pragma unroll
    for (int nj = 0; nj < 4; nj++) {
      const int nrow = nj * 16 + l15;
      unsigned short ph[4], pl[4];
#pragma unroll
      for (int r = 0; r < 4; ++r) {
        float s = Sf[nj][r];
        bf16 hb = f2b(s);
        ph[r] = b2u(hb);
        pl[r] = b2u(f2b(s - b2f(hb)));
      }
      const int cb = (wave * 16 + quad * 4) * 2;
      ushort4 vh; vh.x = ph[0]; vh.y = ph[1]; vh.z = ph[2]; vh.w = ph[3];
      ushort4 vl; vl.x = pl[0]; vl.y = pl[1]; vl.z = pl[2]; vl.w = pl[3];
      *(ushort4*)swz(STh, nrow, 256, cb) = vh;
      *(ushort4*)swz(STl, nrow, 256, cb) = vl;
    }
  }
}

// ---------------- pass2: O = Oinner + Attn@U, fused gated RMSNorm ---------
__global__ __launch_bounds__(512) void pass2_kernel(
    bf16* UC,                        // U in, normed core out (in-place)
    const bf16* __restrict__ Oin, const bf16* __restrict__ qn,
    const bf16* __restrict__ kn, const float* __restrict__ g_arr,
    const bf16* __restrict__ zbuf, const float* __restrict__ norm_w) {
  const int c = blockIdx.x >> 5, h = blockIdx.x & 31, hk = h >> 1;
  const int t0 = c * 64, tid = threadIdx.x;
  __shared__ float Qf[64][129], Kf[64][129];
  __shared__ float Uf[64][128];
  __shared__ float Of[64][129];
  __shared__ float At[64][65];
  __shared__ float cgs[64], nw[128];

  for (int e = tid; e < 1024; e += 512) {
    int row = e >> 4, s = e & 15;
    size_t qko = ((size_t)(t0 + row) * 16 + hk) * 128 + s * 8;
    size_t uo = ((size_t)(t0 + row) * 32 + h) * 128 + s * 8;
    short8 vq = *(const short8*)(qn + qko);
    short8 vk = *(const short8*)(kn + qko);
    short8 vu = *(const short8*)(UC + uo);
    short8 vo = *(const short8*)(Oin + uo);
    bf16 tq[8], tk[8], tu[8], to[8];
    *(short8*)tq = vq; *(short8*)tk = vk; *(short8*)tu = vu; *(short8*)to = vo;
#pragma unroll
    for (int k = 0; k < 8; ++k) {
      Qf[row][s * 8 + k] = b2f(tq[k]);
      Kf[row][s * 8 + k] = b2f(tk[k]);
      Uf[row][s * 8 + k] = b2f(tu[k]);
      Of[row][s * 8 + k] = b2f(to[k]);
    }
  }
  if (tid < 64) {
    float x = g_arr[(size_t)(t0 + tid) * 32 + h];
#pragma unroll
    for (int off = 1; off < 64; off <<= 1) {
      float o = __shfl_up(x, off, 64);
      if (tid >= off) x += o;
    }
    cgs[tid] = x;
  }
  if (tid < 128) nw[tid] = norm_w[tid];
  __syncthreads();
  // Attn build (includes diagonal): 2 rows x 4 cols per thread
  {
    const int ti = tid >> 4, tj = tid & 15;
    float acc[2][4];
#pragma unroll
    for (int r = 0; r < 2; ++r)
#pragma unroll
      for (int s = 0; s < 4; ++s) acc[r][s] = 0.f;
    for (int dk = 0; dk < 128; ++dk) {
      float a0 = Qf[ti * 2 + 0][dk], a1 = Qf[ti * 2 + 1][dk];
      float c0 = Kf[tj * 4 + 0][dk], c1 = Kf[tj * 4 + 1][dk];
      float c2 = Kf[tj * 4 + 2][dk], c3 = Kf[tj * 4 + 3][dk];
      acc[0][0] += a0 * c0; acc[0][1] += a0 * c1; acc[0][2] += a0 * c2; acc[0][3] += a0 * c3;
      acc[1][0] += a1 * c0; acc[1][1] += a1 * c1; acc[1][2] += a1 * c2; acc[1][3] += a1 * c3;
    }
#pragma unroll
    for (int r = 0; r < 2; ++r)
#pragma unroll
      for (int s = 0; s < 4; ++s) {
        int i = ti * 2 + r, j = tj * 4 + s;
        At[i][j] = (j <= i) ? expf(cgs[i] - cgs[j]) * acc[r][s] : 0.f;
      }
  }
  __syncthreads();
  // O += Attn @ U: 2 rows x 8 cols per thread
  {
    const int ri = tid >> 4, tn = tid & 15;
    float acc[2][8];
#pragma unroll
    for (int r = 0; r < 2; ++r)
#pragma unroll
      for (int k = 0; k < 8; ++k) acc[r][k] = 0.f;
    for (int j = 0; j < 64; ++j) {
      float a0 = At[ri * 2 + 0][j], a1 = At[ri * 2 + 1][j];
#pragma unroll
      for (int k = 0; k < 8; ++k) {
        float u = Uf[j][tn + 16 * k];
        acc[0][k] += a0 * u;
        acc[1][k] += a1 * u;
      }
    }
#pragma unroll
    for (int r = 0; r < 2; ++r)
#pragma unroll
      for (int k = 0; k < 8; ++k)
        Of[ri * 2 + r][tn + 16 * k] += acc[r][k];
  }
  __syncthreads();
  // gated RMSNorm + store: 8 lanes per row
  {
    const int r = tid >> 3, q8 = tid & 7;
    float ss = 0.f;
#pragma unroll
    for (int k = 0; k < 16; ++k) {
      float v = Of[r][q8 + 8 * k];
      ss += v * v;
    }
    ss += __shfl_xor(ss, 1, 64);
    ss += __shfl_xor(ss, 2, 64);
    ss += __shfl_xor(ss, 4, 64);
    float scale = rsqrtf(ss * (1.f / 128.f) + EPS_);
#pragma unroll
    for (int k = 0; k < 16; ++k) {
      int n = q8 + 8 * k;
      float val = Of[r][n] * scale * nw[n];
      float zz = b2f(zbuf[(size_t)(t0 + r) * 4096 + h * 128 + n]);
      val *= zz / (1.f + expf(-zz));
      UC[((size_t)(t0 + r) * 32 + h) * 128 + n] = f2b(val);
    }
  }
}

extern "C" void kernel_launch(void* const* d_in, const int* in_sizes, int n_in,
                              void* d_out, int out_size, void* d_ws,
                              size_t ws_size, hipStream_t stream) {
  const float* hidden = (const float*)d_in[0];
  const float* in_w = (const float*)d_in[1];
  const float* conv_w = (const float*)d_in[2];
  const float* A_log = (const float*)d_in[3];
  const float* dt_bias = (const float*)d_in[4];
  const float* norm_w = (const float*)d_in[5];
  const float* out_w = (const float*)d_in[6];
  float* out = (float*)d_out;

  // workspace layout: total 169,345,024 B (proven size)
  // phase A (proj): [projA 67.6M][zbuf 33.6M][Bt_in 50.7M][hb16 16.8M] = 168.6M
  // phase B (core): [projA/TV|TK][zbuf][vbuf][beta][g][qn][kn]
  // phase C (out) : Bt_out reuses zbuf (dead after pass2)
  char* p = (char*)d_ws;
  bf16* projA = (bf16*)p;                          // 67,633,152 [4096][8256]
  bf16* TV = (bf16*)p;                             // alias: TV -> U -> core
  bf16* TK = (bf16*)(p + 33554432ULL);
  bf16* zbuf = (bf16*)(p + 67633152ULL);           // 33,554,432 [4096][32][128]
  char* pR = p + 101187584ULL;                     // tail region, 68,157,440 B
  bf16* vbuf = (bf16*)pR;                          // 33,554,432
  float* beta = (float*)(pR + 33554432ULL);        //    524,288
  float* g = (float*)(pR + 34078720ULL);           //    524,288
  bf16* qn = (bf16*)(pR + 34603008ULL);            // 16,777,216
  bf16* kn = (bf16*)(pR + 51380224ULL);            // 16,777,216
  // phase-A aliases over the (then-dead) tail region:
  bf16* Bt_in = (bf16*)pR;                         // 50,659,328 [12352][2048]
  bf16* hb16 = (bf16*)(pR + 50659328ULL);          // 16,777,216 (dead after GEMM)
  bf16* Bt_out = (bf16*)zbuf;                      // 16,777,216 [2048][4096]

  // 0a. hidden fp32 -> bf16
  cvt_bf16<<<(L_SEQ * HDIM) / 1024, 256, 0, stream>>>(hidden, hb16);
  // 0b. in_proj weight: transpose + convert + pack columns -> Bt_in[n][k]
  transpose_w<3><<<dim3(193, 32), 256, 0, stream>>>(in_w, Bt_in, WLD, HDIM);
  // 1. single in_proj GEMM (both operands K-major, global_load_lds staging),
  //    epilogue routes packed cols: [0,8256) -> projA, [8256,12352) -> zbuf
  gemm_bt<1><<<dim3(97, 32), 256, 0, stream>>>(hb16, Bt_in, projA, zbuf,
                                               NPACK, HDIM);
  // 2. fused conv + silu + l2norm for q,k
  conv_norm_qk<<<L_SEQ * 16, 128, 0, stream>>>(projA, conv_w, qn, kn);
  // 3. conv + silu for v
  conv_silu_v<<<(L_SEQ * 4096) / 256, 256, 0, stream>>>(projA, conv_w, vbuf);
  // 4. beta / g
  compute_bg<<<(L_SEQ * 32) / 256, 256, 0, stream>>>(projA, A_log, dt_bias,
                                                     beta, g);
  // 5. chunked WY precompute (projA dead -> TV/TK overwrite it)
  precompute_chunk<<<2048, 512, 0, stream>>>(kn, vbuf, g, beta, TV, TK);
  // 6. sequential inter-chunk recurrence (TV->U in place, Oinner->vbuf)
  seq_kernel<<<64, 512, 0, stream>>>(TV, TK, qn, kn, g, vbuf);
  // 7. intra-chunk attention + gated RMSNorm (U->core in place)
  pass2_kernel<<<2048, 512, 0, stream>>>(TV, vbuf, qn, kn, g, zbuf, norm_w);
  // 8. out_proj weight: transpose + convert -> Bt_out[n][k] (zbuf dead)
  transpose_w<0><<<dim3(32, 64), 256, 0, stream>>>(out_w, Bt_out, 2048, 4096);
  // 9. out_proj GEMM
  gemm_bt<0><<<dim3(16, 32), 256, 0, stream>>>(TV, Bt_out, out, nullptr,
                                               2048, 4096);
}

// Round 5
// 1392.645 us; speedup vs baseline: 5.9501x; 1.0455x over previous
//
#include <hip/hip_runtime.h>
#include <hip/hip_bf16.h>

#define L_SEQ 4096
#define HDIM 2048
#define NPROJA 8256      // packed q(2048) k(2048) v(4096) ba(64)
#define NPACK 12352      // packed incl z: q|k|v|ba|z
#define WLD 12352        // row stride of in_proj_w
#define EPS_ 1e-6f

using bf16 = __hip_bfloat16;
typedef __attribute__((ext_vector_type(8))) short short8;
typedef __attribute__((ext_vector_type(4))) float f32x4;

__device__ __forceinline__ float b2f(bf16 x) { return __bfloat162float(x); }
__device__ __forceinline__ bf16 f2b(float x) { return __float2bfloat16(x); }
__device__ __forceinline__ unsigned short b2u(bf16 x) {
  union { bf16 b; unsigned short u; } c; c.b = x; return c.u;
}
// XOR-swizzled LDS addressing keyed on row&7 (for 256B/128B-row MFMA tiles)
__device__ __forceinline__ void* swz(void* base, int row, int rowbytes, int colbyte) {
  return (void*)((char*)base + row * rowbytes + (colbyte ^ ((row & 7) << 4)));
}
__device__ __forceinline__ const void* swzc(const void* base, int row, int rowbytes, int colbyte) {
  return (const void*)((const char*)base + row * rowbytes + (colbyte ^ ((row & 7) << 4)));
}
// KhT swizzle: key on (row>>3)&7 (lane-varying) to spread transpose writes
__device__ __forceinline__ void* swzk(void* base, int row, int colbyte) {
  return (void*)((char*)base + row * 128 + (colbyte ^ (((row >> 3) & 7) << 4)));
}
__device__ __forceinline__ const void* swzkc(const void* base, int row, int colbyte) {
  return (const void*)((const char*)base + row * 128 + (colbyte ^ (((row >> 3) & 7) << 4)));
}

__device__ __forceinline__ void async_copy16(const void* g, void* l) {
  __builtin_amdgcn_global_load_lds(
      (const __attribute__((address_space(1))) void*)g,
      (__attribute__((address_space(3))) void*)l, 16, 0, 0);
}

// ---------------- fp32 -> bf16 convert (linear) ---------------------------
__global__ __launch_bounds__(256) void cvt_bf16(const float* __restrict__ in,
                                                bf16* __restrict__ outp) {
  int i = (blockIdx.x * 256 + threadIdx.x) * 4;
  float4 v = *(const float4*)&in[i];
  bf16 o4[4] = {f2b(v.x), f2b(v.y), f2b(v.z), f2b(v.w)};
  *(ushort4*)&outp[i] = *(ushort4*)o4;
}

// -------- packed-column map: n(packed) -> source col of in_proj_w ---------
template <int MODE>
__device__ __forceinline__ int pmap(int n) {
  if constexpr (MODE == 3) {
    if (n < 2048) return (n >> 7) * 768 + (n & 127);
    else if (n < 4096) { int m = n - 2048; return (m >> 7) * 768 + 128 + (m & 127); }
    else if (n < 8192) { int m = n - 4096; return (m >> 8) * 768 + 256 + (m & 255); }
    else if (n < 8256) return 12288 + (n - 8192);
    else { int m = n - 8256; return (m >> 8) * 768 + 512 + (m & 255); }
  } else {
    return n;
  }
}

// -------- weight transpose+convert: Bt[n][k] = bf16(W[k][pmap(n)]) --------
template <int MODE>
__global__ __launch_bounds__(256) void transpose_w(
    const float* __restrict__ W, bf16* __restrict__ Bt, int ldw, int Kd) {
  __shared__ float T[64][65];
  const int nb = blockIdx.x * 64, kb = blockIdx.y * 64;
  const int tid = threadIdx.x;
  const int c = tid & 63, gq = tid >> 6;
  const int sbase = pmap<MODE>(nb);
#pragma unroll
  for (int i = 0; i < 16; ++i) {
    int r = gq * 16 + i;
    T[c][r] = W[(size_t)(kb + r) * ldw + sbase + c];
  }
  __syncthreads();
#pragma unroll
  for (int i = 0; i < 16; ++i) {
    int n = gq * 16 + i;
    Bt[(size_t)(nb + n) * Kd + kb + c] = f2b(T[n][c]);
  }
}

// ---------------- MFMA bf16 GEMM, both operands K-major -------------------
// Single-barrier ping-pong LDS double buffer: per K-step, barrier ->
// issue async stage into buf^1 -> ds_read+MFMA from buf (loads fly under
// compute; next barrier drains them). Flat 1-D grid with n-chunked
// rasterization (chunk=32 n-panels, n-fastest ids): under id%8->XCD
// round-robin each XCD keeps 4 B-panels (2MB) L2-resident per chunk.
template <int ROUTE>
__global__ __launch_bounds__(256) void gemm_bt(
    const bf16* __restrict__ A, const bf16* __restrict__ Bt,
    void* __restrict__ Cp, bf16* __restrict__ Cz, int N, int Kd,
    int MBnum, int NBnum) {
  __shared__ bf16 As[2][128 * 32];
  __shared__ bf16 Bs[2][128 * 32];
  const int tid = threadIdx.x;
  const int wave = tid >> 6, lane = tid & 63;
  const int l15 = lane & 15, quad = lane >> 4;

  int m_blk, n_blk;
  {
    const int CW = 32;
    int fullc = NBnum / CW;
    int rem = NBnum - fullc * CW;
    int thr = fullc * CW * MBnum;
    int wg = blockIdx.x;
    if (wg < thr) {
      int cw = CW * MBnum;
      int chunk = wg / cw, w = wg - chunk * cw;
      n_blk = chunk * CW + (w & (CW - 1));
      m_blk = w / CW;
    } else {
      int w2 = wg - thr;
      int r = rem ? rem : 1;
      n_blk = fullc * CW + w2 % r;
      m_blk = w2 / r;
    }
  }
  const int m0 = m_blk * 128, n0 = n_blk * 128;
  const int mw = (wave >> 1) * 64, nw = (wave & 1) * 64;

  f32x4 acc[4][4];
#pragma unroll
  for (int i = 0; i < 4; i++)
#pragma unroll
    for (int j = 0; j < 4; j++) acc[i][j] = {0.f, 0.f, 0.f, 0.f};

  // staging: chunk = tid (+256); row = chunk>>2, k8 = chunk&3 (16B each)
  const bf16* a_src0 = A + (size_t)(m0 + (tid >> 2)) * Kd + (tid & 3) * 8;
  const bf16* a_src1 = a_src0 + (size_t)64 * Kd;
  const bf16* b_src0 = Bt + (size_t)(n0 + (tid >> 2)) * Kd + (tid & 3) * 8;
  const bf16* b_src1 = b_src0 + (size_t)64 * Kd;
  const int d0 = tid * 8, d1 = (tid + 256) * 8;

  // prologue: stage tile 0 into buffer 0
  async_copy16(a_src0, &As[0][d0]);
  async_copy16(a_src1, &As[0][d1]);
  async_copy16(b_src0, &Bs[0][d0]);
  async_copy16(b_src1, &Bs[0][d1]);

  int cur = 0;
  for (int k0 = 0; k0 < Kd; k0 += 32, cur ^= 1) {
    __syncthreads();  // drains vmcnt (stage of buf[cur] complete+visible);
                      // also: all waves done reading buf[cur^1] last iter
    if (k0 + 32 < Kd) {
      const int nk = k0 + 32, nb = cur ^ 1;
      async_copy16(a_src0 + nk, &As[nb][d0]);
      async_copy16(a_src1 + nk, &As[nb][d1]);
      async_copy16(b_src0 + nk, &Bs[nb][d0]);
      async_copy16(b_src1 + nk, &Bs[nb][d1]);
    }
    short8 af[4], bfr[4];
#pragma unroll
    for (int i = 0; i < 4; i++)
      af[i] = *(const short8*)&As[cur][(mw + i * 16 + l15) * 32 + quad * 8];
#pragma unroll
    for (int j = 0; j < 4; j++)
      bfr[j] = *(const short8*)&Bs[cur][(nw + j * 16 + l15) * 32 + quad * 8];
#pragma unroll
    for (int i = 0; i < 4; i++)
#pragma unroll
      for (int j = 0; j < 4; j++)
        acc[i][j] = __builtin_amdgcn_mfma_f32_16x16x32_bf16(af[i], bfr[j],
                                                            acc[i][j], 0, 0, 0);
  }

#pragma unroll
  for (int i = 0; i < 4; i++) {
#pragma unroll
    for (int j = 0; j < 4; j++) {
      int col = n0 + nw + j * 16 + l15;
      if (col < N) {
#pragma unroll
        for (int r = 0; r < 4; r++) {
          int row = m0 + mw + i * 16 + quad * 4 + r;
          if (ROUTE == 0) {
            ((float*)Cp)[(size_t)row * N + col] = acc[i][j][r];
          } else {
            if (col < NPROJA)
              ((bf16*)Cp)[(size_t)row * NPROJA + col] = f2b(acc[i][j][r]);
            else
              Cz[(size_t)row * 4096 + (col - NPROJA)] = f2b(acc[i][j][r]);
          }
        }
      }
    }
  }
}

// ------- fused conv(K=4 causal) + SiLU + l2norm for q and k ---------------
__global__ __launch_bounds__(128) void conv_norm_qk(
    const bf16* __restrict__ proj, const float* __restrict__ conv_w,
    bf16* __restrict__ qn, bf16* __restrict__ kn) {
  const int t = blockIdx.x >> 4, hk = blockIdx.x & 15;
  const int d = threadIdx.x;
  const int cq = hk * 128 + d;
  const int ck = 2048 + hk * 128 + d;
  float sq = 0.f, sk = 0.f;
#pragma unroll
  for (int j = 0; j < 4; j++) {
    int ts = t + j - 3;
    if (ts >= 0) {
      sq += conv_w[cq * 4 + j] * b2f(proj[(size_t)ts * NPROJA + cq]);
      sk += conv_w[ck * 4 + j] * b2f(proj[(size_t)ts * NPROJA + ck]);
    }
  }
  float qv = sq / (1.f + expf(-sq));
  float kv = sk / (1.f + expf(-sk));
  float ssq = qv * qv, ssk = kv * kv;
#pragma unroll
  for (int off = 32; off > 0; off >>= 1) {
    ssq += __shfl_down(ssq, off, 64);
    ssk += __shfl_down(ssk, off, 64);
  }
  __shared__ float red[4];
  if ((d & 63) == 0) {
    red[(d >> 6) * 2] = ssq;
    red[(d >> 6) * 2 + 1] = ssk;
  }
  __syncthreads();
  float sumq = red[0] + red[2];
  float sumk = red[1] + red[3];
  size_t o = (size_t)(t * 16 + hk) * 128 + d;
  qn[o] = f2b(qv * rsqrtf(sumq + EPS_) * 0.08838834764831845f);
  kn[o] = f2b(kv * rsqrtf(sumk + EPS_));
}

// ------- conv + SiLU for v channels ---------------------------------------
__global__ __launch_bounds__(256) void conv_silu_v(
    const bf16* __restrict__ proj, const float* __restrict__ conv_w,
    bf16* __restrict__ vbuf) {
  int idx = blockIdx.x * 256 + threadIdx.x;
  int t = idx >> 12, c = idx & 4095;
  int chan = 4096 + c;
  float s = 0.f;
#pragma unroll
  for (int j = 0; j < 4; j++) {
    int ts = t + j - 3;
    if (ts >= 0) s += conv_w[chan * 4 + j] * b2f(proj[(size_t)ts * NPROJA + chan]);
  }
  vbuf[idx] = f2b(s / (1.f + expf(-s)));
}

// ---------------- beta / g ------------------------------------------------
__global__ __launch_bounds__(256) void compute_bg(
    const bf16* __restrict__ proj, const float* __restrict__ A_log,
    const float* __restrict__ dt_bias, float* __restrict__ beta_arr,
    float* __restrict__ g_arr) {
  int idx = blockIdx.x * 256 + threadIdx.x;
  int t = idx >> 5, hv = idx & 31;
  size_t base = (size_t)t * NPROJA + 8192 + (hv >> 1) * 4 + (hv & 1);
  float b = b2f(proj[base]);
  float a = b2f(proj[base + 2]);
  beta_arr[idx] = 1.f / (1.f + expf(-b));
  float x = a + dt_bias[hv];
  float sp = (x > 20.f) ? x : log1pf(expf(x));
  g_arr[idx] = -expf(A_log[hv]) * sp;
}

// ---------------- chunked WY precompute (512 threads: 8 waves/CU) ---------
__global__ __launch_bounds__(512) void precompute_chunk(
    const bf16* __restrict__ kn, const bf16* __restrict__ vbuf,
    const float* __restrict__ g_arr, const float* __restrict__ beta_arr,
    bf16* __restrict__ TV, bf16* __restrict__ TK) {
  const int c = blockIdx.x >> 5, h = blockIdx.x & 31, hk = h >> 1;
  const int t0 = c * 64, tid = threadIdx.x;
  __shared__ float Kf[64][129];
  __shared__ float X[64][256];
  __shared__ float BA[64][64];
  __shared__ float cgs[64], bet[64], eKs[64];

  for (int e = tid; e < 1024; e += 512) {
    int row = e >> 4, s = e & 15;
    short8 v = *(const short8*)(kn + ((size_t)(t0 + row) * 16 + hk) * 128 + s * 8);
    bf16 tmp[8];
    *(short8*)tmp = v;
#pragma unroll
    for (int k = 0; k < 8; ++k) Kf[row][s * 8 + k] = b2f(tmp[k]);
  }
  if (tid < 64) {
    float bb = beta_arr[(size_t)(t0 + tid) * 32 + h];
    bet[tid] = bb;
    float x = g_arr[(size_t)(t0 + tid) * 32 + h];
#pragma unroll
    for (int off = 1; off < 64; off <<= 1) {
      float o = __shfl_up(x, off, 64);
      if (tid >= off) x += o;
    }
    cgs[tid] = x;
    eKs[tid] = bb * expf(x);
  }
  __syncthreads();
  // X init = diag(beta) [V | Ktilde]
  for (int e = tid; e < 8192; e += 512) {
    int i = e >> 7, d = e & 127;
    X[i][d] = bet[i] * b2f(vbuf[(size_t)(t0 + i) * 4096 + h * 128 + d]);
    X[i][128 + d] = eKs[i] * Kf[i][d];
  }
  // BA[i][j] = beta_i * exp(cg_i - cg_j) * (k_i . k_j), strictly lower
  {
    const int ti = tid >> 4, tj = tid & 15;
    float acc[2][4];
#pragma unroll
    for (int r = 0; r < 2; ++r)
#pragma unroll
      for (int s = 0; s < 4; ++s) acc[r][s] = 0.f;
    for (int dk = 0; dk < 128; ++dk) {
      float a0 = Kf[ti * 2 + 0][dk], a1 = Kf[ti * 2 + 1][dk];
      float c0 = Kf[tj * 4 + 0][dk], c1 = Kf[tj * 4 + 1][dk];
      float c2 = Kf[tj * 4 + 2][dk], c3 = Kf[tj * 4 + 3][dk];
      acc[0][0] += a0 * c0; acc[0][1] += a0 * c1; acc[0][2] += a0 * c2; acc[0][3] += a0 * c3;
      acc[1][0] += a1 * c0; acc[1][1] += a1 * c1; acc[1][2] += a1 * c2; acc[1][3] += a1 * c3;
    }
#pragma unroll
    for (int r = 0; r < 2; ++r)
#pragma unroll
      for (int s = 0; s < 4; ++s) {
        int i = ti * 2 + r, j = tj * 4 + s;
        BA[i][j] = (j < i) ? bet[i] * expf(cgs[i] - cgs[j]) * acc[r][s] : 0.f;
      }
  }
  __syncthreads();
  // forward substitution: thread owns column (256 cols; waves 4-7 idle here)
  if (tid < 256) {
    const int d = tid;
    for (int i = 1; i < 64; ++i) {
      const float* bar = BA[i];
      float s0 = 0.f, s1 = 0.f;
      int j = 0;
      for (; j + 1 < i; j += 2) {
        s0 += bar[j] * X[j][d];
        s1 += bar[j + 1] * X[j + 1][d];
      }
      if (j < i) s0 += bar[j] * X[j][d];
      X[i][d] -= s0 + s1;
    }
  }
  __syncthreads();
  for (int e = tid; e < 8192; e += 512) {
    int i = e >> 7, d = e & 127;
    size_t o = ((size_t)(t0 + i) * 32 + h) * 128 + d;
    TV[o] = f2b(X[i][d]);
    TK[o] = f2b(X[i][128 + d]);
  }
}

// ---------------- sequential inter-chunk recurrence (MFMA, hi/lo S) -------
__global__ __launch_bounds__(512) void seq_kernel(
    bf16* TVU,                       // [4096][32][128]: TV in, U out (in-place)
    const bf16* __restrict__ TKg, const bf16* __restrict__ qn,
    const bf16* __restrict__ kn, const float* __restrict__ g_arr,
    bf16* __restrict__ Oin) {        // vbuf reused: Oinner out
  const int h = blockIdx.x >> 1, dvh = blockIdx.x & 1, hk = h >> 1;
  const int dv0 = dvh * 64;
  const int tid = threadIdx.x;
  const int wave = tid >> 6, lane = tid & 63, l15 = lane & 15, quad = lane >> 4;
  const int mi = wave >> 1, half = wave & 1;
  const int srow = tid >> 4, scol = tid & 15;

  __shared__ bf16 STh[64 * 128], STl[64 * 128];  // S^T [dv][dk] hi/lo
  __shared__ bf16 UTh[64 * 64], UTl[64 * 64];    // U^T [dv][i]  hi/lo
  __shared__ bf16 TKs[64 * 128];                 // TK [i][dk]
  __shared__ bf16 Qts[64 * 128];                 // Qtilde [i][dk]
  __shared__ bf16 KhT[128 * 64];                 // Khat'^T [dk][i] (swzk)

  for (int e = tid; e < 4096; e += 512) {
    ((unsigned int*)STh)[e] = 0u;
    ((unsigned int*)STl)[e] = 0u;
  }
  f32x4 Sf[4];
#pragma unroll
  for (int i = 0; i < 4; i++) Sf[i] = {0.f, 0.f, 0.f, 0.f};

  short8 tkr0, tkr1, qr0, qr1, kr0, kr1;
  float gv;
  auto issue_loads = [&](int c) {
    const size_t t0 = (size_t)c << 6;
    tkr0 = *(const short8*)(TKg + ((t0 + srow) * 32 + h) * 128 + scol * 8);
    tkr1 = *(const short8*)(TKg + ((t0 + 32 + srow) * 32 + h) * 128 + scol * 8);
    qr0 = *(const short8*)(qn + ((t0 + srow) * 16 + hk) * 128 + scol * 8);
    qr1 = *(const short8*)(qn + ((t0 + 32 + srow) * 16 + hk) * 128 + scol * 8);
    kr0 = *(const short8*)(kn + ((t0 + srow) * 16 + hk) * 128 + scol * 8);
    kr1 = *(const short8*)(kn + ((t0 + 32 + srow) * 16 + hk) * 128 + scol * 8);
    gv = g_arr[(t0 + lane) * 32 + h];
  };
  issue_loads(0);

  for (int c = 0; c < 64; ++c) {
    const int t0 = c << 6;
    __syncthreads();  // (A) prev-chunk GEMM reads done; staging buffers free

    // TV prefetch (consumed in U-phase)
    bf16 tvp[2][4];
#pragma unroll
    for (int nj = 0; nj < 2; nj++) {
      const int nrow = half * 32 + nj * 16 + l15;
#pragma unroll
      for (int r = 0; r < 4; r++) {
        const int i = mi * 16 + quad * 4 + r;
        tvp[nj][r] = TVU[((size_t)(t0 + i) * 32 + h) * 128 + dv0 + nrow];
      }
    }
    // all-wave chunk-local cumulative-g scan (lane = chunk row)
    float cg = gv;
#pragma unroll
    for (int off = 1; off < 64; off <<= 1) {
      float o = __shfl_up(cg, off, 64);
      if (lane >= off) cg += o;
    }
    const float cg63 = __shfl(cg, 63, 64);
    const float lam = expf(cg63);
    const float fq = expf(cg);
    const float fk = expf(cg63 - cg);
    // stage TK (vectorized)
    *(short8*)swz(TKs, srow, 256, scol * 16) = tkr0;
    *(short8*)swz(TKs, srow + 32, 256, scol * 16) = tkr1;
    // stage Qtilde = q * fq[row]
    {
      const float f0 = __shfl(fq, srow, 64);
      const float f1 = __shfl(fq, srow + 32, 64);
      bf16 ta[8], tb[8];
      *(short8*)ta = qr0;
      *(short8*)tb = qr1;
#pragma unroll
      for (int k = 0; k < 8; k++) {
        ta[k] = f2b(b2f(ta[k]) * f0);
        tb[k] = f2b(b2f(tb[k]) * f1);
      }
      *(short8*)swz(Qts, srow, 256, scol * 16) = *(short8*)ta;
      *(short8*)swz(Qts, srow + 32, 256, scol * 16) = *(short8*)tb;
    }
    // stage Khat'^T = (k * fk[row])^T, scalar writes spread via swzk
    {
      const float f0 = __shfl(fk, srow, 64);
      const float f1 = __shfl(fk, srow + 32, 64);
      bf16 ka[8], kb[8];
      *(short8*)ka = kr0;
      *(short8*)kb = kr1;
#pragma unroll
      for (int k = 0; k < 8; k++) {
        const int dk = scol * 8 + k;
        *(bf16*)swzk(KhT, dk, srow * 2) = f2b(b2f(ka[k]) * f0);
        *(bf16*)swzk(KhT, dk, (srow + 32) * 2) = f2b(b2f(kb[k]) * f1);
      }
    }
    // T14: issue next-chunk global loads now (fly during GEMM phases)
    issue_loads(c + 1 < 64 ? c + 1 : 63);
    __syncthreads();  // (B) operands staged

    // GEMM3 (Oinner = Qtilde@S) + GEMM1 (x = TK@S) fused over shared B reads
    f32x4 oacc[2], xacc[2];
#pragma unroll
    for (int nj = 0; nj < 2; nj++) { oacc[nj] = {0.f,0.f,0.f,0.f}; xacc[nj] = {0.f,0.f,0.f,0.f}; }
    const int arow = mi * 16 + l15;
#pragma unroll
    for (int ks = 0; ks < 4; ++ks) {
      const int cb = ks * 64 + quad * 16;
      short8 aq = *(const short8*)swzc(Qts, arow, 256, cb);
      short8 at = *(const short8*)swzc(TKs, arow, 256, cb);
#pragma unroll
      for (int nj = 0; nj < 2; nj++) {
        const int nrow = half * 32 + nj * 16 + l15;
        short8 bh = *(const short8*)swzc(STh, nrow, 256, cb);
        short8 bl = *(const short8*)swzc(STl, nrow, 256, cb);
        oacc[nj] = __builtin_amdgcn_mfma_f32_16x16x32_bf16(aq, bh, oacc[nj], 0, 0, 0);
        xacc[nj] = __builtin_amdgcn_mfma_f32_16x16x32_bf16(at, bh, xacc[nj], 0, 0, 0);
        xacc[nj] = __builtin_amdgcn_mfma_f32_16x16x32_bf16(at, bl, xacc[nj], 0, 0, 0);
      }
    }
    // hoist KhT A-fragments into regs
    const int krow = wave * 16 + l15;
    short8 ak0 = *(const short8*)swzkc(KhT, krow, 0 * 64 + quad * 16);
    short8 ak1 = *(const short8*)swzkc(KhT, krow, 1 * 64 + quad * 16);

    // U phase: U = TV - x; write Oinner + U(global) + U^T hi/lo (LDS)
#pragma unroll
    for (int nj = 0; nj < 2; nj++) {
      const int nrow = half * 32 + nj * 16 + l15;
      unsigned short ph[4], pl[4];
#pragma unroll
      for (int r = 0; r < 4; ++r) {
        const int i = mi * 16 + quad * 4 + r;
        const size_t go = ((size_t)(t0 + i) * 32 + h) * 128 + dv0 + nrow;
        Oin[go] = f2b(oacc[nj][r]);
        float uv = b2f(tvp[nj][r]) - xacc[nj][r];
        bf16 hb = f2b(uv);
        TVU[go] = hb;
        ph[r] = b2u(hb);
        pl[r] = b2u(f2b(uv - b2f(hb)));
      }
      const int cb = (mi * 16 + quad * 4) * 2;
      ushort4 vh; vh.x = ph[0]; vh.y = ph[1]; vh.z = ph[2]; vh.w = ph[3];
      ushort4 vl; vl.x = pl[0]; vl.y = pl[1]; vl.z = pl[2]; vl.w = pl[3];
      *(ushort4*)swz(UTh, nrow, 128, cb) = vh;
      *(ushort4*)swz(UTl, nrow, 128, cb) = vl;
    }
    __syncthreads();  // (C) UT visible

    // GEMM2: S = lam*S + Khat'^T @ U  (S master in f32 accumulators)
#pragma unroll
    for (int nj = 0; nj < 4; nj++) {
      Sf[nj][0] *= lam; Sf[nj][1] *= lam; Sf[nj][2] *= lam; Sf[nj][3] *= lam;
    }
#pragma unroll
    for (int ks = 0; ks < 2; ++ks) {
      const short8 ak = ks ? ak1 : ak0;
      const int cb = ks * 64 + quad * 16;
#pragma unroll
      for (int nj = 0; nj < 4; nj++) {
        const int nrow = nj * 16 + l15;
        short8 bh = *(const short8*)swzc(UTh, nrow, 128, cb);
        short8 bl = *(const short8*)swzc(UTl, nrow, 128, cb);
        Sf[nj] = __builtin_amdgcn_mfma_f32_16x16x32_bf16(ak, bh, Sf[nj], 0, 0, 0);
        Sf[nj] = __builtin_amdgcn_mfma_f32_16x16x32_bf16(ak, bl, Sf[nj], 0, 0, 0);
      }
    }
    // write S^T hi/lo for next chunk
#pragma unroll
    for (int nj = 0; nj < 4; nj++) {
      const int nrow = nj * 16 + l15;
      unsigned short ph[4], pl[4];
#pragma unroll
      for (int r = 0; r < 4; ++r) {
        float s = Sf[nj][r];
        bf16 hb = f2b(s);
        ph[r] = b2u(hb);
        pl[r] = b2u(f2b(s - b2f(hb)));
      }
      const int cb = (wave * 16 + quad * 4) * 2;
      ushort4 vh; vh.x = ph[0]; vh.y = ph[1]; vh.z = ph[2]; vh.w = ph[3];
      ushort4 vl; vl.x = pl[0]; vl.y = pl[1]; vl.z = pl[2]; vl.w = pl[3];
      *(ushort4*)swz(STh, nrow, 256, cb) = vh;
      *(ushort4*)swz(STl, nrow, 256, cb) = vl;
    }
  }
}

// ---------------- pass2: O = Oinner + Attn@U, fused gated RMSNorm ---------
__global__ __launch_bounds__(512) void pass2_kernel(
    bf16* UC,                        // U in, normed core out (in-place)
    const bf16* __restrict__ Oin, const bf16* __restrict__ qn,
    const bf16* __restrict__ kn, const float* __restrict__ g_arr,
    const bf16* __restrict__ zbuf, const float* __restrict__ norm_w) {
  const int c = blockIdx.x >> 5, h = blockIdx.x & 31, hk = h >> 1;
  const int t0 = c * 64, tid = threadIdx.x;
  __shared__ float Qf[64][129], Kf[64][129];
  __shared__ float Uf[64][128];
  __shared__ float Of[64][129];
  __shared__ float At[64][65];
  __shared__ float cgs[64], nw[128];

  for (int e = tid; e < 1024; e += 512) {
    int row = e >> 4, s = e & 15;
    size_t qko = ((size_t)(t0 + row) * 16 + hk) * 128 + s * 8;
    size_t uo = ((size_t)(t0 + row) * 32 + h) * 128 + s * 8;
    short8 vq = *(const short8*)(qn + qko);
    short8 vk = *(const short8*)(kn + qko);
    short8 vu = *(const short8*)(UC + uo);
    short8 vo = *(const short8*)(Oin + uo);
    bf16 tq[8], tk[8], tu[8], to[8];
    *(short8*)tq = vq; *(short8*)tk = vk; *(short8*)tu = vu; *(short8*)to = vo;
#pragma unroll
    for (int k = 0; k < 8; ++k) {
      Qf[row][s * 8 + k] = b2f(tq[k]);
      Kf[row][s * 8 + k] = b2f(tk[k]);
      Uf[row][s * 8 + k] = b2f(tu[k]);
      Of[row][s * 8 + k] = b2f(to[k]);
    }
  }
  if (tid < 64) {
    float x = g_arr[(size_t)(t0 + tid) * 32 + h];
#pragma unroll
    for (int off = 1; off < 64; off <<= 1) {
      float o = __shfl_up(x, off, 64);
      if (tid >= off) x += o;
    }
    cgs[tid] = x;
  }
  if (tid < 128) nw[tid] = norm_w[tid];
  __syncthreads();
  // Attn build (includes diagonal): 2 rows x 4 cols per thread
  {
    const int ti = tid >> 4, tj = tid & 15;
    float acc[2][4];
#pragma unroll
    for (int r = 0; r < 2; ++r)
#pragma unroll
      for (int s = 0; s < 4; ++s) acc[r][s] = 0.f;
    for (int dk = 0; dk < 128; ++dk) {
      float a0 = Qf[ti * 2 + 0][dk], a1 = Qf[ti * 2 + 1][dk];
      float c0 = Kf[tj * 4 + 0][dk], c1 = Kf[tj * 4 + 1][dk];
      float c2 = Kf[tj * 4 + 2][dk], c3 = Kf[tj * 4 + 3][dk];
      acc[0][0] += a0 * c0; acc[0][1] += a0 * c1; acc[0][2] += a0 * c2; acc[0][3] += a0 * c3;
      acc[1][0] += a1 * c0; acc[1][1] += a1 * c1; acc[1][2] += a1 * c2; acc[1][3] += a1 * c3;
    }
#pragma unroll
    for (int r = 0; r < 2; ++r)
#pragma unroll
      for (int s = 0; s < 4; ++s) {
        int i = ti * 2 + r, j = tj * 4 + s;
        At[i][j] = (j <= i) ? expf(cgs[i] - cgs[j]) * acc[r][s] : 0.f;
      }
  }
  __syncthreads();
  // O += Attn @ U: 2 rows x 8 cols per thread
  {
    const int ri = tid >> 4, tn = tid & 15;
    float acc[2][8];
#pragma unroll
    for (int r = 0; r < 2; ++r)
#pragma unroll
      for (int k = 0; k < 8; ++k) acc[r][k] = 0.f;
    for (int j = 0; j < 64; ++j) {
      float a0 = At[ri * 2 + 0][j], a1 = At[ri * 2 + 1][j];
#pragma unroll
      for (int k = 0; k < 8; ++k) {
        float u = Uf[j][tn + 16 * k];
        acc[0][k] += a0 * u;
        acc[1][k] += a1 * u;
      }
    }
#pragma unroll
    for (int r = 0; r < 2; ++r)
#pragma unroll
      for (int k = 0; k < 8; ++k)
        Of[ri * 2 + r][tn + 16 * k] += acc[r][k];
  }
  __syncthreads();
  // gated RMSNorm + store: 8 lanes per row
  {
    const int r = tid >> 3, q8 = tid & 7;
    float ss = 0.f;
#pragma unroll
    for (int k = 0; k < 16; ++k) {
      float v = Of[r][q8 + 8 * k];
      ss += v * v;
    }
    ss += __shfl_xor(ss, 1, 64);
    ss += __shfl_xor(ss, 2, 64);
    ss += __shfl_xor(ss, 4, 64);
    float scale = rsqrtf(ss * (1.f / 128.f) + EPS_);
#pragma unroll
    for (int k = 0; k < 16; ++k) {
      int n = q8 + 8 * k;
      float val = Of[r][n] * scale * nw[n];
      float zz = b2f(zbuf[(size_t)(t0 + r) * 4096 + h * 128 + n]);
      val *= zz / (1.f + expf(-zz));
      UC[((size_t)(t0 + r) * 32 + h) * 128 + n] = f2b(val);
    }
  }
}

extern "C" void kernel_launch(void* const* d_in, const int* in_sizes, int n_in,
                              void* d_out, int out_size, void* d_ws,
                              size_t ws_size, hipStream_t stream) {
  const float* hidden = (const float*)d_in[0];
  const float* in_w = (const float*)d_in[1];
  const float* conv_w = (const float*)d_in[2];
  const float* A_log = (const float*)d_in[3];
  const float* dt_bias = (const float*)d_in[4];
  const float* norm_w = (const float*)d_in[5];
  const float* out_w = (const float*)d_in[6];
  float* out = (float*)d_out;

  // workspace layout: total 169,345,024 B (proven size)
  char* p = (char*)d_ws;
  bf16* projA = (bf16*)p;                          // 67,633,152 [4096][8256]
  bf16* TV = (bf16*)p;                             // alias: TV -> U -> core
  bf16* TK = (bf16*)(p + 33554432ULL);
  bf16* zbuf = (bf16*)(p + 67633152ULL);           // 33,554,432 [4096][32][128]
  char* pR = p + 101187584ULL;                     // tail region, 68,157,440 B
  bf16* vbuf = (bf16*)pR;                          // 33,554,432
  float* beta = (float*)(pR + 33554432ULL);        //    524,288
  float* g = (float*)(pR + 34078720ULL);           //    524,288
  bf16* qn = (bf16*)(pR + 34603008ULL);            // 16,777,216
  bf16* kn = (bf16*)(pR + 51380224ULL);            // 16,777,216
  // phase-A aliases over the (then-dead) tail region:
  bf16* Bt_in = (bf16*)pR;                         // 50,659,328 [12352][2048]
  bf16* hb16 = (bf16*)(pR + 50659328ULL);          // 16,777,216 (dead after GEMM)
  bf16* Bt_out = (bf16*)zbuf;                      // 16,777,216 [2048][4096]

  // 0a. hidden fp32 -> bf16
  cvt_bf16<<<(L_SEQ * HDIM) / 1024, 256, 0, stream>>>(hidden, hb16);
  // 0b. in_proj weight: transpose + convert + pack columns -> Bt_in[n][k]
  transpose_w<3><<<dim3(193, 32), 256, 0, stream>>>(in_w, Bt_in, WLD, HDIM);
  // 1. single in_proj GEMM (ping-pong dbuf, chunk-rasterized flat grid)
  gemm_bt<1><<<97 * 32, 256, 0, stream>>>(hb16, Bt_in, projA, zbuf,
                                          NPACK, HDIM, 32, 97);
  // 2. fused conv + silu + l2norm for q,k
  conv_norm_qk<<<L_SEQ * 16, 128, 0, stream>>>(projA, conv_w, qn, kn);
  // 3. conv + silu for v
  conv_silu_v<<<(L_SEQ * 4096) / 256, 256, 0, stream>>>(projA, conv_w, vbuf);
  // 4. beta / g
  compute_bg<<<(L_SEQ * 32) / 256, 256, 0, stream>>>(projA, A_log, dt_bias,
                                                     beta, g);
  // 5. chunked WY precompute (projA dead -> TV/TK overwrite it)
  precompute_chunk<<<2048, 512, 0, stream>>>(kn, vbuf, g, beta, TV, TK);
  // 6. sequential inter-chunk recurrence (TV->U in place, Oinner->vbuf)
  seq_kernel<<<64, 512, 0, stream>>>(TV, TK, qn, kn, g, vbuf);
  // 7. intra-chunk attention + gated RMSNorm (U->core in place)
  pass2_kernel<<<2048, 512, 0, stream>>>(TV, vbuf, qn, kn, g, zbuf, norm_w);
  // 8. out_proj weight: transpose + convert -> Bt_out[n][k] (zbuf dead)
  transpose_w<0><<<dim3(32, 64), 256, 0, stream>>>(out_w, Bt_out, 2048, 4096);
  // 9. out_proj GEMM
  gemm_bt<0><<<16 * 32, 256, 0, stream>>>(TV, Bt_out, out, nullptr,
                                          2048, 4096, 32, 16);
}

// Round 6
// 1170.100 us; speedup vs baseline: 7.0818x; 1.1902x over previous
//
#include <hip/hip_runtime.h>
#include <hip/hip_bf16.h>

#define L_SEQ 4096
#define HDIM 2048
#define NPROJA 8256      // packed q(2048) k(2048) v(4096) ba(64)
#define NPACK 12352      // packed incl z: q|k|v|ba|z
#define WLD 12352        // row stride of in_proj_w
#define EPS_ 1e-6f

using bf16 = __hip_bfloat16;
typedef __attribute__((ext_vector_type(8))) short short8;
typedef __attribute__((ext_vector_type(4))) float f32x4;

__device__ __forceinline__ float b2f(bf16 x) { return __bfloat162float(x); }
__device__ __forceinline__ bf16 f2b(float x) { return __float2bfloat16(x); }
__device__ __forceinline__ unsigned short b2u(bf16 x) {
  union { bf16 b; unsigned short u; } c; c.b = x; return c.u;
}
// XOR-swizzled LDS addressing keyed on row&7 (for 256B/128B-row MFMA tiles)
__device__ __forceinline__ void* swz(void* base, int row, int rowbytes, int colbyte) {
  return (void*)((char*)base + row * rowbytes + (colbyte ^ ((row & 7) << 4)));
}
__device__ __forceinline__ const void* swzc(const void* base, int row, int rowbytes, int colbyte) {
  return (const void*)((const char*)base + row * rowbytes + (colbyte ^ ((row & 7) << 4)));
}
// KhT swizzle: key on (row>>3)&7 (lane-varying) to spread transpose writes
__device__ __forceinline__ void* swzk(void* base, int row, int colbyte) {
  return (void*)((char*)base + row * 128 + (colbyte ^ (((row >> 3) & 7) << 4)));
}
__device__ __forceinline__ const void* swzkc(const void* base, int row, int colbyte) {
  return (const void*)((const char*)base + row * 128 + (colbyte ^ (((row >> 3) & 7) << 4)));
}

__device__ __forceinline__ void async_copy16(const void* g, void* l) {
  __builtin_amdgcn_global_load_lds(
      (const __attribute__((address_space(1))) void*)g,
      (__attribute__((address_space(3))) void*)l, 16, 0, 0);
}

// ---------------- fp32 -> bf16 convert (linear) ---------------------------
__global__ __launch_bounds__(256) void cvt_bf16(const float* __restrict__ in,
                                                bf16* __restrict__ outp) {
  int i = (blockIdx.x * 256 + threadIdx.x) * 4;
  float4 v = *(const float4*)&in[i];
  bf16 o4[4] = {f2b(v.x), f2b(v.y), f2b(v.z), f2b(v.w)};
  *(ushort4*)&outp[i] = *(ushort4*)o4;
}

// -------- packed-column map: n(packed) -> source col of in_proj_w ---------
template <int MODE>
__device__ __forceinline__ int pmap(int n) {
  if constexpr (MODE == 3) {
    if (n < 2048) return (n >> 7) * 768 + (n & 127);
    else if (n < 4096) { int m = n - 2048; return (m >> 7) * 768 + 128 + (m & 127); }
    else if (n < 8192) { int m = n - 4096; return (m >> 8) * 768 + 256 + (m & 255); }
    else if (n < 8256) return 12288 + (n - 8192);
    else { int m = n - 8256; return (m >> 8) * 768 + 512 + (m & 255); }
  } else {
    return n;
  }
}

// -------- weight transpose+convert: Bt[n][k] = bf16(W[k][pmap(n)]) --------
template <int MODE>
__global__ __launch_bounds__(256) void transpose_w(
    const float* __restrict__ W, bf16* __restrict__ Bt, int ldw, int Kd) {
  __shared__ float T[64][65];
  const int nb = blockIdx.x * 64, kb = blockIdx.y * 64;
  const int tid = threadIdx.x;
  const int c = tid & 63, gq = tid >> 6;
  const int sbase = pmap<MODE>(nb);
#pragma unroll
  for (int i = 0; i < 16; ++i) {
    int r = gq * 16 + i;
    T[c][r] = W[(size_t)(kb + r) * ldw + sbase + c];
  }
  __syncthreads();
#pragma unroll
  for (int i = 0; i < 16; ++i) {
    int n = gq * 16 + i;
    Bt[(size_t)(nb + n) * Kd + kb + c] = f2b(T[n][c]);
  }
}

// ---------------- MFMA bf16 GEMM, both operands K-major -------------------
// Single-barrier ping-pong LDS double buffer + n-chunked flat rasterization.
template <int ROUTE>
__global__ __launch_bounds__(256) void gemm_bt(
    const bf16* __restrict__ A, const bf16* __restrict__ Bt,
    void* __restrict__ Cp, bf16* __restrict__ Cz, int N, int Kd,
    int MBnum, int NBnum) {
  __shared__ bf16 As[2][128 * 32];
  __shared__ bf16 Bs[2][128 * 32];
  const int tid = threadIdx.x;
  const int wave = tid >> 6, lane = tid & 63;
  const int l15 = lane & 15, quad = lane >> 4;

  int m_blk, n_blk;
  {
    const int CW = 32;
    int fullc = NBnum / CW;
    int rem = NBnum - fullc * CW;
    int thr = fullc * CW * MBnum;
    int wg = blockIdx.x;
    if (wg < thr) {
      int cw = CW * MBnum;
      int chunk = wg / cw, w = wg - chunk * cw;
      n_blk = chunk * CW + (w & (CW - 1));
      m_blk = w / CW;
    } else {
      int w2 = wg - thr;
      int r = rem ? rem : 1;
      n_blk = fullc * CW + w2 % r;
      m_blk = w2 / r;
    }
  }
  const int m0 = m_blk * 128, n0 = n_blk * 128;
  const int mw = (wave >> 1) * 64, nw = (wave & 1) * 64;

  f32x4 acc[4][4];
#pragma unroll
  for (int i = 0; i < 4; i++)
#pragma unroll
    for (int j = 0; j < 4; j++) acc[i][j] = {0.f, 0.f, 0.f, 0.f};

  const bf16* a_src0 = A + (size_t)(m0 + (tid >> 2)) * Kd + (tid & 3) * 8;
  const bf16* a_src1 = a_src0 + (size_t)64 * Kd;
  const bf16* b_src0 = Bt + (size_t)(n0 + (tid >> 2)) * Kd + (tid & 3) * 8;
  const bf16* b_src1 = b_src0 + (size_t)64 * Kd;
  const int d0 = tid * 8, d1 = (tid + 256) * 8;

  async_copy16(a_src0, &As[0][d0]);
  async_copy16(a_src1, &As[0][d1]);
  async_copy16(b_src0, &Bs[0][d0]);
  async_copy16(b_src1, &Bs[0][d1]);

  int cur = 0;
  for (int k0 = 0; k0 < Kd; k0 += 32, cur ^= 1) {
    __syncthreads();
    if (k0 + 32 < Kd) {
      const int nk = k0 + 32, nb = cur ^ 1;
      async_copy16(a_src0 + nk, &As[nb][d0]);
      async_copy16(a_src1 + nk, &As[nb][d1]);
      async_copy16(b_src0 + nk, &Bs[nb][d0]);
      async_copy16(b_src1 + nk, &Bs[nb][d1]);
    }
    short8 af[4], bfr[4];
#pragma unroll
    for (int i = 0; i < 4; i++)
      af[i] = *(const short8*)&As[cur][(mw + i * 16 + l15) * 32 + quad * 8];
#pragma unroll
    for (int j = 0; j < 4; j++)
      bfr[j] = *(const short8*)&Bs[cur][(nw + j * 16 + l15) * 32 + quad * 8];
#pragma unroll
    for (int i = 0; i < 4; i++)
#pragma unroll
      for (int j = 0; j < 4; j++)
        acc[i][j] = __builtin_amdgcn_mfma_f32_16x16x32_bf16(af[i], bfr[j],
                                                            acc[i][j], 0, 0, 0);
  }

#pragma unroll
  for (int i = 0; i < 4; i++) {
#pragma unroll
    for (int j = 0; j < 4; j++) {
      int col = n0 + nw + j * 16 + l15;
      if (col < N) {
#pragma unroll
        for (int r = 0; r < 4; r++) {
          int row = m0 + mw + i * 16 + quad * 4 + r;
          if (ROUTE == 0) {
            ((float*)Cp)[(size_t)row * N + col] = acc[i][j][r];
          } else {
            if (col < NPROJA)
              ((bf16*)Cp)[(size_t)row * NPROJA + col] = f2b(acc[i][j][r]);
            else
              Cz[(size_t)row * 4096 + (col - NPROJA)] = f2b(acc[i][j][r]);
          }
        }
      }
    }
  }
}

// ------- fused conv(K=4 causal) + SiLU + l2norm for q and k ---------------
__global__ __launch_bounds__(128) void conv_norm_qk(
    const bf16* __restrict__ proj, const float* __restrict__ conv_w,
    bf16* __restrict__ qn, bf16* __restrict__ kn) {
  const int t = blockIdx.x >> 4, hk = blockIdx.x & 15;
  const int d = threadIdx.x;
  const int cq = hk * 128 + d;
  const int ck = 2048 + hk * 128 + d;
  float sq = 0.f, sk = 0.f;
#pragma unroll
  for (int j = 0; j < 4; j++) {
    int ts = t + j - 3;
    if (ts >= 0) {
      sq += conv_w[cq * 4 + j] * b2f(proj[(size_t)ts * NPROJA + cq]);
      sk += conv_w[ck * 4 + j] * b2f(proj[(size_t)ts * NPROJA + ck]);
    }
  }
  float qv = sq / (1.f + expf(-sq));
  float kv = sk / (1.f + expf(-sk));
  float ssq = qv * qv, ssk = kv * kv;
#pragma unroll
  for (int off = 32; off > 0; off >>= 1) {
    ssq += __shfl_down(ssq, off, 64);
    ssk += __shfl_down(ssk, off, 64);
  }
  __shared__ float red[4];
  if ((d & 63) == 0) {
    red[(d >> 6) * 2] = ssq;
    red[(d >> 6) * 2 + 1] = ssk;
  }
  __syncthreads();
  float sumq = red[0] + red[2];
  float sumk = red[1] + red[3];
  size_t o = (size_t)(t * 16 + hk) * 128 + d;
  qn[o] = f2b(qv * rsqrtf(sumq + EPS_) * 0.08838834764831845f);
  kn[o] = f2b(kv * rsqrtf(sumk + EPS_));
}

// ------- conv + SiLU for v channels ---------------------------------------
__global__ __launch_bounds__(256) void conv_silu_v(
    const bf16* __restrict__ proj, const float* __restrict__ conv_w,
    bf16* __restrict__ vbuf) {
  int idx = blockIdx.x * 256 + threadIdx.x;
  int t = idx >> 12, c = idx & 4095;
  int chan = 4096 + c;
  float s = 0.f;
#pragma unroll
  for (int j = 0; j < 4; j++) {
    int ts = t + j - 3;
    if (ts >= 0) s += conv_w[chan * 4 + j] * b2f(proj[(size_t)ts * NPROJA + chan]);
  }
  vbuf[idx] = f2b(s / (1.f + expf(-s)));
}

// ---------------- beta / g ------------------------------------------------
__global__ __launch_bounds__(256) void compute_bg(
    const bf16* __restrict__ proj, const float* __restrict__ A_log,
    const float* __restrict__ dt_bias, float* __restrict__ beta_arr,
    float* __restrict__ g_arr) {
  int idx = blockIdx.x * 256 + threadIdx.x;
  int t = idx >> 5, hv = idx & 31;
  size_t base = (size_t)t * NPROJA + 8192 + (hv >> 1) * 4 + (hv & 1);
  float b = b2f(proj[base]);
  float a = b2f(proj[base + 2]);
  beta_arr[idx] = 1.f / (1.f + expf(-b));
  float x = a + dt_bias[hv];
  float sp = (x > 20.f) ? x : log1pf(expf(x));
  g_arr[idx] = -expf(A_log[hv]) * sp;
}

// ---------------- chunked WY precompute (MFMA BA + blocked fwd-sub) -------
// BA = tril(diag(beta) exp(cg_i-cg_j) K K^T) via MFMA (products exact);
// X = (I+BA)^{-1} diag(beta)[V | Ktilde] via 16-row blocked substitution:
// rank-16 GEMM updates on all 512 threads + short serial diagonal solves.
__global__ __launch_bounds__(512) void precompute_chunk(
    const bf16* __restrict__ kn, const bf16* __restrict__ vbuf,
    const float* __restrict__ g_arr, const float* __restrict__ beta_arr,
    bf16* __restrict__ TV, bf16* __restrict__ TK) {
  const int c = blockIdx.x >> 5, h = blockIdx.x & 31, hk = h >> 1;
  const int t0 = c * 64, tid = threadIdx.x;
  const int wave = tid >> 6, lane = tid & 63, l15 = lane & 15, quad = lane >> 4;
  __shared__ bf16 Ks[64 * 128];     // swizzled [i][dk], 16KB
  __shared__ float X[64][256];      // 64KB
  __shared__ float BA[64][65];      // 16.6KB (pad 65: conflict-free writes)
  __shared__ float cgs[64], bet[64], eKs[64];

  // stage K rows (swizzled for MFMA frag reads)
  {
    const int row = tid >> 4, s = tid & 15;
    short8 v0 = *(const short8*)(kn + ((size_t)(t0 + row) * 16 + hk) * 128 + s * 8);
    short8 v1 = *(const short8*)(kn + ((size_t)(t0 + 32 + row) * 16 + hk) * 128 + s * 8);
    *(short8*)swz(Ks, row, 256, s * 16) = v0;
    *(short8*)swz(Ks, row + 32, 256, s * 16) = v1;
  }
  if (tid < 64) {
    float bb = beta_arr[(size_t)(t0 + tid) * 32 + h];
    bet[tid] = bb;
    float x = g_arr[(size_t)(t0 + tid) * 32 + h];
#pragma unroll
    for (int off = 1; off < 64; off <<= 1) {
      float o = __shfl_up(x, off, 64);
      if (tid >= off) x += o;
    }
    cgs[tid] = x;
    eKs[tid] = bb * expf(x);
  }
  __syncthreads();

  // BA build via MFMA: 10 lower blocks (bi>=bj); slots b = wave*2+s
#pragma unroll
  for (int s = 0; s < 2; ++s) {
    const int b = wave * 2 + s, bi = b >> 2, bj = b & 3;
    if (bi >= bj) {
      f32x4 acc = {0.f, 0.f, 0.f, 0.f};
      const int ar = bi * 16 + l15, br = bj * 16 + l15;
#pragma unroll
      for (int ks = 0; ks < 4; ++ks) {
        const int cb = ks * 64 + quad * 16;
        short8 af = *(const short8*)swzc(Ks, ar, 256, cb);
        short8 bf = *(const short8*)swzc(Ks, br, 256, cb);
        acc = __builtin_amdgcn_mfma_f32_16x16x32_bf16(af, bf, acc, 0, 0, 0);
      }
      // D[row=quad*4+r][col=l15]; strictly-lower only (upper/diag never read)
#pragma unroll
      for (int r = 0; r < 4; ++r) {
        const int i = bi * 16 + quad * 4 + r, j = bj * 16 + l15;
        if (j < i) BA[i][j] = bet[i] * expf(cgs[i] - cgs[j]) * acc[r];
      }
    }
  }
  // X init = diag(beta) [V | Ktilde]
  {
    const int i = tid >> 4, s = tid & 15;
#pragma unroll
    for (int half = 0; half < 2; ++half) {
      const int row = i + half * 32;
      short8 vv = *(const short8*)(vbuf + (size_t)(t0 + row) * 4096 + h * 128 + s * 8);
      short8 kv = *(const short8*)swzc(Ks, row, 256, s * 16);
      bf16 tv_[8], tk_[8];
      *(short8*)tv_ = vv;
      *(short8*)tk_ = kv;
      const float bb = bet[row], ee = eKs[row];
      float o0[8], o1[8];
#pragma unroll
      for (int k = 0; k < 8; ++k) {
        o0[k] = bb * b2f(tv_[k]);
        o1[k] = ee * b2f(tk_[k]);
      }
      *(float4*)&X[row][s * 8] = *(float4*)&o0[0];
      *(float4*)&X[row][s * 8 + 4] = *(float4*)&o0[4];
      *(float4*)&X[row][128 + s * 8] = *(float4*)&o1[0];
      *(float4*)&X[row][128 + s * 8 + 4] = *(float4*)&o1[4];
    }
  }

  // blocked forward substitution: 4 tiles of 16 rows
  const int li = tid >> 5, g4 = (tid & 31) * 4;
#pragma unroll
  for (int t = 0; t < 4; ++t) {
    const int i0 = t * 16;
    __syncthreads();  // prev tile finalized (or init+BA done at t=0)
    if (t > 0) {
      // rank-i0 update on all 512 threads: X[i0+li] -= BA[i0+li][:i0] @ X[:i0]
      const int gi = i0 + li;
      float4 a0 = *(float4*)&X[gi][g4];
      float4 a1 = *(float4*)&X[gi][128 + g4];
      for (int j = 0; j < i0; ++j) {
        const float bij = BA[gi][j];
        float4 x0 = *(float4*)&X[j][g4];
        float4 x1 = *(float4*)&X[j][128 + g4];
        a0.x -= bij * x0.x; a0.y -= bij * x0.y;
        a0.z -= bij * x0.z; a0.w -= bij * x0.w;
        a1.x -= bij * x1.x; a1.y -= bij * x1.y;
        a1.z -= bij * x1.z; a1.w -= bij * x1.w;
      }
      *(float4*)&X[gi][g4] = a0;
      *(float4*)&X[gi][128 + g4] = a1;
      __syncthreads();  // updated rows visible to diag solve
    }
    // diagonal 16x16 solve: thread owns column d (256 cols)
    if (tid < 256) {
      const int d = tid;
#pragma unroll
      for (int i2 = 1; i2 < 16; ++i2) {
        const int i = i0 + i2;
        float s = 0.f;
        for (int j = i0; j < i; ++j) s += BA[i][j] * X[j][d];
        X[i][d] -= s;
      }
    }
  }
  __syncthreads();
  for (int e = tid; e < 8192; e += 512) {
    int i = e >> 7, d = e & 127;
    size_t o = ((size_t)(t0 + i) * 32 + h) * 128 + d;
    TV[o] = f2b(X[i][d]);
    TK[o] = f2b(X[i][128 + d]);
  }
}

// ---------------- sequential inter-chunk recurrence (MFMA, hi/lo S) -------
__global__ __launch_bounds__(512) void seq_kernel(
    bf16* TVU,                       // [4096][32][128]: TV in, U out (in-place)
    const bf16* __restrict__ TKg, const bf16* __restrict__ qn,
    const bf16* __restrict__ kn, const float* __restrict__ g_arr,
    bf16* __restrict__ Oin) {        // vbuf reused: Oinner out
  const int h = blockIdx.x >> 1, dvh = blockIdx.x & 1, hk = h >> 1;
  const int dv0 = dvh * 64;
  const int tid = threadIdx.x;
  const int wave = tid >> 6, lane = tid & 63, l15 = lane & 15, quad = lane >> 4;
  const int mi = wave >> 1, half = wave & 1;
  const int srow = tid >> 4, scol = tid & 15;

  __shared__ bf16 STh[64 * 128], STl[64 * 128];  // S^T [dv][dk] hi/lo
  __shared__ bf16 UTh[64 * 64], UTl[64 * 64];    // U^T [dv][i]  hi/lo
  __shared__ bf16 TKs[64 * 128];                 // TK [i][dk]
  __shared__ bf16 Qts[64 * 128];                 // Qtilde [i][dk]
  __shared__ bf16 KhT[128 * 64];                 // Khat'^T [dk][i] (swzk)

  for (int e = tid; e < 4096; e += 512) {
    ((unsigned int*)STh)[e] = 0u;
    ((unsigned int*)STl)[e] = 0u;
  }
  f32x4 Sf[4];
#pragma unroll
  for (int i = 0; i < 4; i++) Sf[i] = {0.f, 0.f, 0.f, 0.f};

  short8 tkr0, tkr1, qr0, qr1, kr0, kr1;
  float gv;
  auto issue_loads = [&](int c) {
    const size_t t0 = (size_t)c << 6;
    tkr0 = *(const short8*)(TKg + ((t0 + srow) * 32 + h) * 128 + scol * 8);
    tkr1 = *(const short8*)(TKg + ((t0 + 32 + srow) * 32 + h) * 128 + scol * 8);
    qr0 = *(const short8*)(qn + ((t0 + srow) * 16 + hk) * 128 + scol * 8);
    qr1 = *(const short8*)(qn + ((t0 + 32 + srow) * 16 + hk) * 128 + scol * 8);
    kr0 = *(const short8*)(kn + ((t0 + srow) * 16 + hk) * 128 + scol * 8);
    kr1 = *(const short8*)(kn + ((t0 + 32 + srow) * 16 + hk) * 128 + scol * 8);
    gv = g_arr[(t0 + lane) * 32 + h];
  };
  issue_loads(0);

  for (int c = 0; c < 64; ++c) {
    const int t0 = c << 6;
    __syncthreads();  // (A) prev-chunk GEMM reads done; staging buffers free

    // TV prefetch (consumed in U-phase)
    bf16 tvp[2][4];
#pragma unroll
    for (int nj = 0; nj < 2; nj++) {
      const int nrow = half * 32 + nj * 16 + l15;
#pragma unroll
      for (int r = 0; r < 4; r++) {
        const int i = mi * 16 + quad * 4 + r;
        tvp[nj][r] = TVU[((size_t)(t0 + i) * 32 + h) * 128 + dv0 + nrow];
      }
    }
    // all-wave chunk-local cumulative-g scan (lane = chunk row)
    float cg = gv;
#pragma unroll
    for (int off = 1; off < 64; off <<= 1) {
      float o = __shfl_up(cg, off, 64);
      if (lane >= off) cg += o;
    }
    const float cg63 = __shfl(cg, 63, 64);
    const float lam = expf(cg63);
    const float fq = expf(cg);
    const float fk = expf(cg63 - cg);
    // stage TK (vectorized)
    *(short8*)swz(TKs, srow, 256, scol * 16) = tkr0;
    *(short8*)swz(TKs, srow + 32, 256, scol * 16) = tkr1;
    // stage Qtilde = q * fq[row]
    {
      const float f0 = __shfl(fq, srow, 64);
      const float f1 = __shfl(fq, srow + 32, 64);
      bf16 ta[8], tb[8];
      *(short8*)ta = qr0;
      *(short8*)tb = qr1;
#pragma unroll
      for (int k = 0; k < 8; k++) {
        ta[k] = f2b(b2f(ta[k]) * f0);
        tb[k] = f2b(b2f(tb[k]) * f1);
      }
      *(short8*)swz(Qts, srow, 256, scol * 16) = *(short8*)ta;
      *(short8*)swz(Qts, srow + 32, 256, scol * 16) = *(short8*)tb;
    }
    // stage Khat'^T = (k * fk[row])^T, scalar writes spread via swzk
    {
      const float f0 = __shfl(fk, srow, 64);
      const float f1 = __shfl(fk, srow + 32, 64);
      bf16 ka[8], kb[8];
      *(short8*)ka = kr0;
      *(short8*)kb = kr1;
#pragma unroll
      for (int k = 0; k < 8; k++) {
        const int dk = scol * 8 + k;
        *(bf16*)swzk(KhT, dk, srow * 2) = f2b(b2f(ka[k]) * f0);
        *(bf16*)swzk(KhT, dk, (srow + 32) * 2) = f2b(b2f(kb[k]) * f1);
      }
    }
    // T14: issue next-chunk global loads now (fly during GEMM phases)
    issue_loads(c + 1 < 64 ? c + 1 : 63);
    __syncthreads();  // (B) operands staged

    // GEMM3 (Oinner = Qtilde@S) + GEMM1 (x = TK@S) fused over shared B reads
    f32x4 oacc[2], xacc[2];
#pragma unroll
    for (int nj = 0; nj < 2; nj++) { oacc[nj] = {0.f,0.f,0.f,0.f}; xacc[nj] = {0.f,0.f,0.f,0.f}; }
    const int arow = mi * 16 + l15;
#pragma unroll
    for (int ks = 0; ks < 4; ++ks) {
      const int cb = ks * 64 + quad * 16;
      short8 aq = *(const short8*)swzc(Qts, arow, 256, cb);
      short8 at = *(const short8*)swzc(TKs, arow, 256, cb);
#pragma unroll
      for (int nj = 0; nj < 2; nj++) {
        const int nrow = half * 32 + nj * 16 + l15;
        short8 bh = *(const short8*)swzc(STh, nrow, 256, cb);
        short8 bl = *(const short8*)swzc(STl, nrow, 256, cb);
        oacc[nj] = __builtin_amdgcn_mfma_f32_16x16x32_bf16(aq, bh, oacc[nj], 0, 0, 0);
        xacc[nj] = __builtin_amdgcn_mfma_f32_16x16x32_bf16(at, bh, xacc[nj], 0, 0, 0);
        xacc[nj] = __builtin_amdgcn_mfma_f32_16x16x32_bf16(at, bl, xacc[nj], 0, 0, 0);
      }
    }
    // hoist KhT A-fragments into regs
    const int krow = wave * 16 + l15;
    short8 ak0 = *(const short8*)swzkc(KhT, krow, 0 * 64 + quad * 16);
    short8 ak1 = *(const short8*)swzkc(KhT, krow, 1 * 64 + quad * 16);

    // U phase: U = TV - x; write Oinner + U(global) + U^T hi/lo (LDS)
#pragma unroll
    for (int nj = 0; nj < 2; nj++) {
      const int nrow = half * 32 + nj * 16 + l15;
      unsigned short ph[4], pl[4];
#pragma unroll
      for (int r = 0; r < 4; ++r) {
        const int i = mi * 16 + quad * 4 + r;
        const size_t go = ((size_t)(t0 + i) * 32 + h) * 128 + dv0 + nrow;
        Oin[go] = f2b(oacc[nj][r]);
        float uv = b2f(tvp[nj][r]) - xacc[nj][r];
        bf16 hb = f2b(uv);
        TVU[go] = hb;
        ph[r] = b2u(hb);
        pl[r] = b2u(f2b(uv - b2f(hb)));
      }
      const int cb = (mi * 16 + quad * 4) * 2;
      ushort4 vh; vh.x = ph[0]; vh.y = ph[1]; vh.z = ph[2]; vh.w = ph[3];
      ushort4 vl; vl.x = pl[0]; vl.y = pl[1]; vl.z = pl[2]; vl.w = pl[3];
      *(ushort4*)swz(UTh, nrow, 128, cb) = vh;
      *(ushort4*)swz(UTl, nrow, 128, cb) = vl;
    }
    __syncthreads();  // (C) UT visible

    // GEMM2: S = lam*S + Khat'^T @ U  (S master in f32 accumulators)
#pragma unroll
    for (int nj = 0; nj < 4; nj++) {
      Sf[nj][0] *= lam; Sf[nj][1] *= lam; Sf[nj][2] *= lam; Sf[nj][3] *= lam;
    }
#pragma unroll
    for (int ks = 0; ks < 2; ++ks) {
      const short8 ak = ks ? ak1 : ak0;
      const int cb = ks * 64 + quad * 16;
#pragma unroll
      for (int nj = 0; nj < 4; nj++) {
        const int nrow = nj * 16 + l15;
        short8 bh = *(const short8*)swzc(UTh, nrow, 128, cb);
        short8 bl = *(const short8*)swzc(UTl, nrow, 128, cb);
        Sf[nj] = __builtin_amdgcn_mfma_f32_16x16x32_bf16(ak, bh, Sf[nj], 0, 0, 0);
        Sf[nj] = __builtin_amdgcn_mfma_f32_16x16x32_bf16(ak, bl, Sf[nj], 0, 0, 0);
      }
    }
    // write S^T hi/lo for next chunk
#pragma unroll
    for (int nj = 0; nj < 4; nj++) {
      const int nrow = nj * 16 + l15;
      unsigned short ph[4], pl[4];
#pragma unroll
      for (int r = 0; r < 4; ++r) {
        float s = Sf[nj][r];
        bf16 hb = f2b(s);
        ph[r] = b2u(hb);
        pl[r] = b2u(f2b(s - b2f(hb)));
      }
      const int cb = (wave * 16 + quad * 4) * 2;
      ushort4 vh; vh.x = ph[0]; vh.y = ph[1]; vh.z = ph[2]; vh.w = ph[3];
      ushort4 vl; vl.x = pl[0]; vl.y = pl[1]; vl.z = pl[2]; vl.w = pl[3];
      *(ushort4*)swz(STh, nrow, 256, cb) = vh;
      *(ushort4*)swz(STl, nrow, 256, cb) = vl;
    }
  }
}

// ---------------- pass2: O = Oinner + Attn@U, fused gated RMSNorm ---------
__global__ __launch_bounds__(512) void pass2_kernel(
    bf16* UC,                        // U in, normed core out (in-place)
    const bf16* __restrict__ Oin, const bf16* __restrict__ qn,
    const bf16* __restrict__ kn, const float* __restrict__ g_arr,
    const bf16* __restrict__ zbuf, const float* __restrict__ norm_w) {
  const int c = blockIdx.x >> 5, h = blockIdx.x & 31, hk = h >> 1;
  const int t0 = c * 64, tid = threadIdx.x;
  __shared__ float Qf[64][129], Kf[64][129];
  __shared__ float Uf[64][128];
  __shared__ float Of[64][129];
  __shared__ float At[64][65];
  __shared__ float cgs[64], nw[128];

  for (int e = tid; e < 1024; e += 512) {
    int row = e >> 4, s = e & 15;
    size_t qko = ((size_t)(t0 + row) * 16 + hk) * 128 + s * 8;
    size_t uo = ((size_t)(t0 + row) * 32 + h) * 128 + s * 8;
    short8 vq = *(const short8*)(qn + qko);
    short8 vk = *(const short8*)(kn + qko);
    short8 vu = *(const short8*)(UC + uo);
    short8 vo = *(const short8*)(Oin + uo);
    bf16 tq[8], tk[8], tu[8], to[8];
    *(short8*)tq = vq; *(short8*)tk = vk; *(short8*)tu = vu; *(short8*)to = vo;
#pragma unroll
    for (int k = 0; k < 8; ++k) {
      Qf[row][s * 8 + k] = b2f(tq[k]);
      Kf[row][s * 8 + k] = b2f(tk[k]);
      Uf[row][s * 8 + k] = b2f(tu[k]);
      Of[row][s * 8 + k] = b2f(to[k]);
    }
  }
  if (tid < 64) {
    float x = g_arr[(size_t)(t0 + tid) * 32 + h];
#pragma unroll
    for (int off = 1; off < 64; off <<= 1) {
      float o = __shfl_up(x, off, 64);
      if (tid >= off) x += o;
    }
    cgs[tid] = x;
  }
  if (tid < 128) nw[tid] = norm_w[tid];
  __syncthreads();
  // Attn build (includes diagonal): 2 rows x 4 cols per thread
  {
    const int ti = tid >> 4, tj = tid & 15;
    float acc[2][4];
#pragma unroll
    for (int r = 0; r < 2; ++r)
#pragma unroll
      for (int s = 0; s < 4; ++s) acc[r][s] = 0.f;
    for (int dk = 0; dk < 128; ++dk) {
      float a0 = Qf[ti * 2 + 0][dk], a1 = Qf[ti * 2 + 1][dk];
      float c0 = Kf[tj * 4 + 0][dk], c1 = Kf[tj * 4 + 1][dk];
      float c2 = Kf[tj * 4 + 2][dk], c3 = Kf[tj * 4 + 3][dk];
      acc[0][0] += a0 * c0; acc[0][1] += a0 * c1; acc[0][2] += a0 * c2; acc[0][3] += a0 * c3;
      acc[1][0] += a1 * c0; acc[1][1] += a1 * c1; acc[1][2] += a1 * c2; acc[1][3] += a1 * c3;
    }
#pragma unroll
    for (int r = 0; r < 2; ++r)
#pragma unroll
      for (int s = 0; s < 4; ++s) {
        int i = ti * 2 + r, j = tj * 4 + s;
        At[i][j] = (j <= i) ? expf(cgs[i] - cgs[j]) * acc[r][s] : 0.f;
      }
  }
  __syncthreads();
  // O += Attn @ U: 2 rows x 8 cols per thread
  {
    const int ri = tid >> 4, tn = tid & 15;
    float acc[2][8];
#pragma unroll
    for (int r = 0; r < 2; ++r)
#pragma unroll
      for (int k = 0; k < 8; ++k) acc[r][k] = 0.f;
    for (int j = 0; j < 64; ++j) {
      float a0 = At[ri * 2 + 0][j], a1 = At[ri * 2 + 1][j];
#pragma unroll
      for (int k = 0; k < 8; ++k) {
        float u = Uf[j][tn + 16 * k];
        acc[0][k] += a0 * u;
        acc[1][k] += a1 * u;
      }
    }
#pragma unroll
    for (int r = 0; r < 2; ++r)
#pragma unroll
      for (int k = 0; k < 8; ++k)
        Of[ri * 2 + r][tn + 16 * k] += acc[r][k];
  }
  __syncthreads();
  // gated RMSNorm + store: 8 lanes per row
  {
    const int r = tid >> 3, q8 = tid & 7;
    float ss = 0.f;
#pragma unroll
    for (int k = 0; k < 16; ++k) {
      float v = Of[r][q8 + 8 * k];
      ss += v * v;
    }
    ss += __shfl_xor(ss, 1, 64);
    ss += __shfl_xor(ss, 2, 64);
    ss += __shfl_xor(ss, 4, 64);
    float scale = rsqrtf(ss * (1.f / 128.f) + EPS_);
#pragma unroll
    for (int k = 0; k < 16; ++k) {
      int n = q8 + 8 * k;
      float val = Of[r][n] * scale * nw[n];
      float zz = b2f(zbuf[(size_t)(t0 + r) * 4096 + h * 128 + n]);
      val *= zz / (1.f + expf(-zz));
      UC[((size_t)(t0 + r) * 32 + h) * 128 + n] = f2b(val);
    }
  }
}

extern "C" void kernel_launch(void* const* d_in, const int* in_sizes, int n_in,
                              void* d_out, int out_size, void* d_ws,
                              size_t ws_size, hipStream_t stream) {
  const float* hidden = (const float*)d_in[0];
  const float* in_w = (const float*)d_in[1];
  const float* conv_w = (const float*)d_in[2];
  const float* A_log = (const float*)d_in[3];
  const float* dt_bias = (const float*)d_in[4];
  const float* norm_w = (const float*)d_in[5];
  const float* out_w = (const float*)d_in[6];
  float* out = (float*)d_out;

  // workspace layout: total 169,345,024 B (proven size)
  char* p = (char*)d_ws;
  bf16* projA = (bf16*)p;                          // 67,633,152 [4096][8256]
  bf16* TV = (bf16*)p;                             // alias: TV -> U -> core
  bf16* TK = (bf16*)(p + 33554432ULL);
  bf16* zbuf = (bf16*)(p + 67633152ULL);           // 33,554,432 [4096][32][128]
  char* pR = p + 101187584ULL;                     // tail region, 68,157,440 B
  bf16* vbuf = (bf16*)pR;                          // 33,554,432
  float* beta = (float*)(pR + 33554432ULL);        //    524,288
  float* g = (float*)(pR + 34078720ULL);           //    524,288
  bf16* qn = (bf16*)(pR + 34603008ULL);            // 16,777,216
  bf16* kn = (bf16*)(pR + 51380224ULL);            // 16,777,216
  // phase-A aliases over the (then-dead) tail region:
  bf16* Bt_in = (bf16*)pR;                         // 50,659,328 [12352][2048]
  bf16* hb16 = (bf16*)(pR + 50659328ULL);          // 16,777,216 (dead after GEMM)
  bf16* Bt_out = (bf16*)zbuf;                      // 16,777,216 [2048][4096]

  // 0a. hidden fp32 -> bf16
  cvt_bf16<<<(L_SEQ * HDIM) / 1024, 256, 0, stream>>>(hidden, hb16);
  // 0b. in_proj weight: transpose + convert + pack columns -> Bt_in[n][k]
  transpose_w<3><<<dim3(193, 32), 256, 0, stream>>>(in_w, Bt_in, WLD, HDIM);
  // 1. single in_proj GEMM (ping-pong dbuf, chunk-rasterized flat grid)
  gemm_bt<1><<<97 * 32, 256, 0, stream>>>(hb16, Bt_in, projA, zbuf,
                                          NPACK, HDIM, 32, 97);
  // 2. fused conv + silu + l2norm for q,k
  conv_norm_qk<<<L_SEQ * 16, 128, 0, stream>>>(projA, conv_w, qn, kn);
  // 3. conv + silu for v
  conv_silu_v<<<(L_SEQ * 4096) / 256, 256, 0, stream>>>(projA, conv_w, vbuf);
  // 4. beta / g
  compute_bg<<<(L_SEQ * 32) / 256, 256, 0, stream>>>(projA, A_log, dt_bias,
                                                     beta, g);
  // 5. chunked WY precompute (projA dead -> TV/TK overwrite it)
  precompute_chunk<<<2048, 512, 0, stream>>>(kn, vbuf, g, beta, TV, TK);
  // 6. sequential inter-chunk recurrence (TV->U in place, Oinner->vbuf)
  seq_kernel<<<64, 512, 0, stream>>>(TV, TK, qn, kn, g, vbuf);
  // 7. intra-chunk attention + gated RMSNorm (U->core in place)
  pass2_kernel<<<2048, 512, 0, stream>>>(TV, vbuf, qn, kn, g, zbuf, norm_w);
  // 8. out_proj weight: transpose + convert -> Bt_out[n][k] (zbuf dead)
  transpose_w<0><<<dim3(32, 64), 256, 0, stream>>>(out_w, Bt_out, 2048, 4096);
  // 9. out_proj GEMM
  gemm_bt<0><<<16 * 32, 256, 0, stream>>>(TV, Bt_out, out, nullptr,
                                          2048, 4096, 32, 16);
}

// Round 7
// 1162.576 us; speedup vs baseline: 7.1276x; 1.0065x over previous
//
#include <hip/hip_runtime.h>
#include <hip/hip_bf16.h>

#define L_SEQ 4096
#define HDIM 2048
#define NPROJA 8256      // packed q(2048) k(2048) v(4096) ba(64)
#define NPACK 12352      // packed incl z: q|k|v|ba|z
#define WLD 12352        // row stride of in_proj_w
#define EPS_ 1e-6f

using bf16 = __hip_bfloat16;
typedef __attribute__((ext_vector_type(8))) short short8;
typedef __attribute__((ext_vector_type(4))) float f32x4;

__device__ __forceinline__ float b2f(bf16 x) { return __bfloat162float(x); }
__device__ __forceinline__ bf16 f2b(float x) { return __float2bfloat16(x); }
__device__ __forceinline__ unsigned short b2u(bf16 x) {
  union { bf16 b; unsigned short u; } c; c.b = x; return c.u;
}
// XOR-swizzled LDS addressing keyed on row&7 (for 256B/128B-row MFMA tiles)
__device__ __forceinline__ void* swz(void* base, int row, int rowbytes, int colbyte) {
  return (void*)((char*)base + row * rowbytes + (colbyte ^ ((row & 7) << 4)));
}
__device__ __forceinline__ const void* swzc(const void* base, int row, int rowbytes, int colbyte) {
  return (const void*)((const char*)base + row * rowbytes + (colbyte ^ ((row & 7) << 4)));
}
// KhT swizzle: key on (row>>3)&7 (lane-varying) to spread transpose writes
__device__ __forceinline__ void* swzk(void* base, int row, int colbyte) {
  return (void*)((char*)base + row * 128 + (colbyte ^ (((row >> 3) & 7) << 4)));
}
__device__ __forceinline__ const void* swzkc(const void* base, int row, int colbyte) {
  return (const void*)((const char*)base + row * 128 + (colbyte ^ (((row >> 3) & 7) << 4)));
}

__device__ __forceinline__ void async_copy16(const void* g, void* l) {
  __builtin_amdgcn_global_load_lds(
      (const __attribute__((address_space(1))) void*)g,
      (__attribute__((address_space(3))) void*)l, 16, 0, 0);
}

// ---------------- fp32 -> bf16 convert (linear) ---------------------------
__global__ __launch_bounds__(256) void cvt_bf16(const float* __restrict__ in,
                                                bf16* __restrict__ outp) {
  int i = (blockIdx.x * 256 + threadIdx.x) * 4;
  float4 v = *(const float4*)&in[i];
  bf16 o4[4] = {f2b(v.x), f2b(v.y), f2b(v.z), f2b(v.w)};
  *(ushort4*)&outp[i] = *(ushort4*)o4;
}

// -------- packed-column map: n(packed) -> source col of in_proj_w ---------
template <int MODE>
__device__ __forceinline__ int pmap(int n) {
  if constexpr (MODE == 3) {
    if (n < 2048) return (n >> 7) * 768 + (n & 127);
    else if (n < 4096) { int m = n - 2048; return (m >> 7) * 768 + 128 + (m & 127); }
    else if (n < 8192) { int m = n - 4096; return (m >> 8) * 768 + 256 + (m & 255); }
    else if (n < 8256) return 12288 + (n - 8192);
    else { int m = n - 8256; return (m >> 8) * 768 + 512 + (m & 255); }
  } else {
    return n;
  }
}

// -------- weight transpose+convert: Bt[n][k] = bf16(W[k][pmap(n)]) --------
template <int MODE>
__global__ __launch_bounds__(256) void transpose_w(
    const float* __restrict__ W, bf16* __restrict__ Bt, int ldw, int Kd) {
  __shared__ float T[64][65];
  const int nb = blockIdx.x * 64, kb = blockIdx.y * 64;
  const int tid = threadIdx.x;
  const int c = tid & 63, gq = tid >> 6;
  const int sbase = pmap<MODE>(nb);
#pragma unroll
  for (int i = 0; i < 16; ++i) {
    int r = gq * 16 + i;
    T[c][r] = W[(size_t)(kb + r) * ldw + sbase + c];
  }
  __syncthreads();
#pragma unroll
  for (int i = 0; i < 16; ++i) {
    int n = gq * 16 + i;
    Bt[(size_t)(nb + n) * Kd + kb + c] = f2b(T[n][c]);
  }
}

// ---------------- MFMA bf16 GEMM, both operands K-major -------------------
// 3-buffer, 2-tiles-ahead pipeline: per iter, counted s_waitcnt vmcnt(4)
// retires only tile-i's 4 loads (tile i+1's stay in flight across the raw
// s_barrier), then tile i+2 is issued. Loads get ~2 MFMA phases of cover.
// Flat grid, n-chunked rasterization (32 n-panels/chunk) for L2 locality.
template <int ROUTE>
__global__ __launch_bounds__(256) void gemm_bt(
    const bf16* __restrict__ A, const bf16* __restrict__ Bt,
    void* __restrict__ Cp, bf16* __restrict__ Cz, int N, int Kd,
    int MBnum, int NBnum) {
  __shared__ bf16 As[3][128 * 32];
  __shared__ bf16 Bs[3][128 * 32];
  const int tid = threadIdx.x;
  const int wave = tid >> 6, lane = tid & 63;
  const int l15 = lane & 15, quad = lane >> 4;

  int m_blk, n_blk;
  {
    const int CW = 32;
    int fullc = NBnum / CW;
    int rem = NBnum - fullc * CW;
    int thr = fullc * CW * MBnum;
    int wg = blockIdx.x;
    if (wg < thr) {
      int cw = CW * MBnum;
      int chunk = wg / cw, w = wg - chunk * cw;
      n_blk = chunk * CW + (w & (CW - 1));
      m_blk = w / CW;
    } else {
      int w2 = wg - thr;
      int r = rem ? rem : 1;
      n_blk = fullc * CW + w2 % r;
      m_blk = w2 / r;
    }
  }
  const int m0 = m_blk * 128, n0 = n_blk * 128;
  const int mw = (wave >> 1) * 64, nw = (wave & 1) * 64;

  f32x4 acc[4][4];
#pragma unroll
  for (int i = 0; i < 4; i++)
#pragma unroll
    for (int j = 0; j < 4; j++) acc[i][j] = {0.f, 0.f, 0.f, 0.f};

  const bf16* a_src0 = A + (size_t)(m0 + (tid >> 2)) * Kd + (tid & 3) * 8;
  const bf16* a_src1 = a_src0 + (size_t)64 * Kd;
  const bf16* b_src0 = Bt + (size_t)(n0 + (tid >> 2)) * Kd + (tid & 3) * 8;
  const bf16* b_src1 = b_src0 + (size_t)64 * Kd;
  const int d0 = tid * 8, d1 = (tid + 256) * 8;

  // prologue: stage tiles 0 and 1 (Kd >= 64 always here)
  async_copy16(a_src0, &As[0][d0]);
  async_copy16(a_src1, &As[0][d1]);
  async_copy16(b_src0, &Bs[0][d0]);
  async_copy16(b_src1, &Bs[0][d1]);
  async_copy16(a_src0 + 32, &As[1][d0]);
  async_copy16(a_src1 + 32, &As[1][d1]);
  async_copy16(b_src0 + 32, &Bs[1][d0]);
  async_copy16(b_src1 + 32, &Bs[1][d1]);

  auto mfma_step = [&](int bsel) {
    short8 af[4], bfr[4];
#pragma unroll
    for (int i = 0; i < 4; i++)
      af[i] = *(const short8*)&As[bsel][(mw + i * 16 + l15) * 32 + quad * 8];
#pragma unroll
    for (int j = 0; j < 4; j++)
      bfr[j] = *(const short8*)&Bs[bsel][(nw + j * 16 + l15) * 32 + quad * 8];
#pragma unroll
    for (int i = 0; i < 4; i++)
#pragma unroll
      for (int j = 0; j < 4; j++)
        acc[i][j] = __builtin_amdgcn_mfma_f32_16x16x32_bf16(af[i], bfr[j],
                                                            acc[i][j], 0, 0, 0);
  };

  int cur = 0;
  for (int k0 = 0; k0 < Kd - 32; k0 += 32) {
    // tile-i's 4 loads are the 4 oldest of 8 outstanding -> retire them only
    asm volatile("s_waitcnt vmcnt(4)" ::: "memory");
    __builtin_amdgcn_s_barrier();
    __builtin_amdgcn_sched_barrier(0);
    const int nk = k0 + 64;
    if (nk < Kd) {
      int nb = cur + 2; if (nb >= 3) nb -= 3;
      async_copy16(a_src0 + nk, &As[nb][d0]);
      async_copy16(a_src1 + nk, &As[nb][d1]);
      async_copy16(b_src0 + nk, &Bs[nb][d0]);
      async_copy16(b_src1 + nk, &Bs[nb][d1]);
    }
    mfma_step(cur);
    cur = (cur + 1 == 3) ? 0 : cur + 1;
  }
  // final tile: drain everything
  asm volatile("s_waitcnt vmcnt(0)" ::: "memory");
  __builtin_amdgcn_s_barrier();
  __builtin_amdgcn_sched_barrier(0);
  mfma_step(cur);

#pragma unroll
  for (int i = 0; i < 4; i++) {
#pragma unroll
    for (int j = 0; j < 4; j++) {
      int col = n0 + nw + j * 16 + l15;
      if (col < N) {
#pragma unroll
        for (int r = 0; r < 4; r++) {
          int row = m0 + mw + i * 16 + quad * 4 + r;
          if (ROUTE == 0) {
            ((float*)Cp)[(size_t)row * N + col] = acc[i][j][r];
          } else {
            if (col < NPROJA)
              ((bf16*)Cp)[(size_t)row * NPROJA + col] = f2b(acc[i][j][r]);
            else
              Cz[(size_t)row * 4096 + (col - NPROJA)] = f2b(acc[i][j][r]);
          }
        }
      }
    }
  }
}

// ------- fused conv(K=4 causal) + SiLU + l2norm for q and k (vectorized) --
// block = (t, hk-group of 8); 16 lanes x 8 channels per head row.
__global__ __launch_bounds__(128) void conv_norm_qk(
    const bf16* __restrict__ proj, const float* __restrict__ conv_w,
    bf16* __restrict__ qn, bf16* __restrict__ kn) {
  const int t = blockIdx.x >> 1, g = blockIdx.x & 1;
  const int r = threadIdx.x >> 4, s = threadIdx.x & 15;
  const int hk = g * 8 + r;
  const int cq = hk * 128 + s * 8;
  const int ck = 2048 + cq;
  float4 cwq[8], cwk[8];
#pragma unroll
  for (int e = 0; e < 8; ++e) {
    cwq[e] = *(const float4*)&conv_w[(cq + e) * 4];
    cwk[e] = *(const float4*)&conv_w[(ck + e) * 4];
  }
  float aq[8], ak[8];
#pragma unroll
  for (int e = 0; e < 8; ++e) { aq[e] = 0.f; ak[e] = 0.f; }
#pragma unroll
  for (int j = 0; j < 4; j++) {
    int ts = t + j - 3;
    if (ts >= 0) {
      short8 vq = *(const short8*)(proj + (size_t)ts * NPROJA + cq);
      short8 vk = *(const short8*)(proj + (size_t)ts * NPROJA + ck);
      bf16 tq[8], tk[8];
      *(short8*)tq = vq;
      *(short8*)tk = vk;
#pragma unroll
      for (int e = 0; e < 8; ++e) {
        aq[e] += ((const float*)&cwq[e])[j] * b2f(tq[e]);
        ak[e] += ((const float*)&cwk[e])[j] * b2f(tk[e]);
      }
    }
  }
  float fq[8], fk[8], ssq = 0.f, ssk = 0.f;
#pragma unroll
  for (int e = 0; e < 8; ++e) {
    fq[e] = aq[e] / (1.f + expf(-aq[e]));
    fk[e] = ak[e] / (1.f + expf(-ak[e]));
    ssq += fq[e] * fq[e];
    ssk += fk[e] * fk[e];
  }
#pragma unroll
  for (int off = 1; off < 16; off <<= 1) {
    ssq += __shfl_xor(ssq, off, 64);
    ssk += __shfl_xor(ssk, off, 64);
  }
  const float rq = rsqrtf(ssq + EPS_) * 0.08838834764831845f;
  const float rk = rsqrtf(ssk + EPS_);
  bf16 wq[8], wk[8];
#pragma unroll
  for (int e = 0; e < 8; ++e) {
    wq[e] = f2b(fq[e] * rq);
    wk[e] = f2b(fk[e] * rk);
  }
  size_t o = (size_t)(t * 16 + hk) * 128 + s * 8;
  *(short8*)(qn + o) = *(short8*)wq;
  *(short8*)(kn + o) = *(short8*)wk;
}

// ------- conv + SiLU for v channels (vectorized: 8 channels/thread) -------
__global__ __launch_bounds__(256) void conv_silu_v(
    const bf16* __restrict__ proj, const float* __restrict__ conv_w,
    bf16* __restrict__ vbuf) {
  int idx = blockIdx.x * 256 + threadIdx.x;
  int t = idx >> 9, c8 = (idx & 511) * 8;
  int chan = 4096 + c8;
  float4 cw[8];
#pragma unroll
  for (int e = 0; e < 8; ++e) cw[e] = *(const float4*)&conv_w[(chan + e) * 4];
  float acc[8];
#pragma unroll
  for (int e = 0; e < 8; ++e) acc[e] = 0.f;
#pragma unroll
  for (int j = 0; j < 4; j++) {
    int ts = t + j - 3;
    if (ts >= 0) {
      short8 v = *(const short8*)(proj + (size_t)ts * NPROJA + chan);
      bf16 tv[8];
      *(short8*)tv = v;
#pragma unroll
      for (int e = 0; e < 8; ++e)
        acc[e] += ((const float*)&cw[e])[j] * b2f(tv[e]);
    }
  }
  bf16 o[8];
#pragma unroll
  for (int e = 0; e < 8; ++e) o[e] = f2b(acc[e] / (1.f + expf(-acc[e])));
  *(short8*)(vbuf + (size_t)t * 4096 + c8) = *(short8*)o;
}

// ---------------- beta / g ------------------------------------------------
__global__ __launch_bounds__(256) void compute_bg(
    const bf16* __restrict__ proj, const float* __restrict__ A_log,
    const float* __restrict__ dt_bias, float* __restrict__ beta_arr,
    float* __restrict__ g_arr) {
  int idx = blockIdx.x * 256 + threadIdx.x;
  int t = idx >> 5, hv = idx & 31;
  size_t base = (size_t)t * NPROJA + 8192 + (hv >> 1) * 4 + (hv & 1);
  float b = b2f(proj[base]);
  float a = b2f(proj[base + 2]);
  beta_arr[idx] = 1.f / (1.f + expf(-b));
  float x = a + dt_bias[hv];
  float sp = (x > 20.f) ? x : log1pf(expf(x));
  g_arr[idx] = -expf(A_log[hv]) * sp;
}

// ---------------- chunked WY precompute (MFMA BA + blocked fwd-sub) -------
__global__ __launch_bounds__(512) void precompute_chunk(
    const bf16* __restrict__ kn, const bf16* __restrict__ vbuf,
    const float* __restrict__ g_arr, const float* __restrict__ beta_arr,
    bf16* __restrict__ TV, bf16* __restrict__ TK) {
  const int c = blockIdx.x >> 5, h = blockIdx.x & 31, hk = h >> 1;
  const int t0 = c * 64, tid = threadIdx.x;
  const int wave = tid >> 6, lane = tid & 63, l15 = lane & 15, quad = lane >> 4;
  __shared__ bf16 Ks[64 * 128];     // swizzled [i][dk], 16KB
  __shared__ float X[64][256];      // 64KB
  __shared__ float BA[64][65];      // pad 65: conflict-free writes
  __shared__ float cgs[64], bet[64], eKs[64];

  {
    const int row = tid >> 4, s = tid & 15;
    short8 v0 = *(const short8*)(kn + ((size_t)(t0 + row) * 16 + hk) * 128 + s * 8);
    short8 v1 = *(const short8*)(kn + ((size_t)(t0 + 32 + row) * 16 + hk) * 128 + s * 8);
    *(short8*)swz(Ks, row, 256, s * 16) = v0;
    *(short8*)swz(Ks, row + 32, 256, s * 16) = v1;
  }
  if (tid < 64) {
    float bb = beta_arr[(size_t)(t0 + tid) * 32 + h];
    bet[tid] = bb;
    float x = g_arr[(size_t)(t0 + tid) * 32 + h];
#pragma unroll
    for (int off = 1; off < 64; off <<= 1) {
      float o = __shfl_up(x, off, 64);
      if (tid >= off) x += o;
    }
    cgs[tid] = x;
    eKs[tid] = bb * expf(x);
  }
  __syncthreads();

  // BA build via MFMA: 10 lower blocks (bi>=bj); slots b = wave*2+s
#pragma unroll
  for (int s = 0; s < 2; ++s) {
    const int b = wave * 2 + s, bi = b >> 2, bj = b & 3;
    if (bi >= bj) {
      f32x4 acc = {0.f, 0.f, 0.f, 0.f};
      const int ar = bi * 16 + l15, br = bj * 16 + l15;
#pragma unroll
      for (int ks = 0; ks < 4; ++ks) {
        const int cb = ks * 64 + quad * 16;
        short8 af = *(const short8*)swzc(Ks, ar, 256, cb);
        short8 bf = *(const short8*)swzc(Ks, br, 256, cb);
        acc = __builtin_amdgcn_mfma_f32_16x16x32_bf16(af, bf, acc, 0, 0, 0);
      }
#pragma unroll
      for (int r = 0; r < 4; ++r) {
        const int i = bi * 16 + quad * 4 + r, j = bj * 16 + l15;
        if (j < i) BA[i][j] = bet[i] * expf(cgs[i] - cgs[j]) * acc[r];
      }
    }
  }
  // X init = diag(beta) [V | Ktilde]
  {
    const int i = tid >> 4, s = tid & 15;
#pragma unroll
    for (int half = 0; half < 2; ++half) {
      const int row = i + half * 32;
      short8 vv = *(const short8*)(vbuf + (size_t)(t0 + row) * 4096 + h * 128 + s * 8);
      short8 kv = *(const short8*)swzc(Ks, row, 256, s * 16);
      bf16 tv_[8], tk_[8];
      *(short8*)tv_ = vv;
      *(short8*)tk_ = kv;
      const float bb = bet[row], ee = eKs[row];
      float o0[8], o1[8];
#pragma unroll
      for (int k = 0; k < 8; ++k) {
        o0[k] = bb * b2f(tv_[k]);
        o1[k] = ee * b2f(tk_[k]);
      }
      *(float4*)&X[row][s * 8] = *(float4*)&o0[0];
      *(float4*)&X[row][s * 8 + 4] = *(float4*)&o0[4];
      *(float4*)&X[row][128 + s * 8] = *(float4*)&o1[0];
      *(float4*)&X[row][128 + s * 8 + 4] = *(float4*)&o1[4];
    }
  }

  // blocked forward substitution: 4 tiles of 16 rows
  const int li = tid >> 5, g4 = (tid & 31) * 4;
#pragma unroll
  for (int t = 0; t < 4; ++t) {
    const int i0 = t * 16;
    __syncthreads();
    if (t > 0) {
      const int gi = i0 + li;
      float4 a0 = *(float4*)&X[gi][g4];
      float4 a1 = *(float4*)&X[gi][128 + g4];
      for (int j = 0; j < i0; ++j) {
        const float bij = BA[gi][j];
        float4 x0 = *(float4*)&X[j][g4];
        float4 x1 = *(float4*)&X[j][128 + g4];
        a0.x -= bij * x0.x; a0.y -= bij * x0.y;
        a0.z -= bij * x0.z; a0.w -= bij * x0.w;
        a1.x -= bij * x1.x; a1.y -= bij * x1.y;
        a1.z -= bij * x1.z; a1.w -= bij * x1.w;
      }
      *(float4*)&X[gi][g4] = a0;
      *(float4*)&X[gi][128 + g4] = a1;
      __syncthreads();
    }
    if (tid < 256) {
      const int d = tid;
#pragma unroll
      for (int i2 = 1; i2 < 16; ++i2) {
        const int i = i0 + i2;
        float s = 0.f;
        for (int j = i0; j < i; ++j) s += BA[i][j] * X[j][d];
        X[i][d] -= s;
      }
    }
  }
  __syncthreads();
  for (int e = tid; e < 8192; e += 512) {
    int i = e >> 7, d = e & 127;
    size_t o = ((size_t)(t0 + i) * 32 + h) * 128 + d;
    TV[o] = f2b(X[i][d]);
    TK[o] = f2b(X[i][128 + d]);
  }
}

// ---------------- sequential inter-chunk recurrence (MFMA, hi/lo S) -------
__global__ __launch_bounds__(512) void seq_kernel(
    bf16* TVU,                       // [4096][32][128]: TV in, U out (in-place)
    const bf16* __restrict__ TKg, const bf16* __restrict__ qn,
    const bf16* __restrict__ kn, const float* __restrict__ g_arr,
    bf16* __restrict__ Oin) {        // vbuf reused: Oinner out
  const int h = blockIdx.x >> 1, dvh = blockIdx.x & 1, hk = h >> 1;
  const int dv0 = dvh * 64;
  const int tid = threadIdx.x;
  const int wave = tid >> 6, lane = tid & 63, l15 = lane & 15, quad = lane >> 4;
  const int mi = wave >> 1, half = wave & 1;
  const int srow = tid >> 4, scol = tid & 15;

  __shared__ bf16 STh[64 * 128], STl[64 * 128];  // S^T [dv][dk] hi/lo
  __shared__ bf16 UTh[64 * 64], UTl[64 * 64];    // U^T [dv][i]  hi/lo
  __shared__ bf16 TKs[64 * 128];                 // TK [i][dk]
  __shared__ bf16 Qts[64 * 128];                 // Qtilde [i][dk]
  __shared__ bf16 KhT[128 * 64];                 // Khat'^T [dk][i] (swzk)

  for (int e = tid; e < 4096; e += 512) {
    ((unsigned int*)STh)[e] = 0u;
    ((unsigned int*)STl)[e] = 0u;
  }
  f32x4 Sf[4];
#pragma unroll
  for (int i = 0; i < 4; i++) Sf[i] = {0.f, 0.f, 0.f, 0.f};

  short8 tkr0, tkr1, qr0, qr1, kr0, kr1;
  float gv;
  auto issue_loads = [&](int c) {
    const size_t t0 = (size_t)c << 6;
    tkr0 = *(const short8*)(TKg + ((t0 + srow) * 32 + h) * 128 + scol * 8);
    tkr1 = *(const short8*)(TKg + ((t0 + 32 + srow) * 32 + h) * 128 + scol * 8);
    qr0 = *(const short8*)(qn + ((t0 + srow) * 16 + hk) * 128 + scol * 8);
    qr1 = *(const short8*)(qn + ((t0 + 32 + srow) * 16 + hk) * 128 + scol * 8);
    kr0 = *(const short8*)(kn + ((t0 + srow) * 16 + hk) * 128 + scol * 8);
    kr1 = *(const short8*)(kn + ((t0 + 32 + srow) * 16 + hk) * 128 + scol * 8);
    gv = g_arr[(t0 + lane) * 32 + h];
  };
  issue_loads(0);

  for (int c = 0; c < 64; ++c) {
    const int t0 = c << 6;
    __syncthreads();  // (A) prev-chunk GEMM reads done; staging buffers free

    // TV prefetch (consumed in U-phase)
    bf16 tvp[2][4];
#pragma unroll
    for (int nj = 0; nj < 2; nj++) {
      const int nrow = half * 32 + nj * 16 + l15;
#pragma unroll
      for (int r = 0; r < 4; r++) {
        const int i = mi * 16 + quad * 4 + r;
        tvp[nj][r] = TVU[((size_t)(t0 + i) * 32 + h) * 128 + dv0 + nrow];
      }
    }
    // all-wave chunk-local cumulative-g scan (lane = chunk row)
    float cg = gv;
#pragma unroll
    for (int off = 1; off < 64; off <<= 1) {
      float o = __shfl_up(cg, off, 64);
      if (lane >= off) cg += o;
    }
    const float cg63 = __shfl(cg, 63, 64);
    const float lam = expf(cg63);
    const float fq = expf(cg);
    const float fk = expf(cg63 - cg);
    // stage TK (vectorized)
    *(short8*)swz(TKs, srow, 256, scol * 16) = tkr0;
    *(short8*)swz(TKs, srow + 32, 256, scol * 16) = tkr1;
    // stage Qtilde = q * fq[row]
    {
      const float f0 = __shfl(fq, srow, 64);
      const float f1 = __shfl(fq, srow + 32, 64);
      bf16 ta[8], tb[8];
      *(short8*)ta = qr0;
      *(short8*)tb = qr1;
#pragma unroll
      for (int k = 0; k < 8; k++) {
        ta[k] = f2b(b2f(ta[k]) * f0);
        tb[k] = f2b(b2f(tb[k]) * f1);
      }
      *(short8*)swz(Qts, srow, 256, scol * 16) = *(short8*)ta;
      *(short8*)swz(Qts, srow + 32, 256, scol * 16) = *(short8*)tb;
    }
    // stage Khat'^T = (k * fk[row])^T, scalar writes spread via swzk
    {
      const float f0 = __shfl(fk, srow, 64);
      const float f1 = __shfl(fk, srow + 32, 64);
      bf16 ka[8], kb[8];
      *(short8*)ka = kr0;
      *(short8*)kb = kr1;
#pragma unroll
      for (int k = 0; k < 8; k++) {
        const int dk = scol * 8 + k;
        *(bf16*)swzk(KhT, dk, srow * 2) = f2b(b2f(ka[k]) * f0);
        *(bf16*)swzk(KhT, dk, (srow + 32) * 2) = f2b(b2f(kb[k]) * f1);
      }
    }
    // T14: issue next-chunk global loads now (fly during GEMM phases)
    issue_loads(c + 1 < 64 ? c + 1 : 63);
    __syncthreads();  // (B) operands staged

    // GEMM3 (Oinner = Qtilde@S) + GEMM1 (x = TK@S) fused over shared B reads
    f32x4 oacc[2], xacc[2];
#pragma unroll
    for (int nj = 0; nj < 2; nj++) { oacc[nj] = {0.f,0.f,0.f,0.f}; xacc[nj] = {0.f,0.f,0.f,0.f}; }
    const int arow = mi * 16 + l15;
#pragma unroll
    for (int ks = 0; ks < 4; ++ks) {
      const int cb = ks * 64 + quad * 16;
      short8 aq = *(const short8*)swzc(Qts, arow, 256, cb);
      short8 at = *(const short8*)swzc(TKs, arow, 256, cb);
#pragma unroll
      for (int nj = 0; nj < 2; nj++) {
        const int nrow = half * 32 + nj * 16 + l15;
        short8 bh = *(const short8*)swzc(STh, nrow, 256, cb);
        short8 bl = *(const short8*)swzc(STl, nrow, 256, cb);
        oacc[nj] = __builtin_amdgcn_mfma_f32_16x16x32_bf16(aq, bh, oacc[nj], 0, 0, 0);
        xacc[nj] = __builtin_amdgcn_mfma_f32_16x16x32_bf16(at, bh, xacc[nj], 0, 0, 0);
        xacc[nj] = __builtin_amdgcn_mfma_f32_16x16x32_bf16(at, bl, xacc[nj], 0, 0, 0);
      }
    }
    // hoist KhT A-fragments into regs
    const int krow = wave * 16 + l15;
    short8 ak0 = *(const short8*)swzkc(KhT, krow, 0 * 64 + quad * 16);
    short8 ak1 = *(const short8*)swzkc(KhT, krow, 1 * 64 + quad * 16);

    // U phase: U = TV - x; write Oinner + U(global) + U^T hi/lo (LDS)
#pragma unroll
    for (int nj = 0; nj < 2; nj++) {
      const int nrow = half * 32 + nj * 16 + l15;
      unsigned short ph[4], pl[4];
#pragma unroll
      for (int r = 0; r < 4; ++r) {
        const int i = mi * 16 + quad * 4 + r;
        const size_t go = ((size_t)(t0 + i) * 32 + h) * 128 + dv0 + nrow;
        Oin[go] = f2b(oacc[nj][r]);
        float uv = b2f(tvp[nj][r]) - xacc[nj][r];
        bf16 hb = f2b(uv);
        TVU[go] = hb;
        ph[r] = b2u(hb);
        pl[r] = b2u(f2b(uv - b2f(hb)));
      }
      const int cb = (mi * 16 + quad * 4) * 2;
      ushort4 vh; vh.x = ph[0]; vh.y = ph[1]; vh.z = ph[2]; vh.w = ph[3];
      ushort4 vl; vl.x = pl[0]; vl.y = pl[1]; vl.z = pl[2]; vl.w = pl[3];
      *(ushort4*)swz(UTh, nrow, 128, cb) = vh;
      *(ushort4*)swz(UTl, nrow, 128, cb) = vl;
    }
    __syncthreads();  // (C) UT visible

    // GEMM2: S = lam*S + Khat'^T @ U  (S master in f32 accumulators)
#pragma unroll
    for (int nj = 0; nj < 4; nj++) {
      Sf[nj][0] *= lam; Sf[nj][1] *= lam; Sf[nj][2] *= lam; Sf[nj][3] *= lam;
    }
#pragma unroll
    for (int ks = 0; ks < 2; ++ks) {
      const short8 ak = ks ? ak1 : ak0;
      const int cb = ks * 64 + quad * 16;
#pragma unroll
      for (int nj = 0; nj < 4; nj++) {
        const int nrow = nj * 16 + l15;
        short8 bh = *(const short8*)swzc(UTh, nrow, 128, cb);
        short8 bl = *(const short8*)swzc(UTl, nrow, 128, cb);
        Sf[nj] = __builtin_amdgcn_mfma_f32_16x16x32_bf16(ak, bh, Sf[nj], 0, 0, 0);
        Sf[nj] = __builtin_amdgcn_mfma_f32_16x16x32_bf16(ak, bl, Sf[nj], 0, 0, 0);
      }
    }
    // write S^T hi/lo for next chunk
#pragma unroll
    for (int nj = 0; nj < 4; nj++) {
      const int nrow = nj * 16 + l15;
      unsigned short ph[4], pl[4];
#pragma unroll
      for (int r = 0; r < 4; ++r) {
        float s = Sf[nj][r];
        bf16 hb = f2b(s);
        ph[r] = b2u(hb);
        pl[r] = b2u(f2b(s - b2f(hb)));
      }
      const int cb = (wave * 16 + quad * 4) * 2;
      ushort4 vh; vh.x = ph[0]; vh.y = ph[1]; vh.z = ph[2]; vh.w = ph[3];
      ushort4 vl; vl.x = pl[0]; vl.y = pl[1]; vl.z = pl[2]; vl.w = pl[3];
      *(ushort4*)swz(STh, nrow, 256, cb) = vh;
      *(ushort4*)swz(STl, nrow, 256, cb) = vl;
    }
  }
}

// ---------------- pass2: O = Oinner + Attn@U, fused gated RMSNorm ---------
__global__ __launch_bounds__(512) void pass2_kernel(
    bf16* UC,                        // U in, normed core out (in-place)
    const bf16* __restrict__ Oin, const bf16* __restrict__ qn,
    const bf16* __restrict__ kn, const float* __restrict__ g_arr,
    const bf16* __restrict__ zbuf, const float* __restrict__ norm_w) {
  const int c = blockIdx.x >> 5, h = blockIdx.x & 31, hk = h >> 1;
  const int t0 = c * 64, tid = threadIdx.x;
  __shared__ float Qf[64][129], Kf[64][129];
  __shared__ float Uf[64][128];
  __shared__ float Of[64][129];
  __shared__ float At[64][65];
  __shared__ float cgs[64], nw[128];

  for (int e = tid; e < 1024; e += 512) {
    int row = e >> 4, s = e & 15;
    size_t qko = ((size_t)(t0 + row) * 16 + hk) * 128 + s * 8;
    size_t uo = ((size_t)(t0 + row) * 32 + h) * 128 + s * 8;
    short8 vq = *(const short8*)(qn + qko);
    short8 vk = *(const short8*)(kn + qko);
    short8 vu = *(const short8*)(UC + uo);
    short8 vo = *(const short8*)(Oin + uo);
    bf16 tq[8], tk[8], tu[8], to[8];
    *(short8*)tq = vq; *(short8*)tk = vk; *(short8*)tu = vu; *(short8*)to = vo;
#pragma unroll
    for (int k = 0; k < 8; ++k) {
      Qf[row][s * 8 + k] = b2f(tq[k]);
      Kf[row][s * 8 + k] = b2f(tk[k]);
      Uf[row][s * 8 + k] = b2f(tu[k]);
      Of[row][s * 8 + k] = b2f(to[k]);
    }
  }
  if (tid < 64) {
    float x = g_arr[(size_t)(t0 + tid) * 32 + h];
#pragma unroll
    for (int off = 1; off < 64; off <<= 1) {
      float o = __shfl_up(x, off, 64);
      if (tid >= off) x += o;
    }
    cgs[tid] = x;
  }
  if (tid < 128) nw[tid] = norm_w[tid];
  __syncthreads();
  // Attn build (includes diagonal): 2 rows x 4 cols per thread
  {
    const int ti = tid >> 4, tj = tid & 15;
    float acc[2][4];
#pragma unroll
    for (int r = 0; r < 2; ++r)
#pragma unroll
      for (int s = 0; s < 4; ++s) acc[r][s] = 0.f;
    for (int dk = 0; dk < 128; ++dk) {
      float a0 = Qf[ti * 2 + 0][dk], a1 = Qf[ti * 2 + 1][dk];
      float c0 = Kf[tj * 4 + 0][dk], c1 = Kf[tj * 4 + 1][dk];
      float c2 = Kf[tj * 4 + 2][dk], c3 = Kf[tj * 4 + 3][dk];
      acc[0][0] += a0 * c0; acc[0][1] += a0 * c1; acc[0][2] += a0 * c2; acc[0][3] += a0 * c3;
      acc[1][0] += a1 * c0; acc[1][1] += a1 * c1; acc[1][2] += a1 * c2; acc[1][3] += a1 * c3;
    }
#pragma unroll
    for (int r = 0; r < 2; ++r)
#pragma unroll
      for (int s = 0; s < 4; ++s) {
        int i = ti * 2 + r, j = tj * 4 + s;
        At[i][j] = (j <= i) ? expf(cgs[i] - cgs[j]) * acc[r][s] : 0.f;
      }
  }
  __syncthreads();
  // O += Attn @ U: 2 rows x 8 cols per thread
  {
    const int ri = tid >> 4, tn = tid & 15;
    float acc[2][8];
#pragma unroll
    for (int r = 0; r < 2; ++r)
#pragma unroll
      for (int k = 0; k < 8; ++k) acc[r][k] = 0.f;
    for (int j = 0; j < 64; ++j) {
      float a0 = At[ri * 2 + 0][j], a1 = At[ri * 2 + 1][j];
#pragma unroll
      for (int k = 0; k < 8; ++k) {
        float u = Uf[j][tn + 16 * k];
        acc[0][k] += a0 * u;
        acc[1][k] += a1 * u;
      }
    }
#pragma unroll
    for (int r = 0; r < 2; ++r)
#pragma unroll
      for (int k = 0; k < 8; ++k)
        Of[ri * 2 + r][tn + 16 * k] += acc[r][k];
  }
  __syncthreads();
  // gated RMSNorm + store: 8 lanes per row
  {
    const int r = tid >> 3, q8 = tid & 7;
    float ss = 0.f;
#pragma unroll
    for (int k = 0; k < 16; ++k) {
      float v = Of[r][q8 + 8 * k];
      ss += v * v;
    }
    ss += __shfl_xor(ss, 1, 64);
    ss += __shfl_xor(ss, 2, 64);
    ss += __shfl_xor(ss, 4, 64);
    float scale = rsqrtf(ss * (1.f / 128.f) + EPS_);
#pragma unroll
    for (int k = 0; k < 16; ++k) {
      int n = q8 + 8 * k;
      float val = Of[r][n] * scale * nw[n];
      float zz = b2f(zbuf[(size_t)(t0 + r) * 4096 + h * 128 + n]);
      val *= zz / (1.f + expf(-zz));
      UC[((size_t)(t0 + r) * 32 + h) * 128 + n] = f2b(val);
    }
  }
}

extern "C" void kernel_launch(void* const* d_in, const int* in_sizes, int n_in,
                              void* d_out, int out_size, void* d_ws,
                              size_t ws_size, hipStream_t stream) {
  const float* hidden = (const float*)d_in[0];
  const float* in_w = (const float*)d_in[1];
  const float* conv_w = (const float*)d_in[2];
  const float* A_log = (const float*)d_in[3];
  const float* dt_bias = (const float*)d_in[4];
  const float* norm_w = (const float*)d_in[5];
  const float* out_w = (const float*)d_in[6];
  float* out = (float*)d_out;

  // workspace layout: total 169,345,024 B (proven size)
  char* p = (char*)d_ws;
  bf16* projA = (bf16*)p;                          // 67,633,152 [4096][8256]
  bf16* TV = (bf16*)p;                             // alias: TV -> U -> core
  bf16* TK = (bf16*)(p + 33554432ULL);
  bf16* zbuf = (bf16*)(p + 67633152ULL);           // 33,554,432 [4096][32][128]
  char* pR = p + 101187584ULL;                     // tail region, 68,157,440 B
  bf16* vbuf = (bf16*)pR;                          // 33,554,432
  float* beta = (float*)(pR + 33554432ULL);        //    524,288
  float* g = (float*)(pR + 34078720ULL);           //    524,288
  bf16* qn = (bf16*)(pR + 34603008ULL);            // 16,777,216
  bf16* kn = (bf16*)(pR + 51380224ULL);            // 16,777,216
  // phase-A aliases over the (then-dead) tail region:
  bf16* Bt_in = (bf16*)pR;                         // 50,659,328 [12352][2048]
  bf16* hb16 = (bf16*)(pR + 50659328ULL);          // 16,777,216 (dead after GEMM)
  bf16* Bt_out = (bf16*)zbuf;                      // 16,777,216 [2048][4096]

  // 0a. hidden fp32 -> bf16
  cvt_bf16<<<(L_SEQ * HDIM) / 1024, 256, 0, stream>>>(hidden, hb16);
  // 0b. in_proj weight: transpose + convert + pack columns -> Bt_in[n][k]
  transpose_w<3><<<dim3(193, 32), 256, 0, stream>>>(in_w, Bt_in, WLD, HDIM);
  // 1. single in_proj GEMM (3-buf counted-vmcnt pipeline, chunk raster)
  gemm_bt<1><<<97 * 32, 256, 0, stream>>>(hb16, Bt_in, projA, zbuf,
                                          NPACK, HDIM, 32, 97);
  // 2. fused conv + silu + l2norm for q,k (vectorized)
  conv_norm_qk<<<L_SEQ * 2, 128, 0, stream>>>(projA, conv_w, qn, kn);
  // 3. conv + silu for v (vectorized)
  conv_silu_v<<<(L_SEQ * 512) / 256, 256, 0, stream>>>(projA, conv_w, vbuf);
  // 4. beta / g
  compute_bg<<<(L_SEQ * 32) / 256, 256, 0, stream>>>(projA, A_log, dt_bias,
                                                     beta, g);
  // 5. chunked WY precompute (projA dead -> TV/TK overwrite it)
  precompute_chunk<<<2048, 512, 0, stream>>>(kn, vbuf, g, beta, TV, TK);
  // 6. sequential inter-chunk recurrence (TV->U in place, Oinner->vbuf)
  seq_kernel<<<64, 512, 0, stream>>>(TV, TK, qn, kn, g, vbuf);
  // 7. intra-chunk attention + gated RMSNorm (U->core in place)
  pass2_kernel<<<2048, 512, 0, stream>>>(TV, vbuf, qn, kn, g, zbuf, norm_w);
  // 8. out_proj weight: transpose + convert -> Bt_out[n][k] (zbuf dead)
  transpose_w<0><<<dim3(32, 64), 256, 0, stream>>>(out_w, Bt_out, 2048, 4096);
  // 9. out_proj GEMM
  gemm_bt<0><<<16 * 32, 256, 0, stream>>>(TV, Bt_out, out, nullptr,
                                          2048, 4096, 32, 16);
}